// Round 3
// baseline (2798.336 us; speedup 1.0000x reference)
//
#include <hip/hip_runtime.h>
#include <hip/hip_bf16.h>
#include <math.h>

typedef unsigned short u16;
typedef unsigned int u32;

// ---------- bf16 helpers ----------
__device__ __forceinline__ float bf1(u16 s) {
    union { u32 u; float f; } x; x.u = ((u32)s) << 16; return x.f;
}
__device__ __forceinline__ float2 bf2(u32 u) {
    union { u32 a; float f; } lo, hi;
    lo.a = u << 16; hi.a = u & 0xffff0000u;
    float2 r; r.x = lo.f; r.y = hi.f; return r;
}
__device__ __forceinline__ u16 f2bf(float f) {
    u32 u = __float_as_uint(f);
    u32 r = (u + 0x7fffu + ((u >> 16) & 1u)) >> 16;
    return (u16)r;
}

// ---------- dtype detection: flag=1 if external tensors are fp32 ----------
// Reads Wq's even u16 halves as bf16. True-bf16 weights: all |w| < 1.
// fp32 weights misread: low mantissa halves decode to huge/NaN values.
__global__ void detect_k(const u16* __restrict__ W, int* __restrict__ flag) {
    __shared__ int s;
    if (threadIdx.x == 0) s = 0;
    __syncthreads();
    int bad = 0;
    for (int i = threadIdx.x; i < (1 << 19); i += blockDim.x) {
        const float v = bf1(W[2 * i]);
        if (!(fabsf(v) < 1000.f)) bad = 1;   // catches huge AND NaN
    }
    if (bad) atomicOr(&s, 1);
    __syncthreads();
    if (threadIdx.x == 0) *flag = s;
}

__device__ __forceinline__ bool mode_mismatch(const int* dflag, bool wantF32) {
    return ((*dflag) != 0) != wantF32;
}

// log2(10000)/512
#define ROPE_LOG2C (13.287712379549449f / 512.0f)

// ---------- RoPE pass 1: P[t][r] = sum_d base(t,d) * A[d][r] ----------
template <bool WF32>
__global__ void rope1_k(const int* __restrict__ dflag, const void* __restrict__ Ap,
                        float* __restrict__ P) {
    if (mode_mismatch(dflag, WF32)) return;
    const int gid = blockIdx.x * blockDim.x + threadIdx.x;
    if (gid >= 2048 * 16) return;
    const int t = gid >> 4, r = gid & 15;
    const u16* Ab = (const u16*)Ap;
    const float* Af = (const float*)Ap;
    float acc = 0.f;
    for (int i = 0; i < 512; ++i) {
        const float th = exp2f(-(float)i * ROPE_LOG2C);
        const float ang = (float)t * th;
        const float sv = sinf(ang), cv = cosf(ang);
        const float a0 = WF32 ? Af[i * 16 + r] : bf1(Ab[i * 16 + r]);
        const float a1 = WF32 ? Af[(512 + i) * 16 + r] : bf1(Ab[(512 + i) * 16 + r]);
        acc = fmaf(sv, a0, acc);
        acc = fmaf(cv, a1, acc);
    }
    P[gid] = acc;
}

// ---------- RoPE pass 2: sin_f/cos_f[t][i] = trig + (P @ B) ----------
template <bool WF32>
__global__ void rope2_k(const int* __restrict__ dflag, const float* __restrict__ P,
                        const void* __restrict__ Bp, float* __restrict__ sf,
                        float* __restrict__ cf) {
    if (mode_mismatch(dflag, WF32)) return;
    const int gid = blockIdx.x * blockDim.x + threadIdx.x;
    if (gid >= 2048 * 512) return;
    const int t = gid >> 9, i = gid & 511;
    const u16* Bb = (const u16*)Bp;
    const float* Bf = (const float*)Bp;
    float ls = 0.f, lc = 0.f;
#pragma unroll
    for (int r = 0; r < 16; ++r) {
        const float p = P[t * 16 + r];
        const float b0 = WF32 ? Bf[r * 1024 + i] : bf1(Bb[r * 1024 + i]);
        const float b1 = WF32 ? Bf[r * 1024 + 512 + i] : bf1(Bb[r * 1024 + 512 + i]);
        ls = fmaf(p, b0, ls);
        lc = fmaf(p, b1, lc);
    }
    const float th = exp2f(-(float)i * ROPE_LOG2C);
    const float ang = (float)t * th;
    sf[gid] = sinf(ang) + ls;
    cf[gid] = cosf(ang) + lc;
}

// ---------- tiled vector GEMM: C(MxN) = A(MxK) @ Bw(KxN) + epilogue ----------
enum { EP_NONE = 0, EP_ROPE = 1, EP_RBF = 2, EP_RELU = 3, EP_RF32 = 4 };

template <bool ABF, bool CBF, bool WF32, int EPI>
__global__ __launch_bounds__(256) void gemm_k(
    const int* __restrict__ dflag,
    const void* __restrict__ Ap, const void* __restrict__ Bw,
    const void* __restrict__ bias, const float* __restrict__ sf,
    const float* __restrict__ cf, const void* __restrict__ rbf,
    const float* __restrict__ rf, void* __restrict__ Cp,
    int M, int N, int K) {
    if (mode_mismatch(dflag, WF32)) return;
    __shared__ float As[16][128];   // [k][m]
    __shared__ float Bs[16][128];   // [k][n]
    const int tid = threadIdx.x;
    const int tx = tid & 15, ty = tid >> 4;
    const int m0 = blockIdx.y * 128, n0 = blockIdx.x * 128;
    const float* Af = (const float*)Ap;
    const u16* Ab = (const u16*)Ap;
    float acc[8][8];
#pragma unroll
    for (int i = 0; i < 8; i++)
#pragma unroll
        for (int j = 0; j < 8; j++) acc[i][j] = 0.f;

    const int kq = (tid & 3) * 4;   // k sub-offset for A loads
    const int arow = tid >> 2;      // 0..63
    const int bkk = tid >> 4;       // 0..15
    const int bnc = (tid & 15) * 8; // 0..120

    for (int k0 = 0; k0 < K; k0 += 16) {
        __syncthreads();
        // A tile 128x16, stored transposed As[k][m]
#pragma unroll
        for (int rr = 0; rr < 2; ++rr) {
            const int row = arow + rr * 64;
            const size_t off = (size_t)(m0 + row) * K + (k0 + kq);
            float4 av;
            if (ABF) {
                ushort4 uu = *(const ushort4*)(Ab + off);
                av = make_float4(bf1(uu.x), bf1(uu.y), bf1(uu.z), bf1(uu.w));
            } else {
                av = *(const float4*)(Af + off);
            }
            As[kq + 0][row] = av.x; As[kq + 1][row] = av.y;
            As[kq + 2][row] = av.z; As[kq + 3][row] = av.w;
        }
        // B tile 16x128 (external weights; dtype per WF32)
        if (WF32) {
            const float* bp = (const float*)Bw + (size_t)(k0 + bkk) * N + (n0 + bnc);
            *(float4*)&Bs[bkk][bnc]     = *(const float4*)bp;
            *(float4*)&Bs[bkk][bnc + 4] = *(const float4*)(bp + 4);
        } else {
            const u16* bp = (const u16*)Bw + (size_t)(k0 + bkk) * N + (n0 + bnc);
            uint4 u = *(const uint4*)bp;
            float2 f0 = bf2(u.x), f1 = bf2(u.y), f2 = bf2(u.z), f3 = bf2(u.w);
            *(float4*)&Bs[bkk][bnc] = make_float4(f0.x, f0.y, f1.x, f1.y);
            *(float4*)&Bs[bkk][bnc + 4] = make_float4(f2.x, f2.y, f3.x, f3.y);
        }
        __syncthreads();
#pragma unroll
        for (int kk = 0; kk < 16; ++kk) {
            float a[8], b[8];
            float4 a0 = *(const float4*)&As[kk][ty * 8];
            float4 a1 = *(const float4*)&As[kk][ty * 8 + 4];
            float4 b0 = *(const float4*)&Bs[kk][tx * 8];
            float4 b1 = *(const float4*)&Bs[kk][tx * 8 + 4];
            a[0] = a0.x; a[1] = a0.y; a[2] = a0.z; a[3] = a0.w;
            a[4] = a1.x; a[5] = a1.y; a[6] = a1.z; a[7] = a1.w;
            b[0] = b0.x; b[1] = b0.y; b[2] = b0.z; b[3] = b0.w;
            b[4] = b1.x; b[5] = b1.y; b[6] = b1.z; b[7] = b1.w;
#pragma unroll
            for (int i = 0; i < 8; i++)
#pragma unroll
                for (int j = 0; j < 8; j++)
                    acc[i][j] = fmaf(a[i], b[j], acc[i][j]);
        }
    }
    // epilogue
    const int nb = n0 + tx * 8;
    float bb[8];
#pragma unroll
    for (int j = 0; j < 8; j++)
        bb[j] = WF32 ? ((const float*)bias)[nb + j] : bf1(((const u16*)bias)[nb + j]);
#pragma unroll
    for (int i = 0; i < 8; i++) {
        const int m = m0 + ty * 8 + i;
        float o[8];
#pragma unroll
        for (int j = 0; j < 8; j++) o[j] = acc[i][j] + bb[j];
        if (EPI == EP_ROPE) {
            const int t = m & 2047;
#pragma unroll
            for (int p = 0; p < 4; p++) {
                const int fi = (nb >> 1) + p;
                const float sv = sf[t * 512 + fi], cv = cf[t * 512 + fi];
                const float e = o[2 * p], od = o[2 * p + 1];
                o[2 * p]     = e * cv - od * sv;
                o[2 * p + 1] = e * sv + od * cv;
            }
        }
        if (EPI == EP_RBF) {
            if (WF32) {
                const float* rp = (const float*)rbf + (size_t)m * N + nb;
                float4 r0 = *(const float4*)rp;
                float4 r1 = *(const float4*)(rp + 4);
                o[0] += r0.x; o[1] += r0.y; o[2] += r0.z; o[3] += r0.w;
                o[4] += r1.x; o[5] += r1.y; o[6] += r1.z; o[7] += r1.w;
            } else {
                uint4 u = *(const uint4*)((const u16*)rbf + (size_t)m * N + nb);
                float2 f0 = bf2(u.x), f1 = bf2(u.y), f2 = bf2(u.z), f3 = bf2(u.w);
                o[0] += f0.x; o[1] += f0.y; o[2] += f1.x; o[3] += f1.y;
                o[4] += f2.x; o[5] += f2.y; o[6] += f3.x; o[7] += f3.y;
            }
        }
        if (EPI == EP_RELU) {
#pragma unroll
            for (int j = 0; j < 8; j++) o[j] = fmaxf(o[j], 0.f);
        }
        if (EPI == EP_RF32) {
            const float* rp = rf + (size_t)m * N + nb;
            float4 r0 = *(const float4*)rp;
            float4 r1 = *(const float4*)(rp + 4);
            o[0] += r0.x; o[1] += r0.y; o[2] += r0.z; o[3] += r0.w;
            o[4] += r1.x; o[5] += r1.y; o[6] += r1.z; o[7] += r1.w;
        }
        if (CBF) {
            u16* cb = (u16*)Cp + (size_t)m * N + nb;
            ushort4 s0, s1;
            s0.x = f2bf(o[0]); s0.y = f2bf(o[1]); s0.z = f2bf(o[2]); s0.w = f2bf(o[3]);
            s1.x = f2bf(o[4]); s1.y = f2bf(o[5]); s1.z = f2bf(o[6]); s1.w = f2bf(o[7]);
            *(ushort4*)cb = s0;
            *(ushort4*)(cb + 4) = s1;
        } else {
            float* cp = (float*)Cp + (size_t)m * N + nb;
            *(float4*)(cp)     = make_float4(o[0], o[1], o[2], o[3]);
            *(float4*)(cp + 4) = make_float4(o[4], o[5], o[6], o[7]);
        }
    }
}

// ---------- flash attention (full softmax, no mask), bf16 q/k/v/ctx ----------
// All tensors internal ws buffers -> mode-independent, single variant.
__global__ __launch_bounds__(256) void attn_k(
    const u16* __restrict__ Q, const u16* __restrict__ Kg,
    const u16* __restrict__ Vg, u16* __restrict__ O) {
    __shared__ float QsT[64][36];  // [d][row], q pre-scaled by 1/8
    __shared__ float KsT[64][66];  // [d][key]
    __shared__ float Vs[64][68];   // [key][d]
    __shared__ float Ps[32][68];   // [row][key]
    const int tid = threadIdx.x;
    const int bh = blockIdx.y;
    const int b = bh >> 4, h = bh & 15;
    const int row0 = blockIdx.x * 32;
    const size_t base = ((size_t)b * 2048) * 1024 + (size_t)h * 64;

    for (int pos = tid; pos < 512; pos += 256) {
        const int r = pos >> 4, d4 = (pos & 15) * 4;
        ushort4 qv = *(const ushort4*)&Q[base + (size_t)(row0 + r) * 1024 + d4];
        QsT[d4 + 0][r] = bf1(qv.x) * 0.125f;
        QsT[d4 + 1][r] = bf1(qv.y) * 0.125f;
        QsT[d4 + 2][r] = bf1(qv.z) * 0.125f;
        QsT[d4 + 3][r] = bf1(qv.w) * 0.125f;
    }

    const int tx = tid & 31, ty = tid >> 5;  // half-wave owns 4 rows
    float m_i[4], l_i[4], accv[4][2];
#pragma unroll
    for (int i = 0; i < 4; i++) {
        m_i[i] = -INFINITY; l_i[i] = 0.f; accv[i][0] = 0.f; accv[i][1] = 0.f;
    }

    for (int kc = 0; kc < 2048; kc += 64) {
        __syncthreads();
        for (int pos = tid; pos < 1024; pos += 256) {
            const int key = pos >> 4, d4 = (pos & 15) * 4;
            ushort4 kv = *(const ushort4*)&Kg[base + (size_t)(kc + key) * 1024 + d4];
            KsT[d4 + 0][key] = bf1(kv.x); KsT[d4 + 1][key] = bf1(kv.y);
            KsT[d4 + 2][key] = bf1(kv.z); KsT[d4 + 3][key] = bf1(kv.w);
            ushort4 vv4 = *(const ushort4*)&Vg[base + (size_t)(kc + key) * 1024 + d4];
            Vs[key][d4 + 0] = bf1(vv4.x); Vs[key][d4 + 1] = bf1(vv4.y);
            Vs[key][d4 + 2] = bf1(vv4.z); Vs[key][d4 + 3] = bf1(vv4.w);
        }
        __syncthreads();

        float s[4][2];
#pragma unroll
        for (int i = 0; i < 4; i++) { s[i][0] = 0.f; s[i][1] = 0.f; }
#pragma unroll
        for (int d = 0; d < 64; ++d) {
            float4 qv = *(const float4*)&QsT[d][ty * 4];
            float2 kv = *(const float2*)&KsT[d][tx * 2];
            s[0][0] = fmaf(qv.x, kv.x, s[0][0]); s[0][1] = fmaf(qv.x, kv.y, s[0][1]);
            s[1][0] = fmaf(qv.y, kv.x, s[1][0]); s[1][1] = fmaf(qv.y, kv.y, s[1][1]);
            s[2][0] = fmaf(qv.z, kv.x, s[2][0]); s[2][1] = fmaf(qv.z, kv.y, s[2][1]);
            s[3][0] = fmaf(qv.w, kv.x, s[3][0]); s[3][1] = fmaf(qv.w, kv.y, s[3][1]);
        }

#pragma unroll
        for (int i = 0; i < 4; i++) {
            float sm = fmaxf(s[i][0], s[i][1]);
#pragma unroll
            for (int msk = 16; msk >= 1; msk >>= 1)
                sm = fmaxf(sm, __shfl_xor(sm, msk));
            const float mnew = fmaxf(m_i[i], sm);
            const float alpha = __expf(m_i[i] - mnew);
            const float p0 = __expf(s[i][0] - mnew);
            const float p1 = __expf(s[i][1] - mnew);
            float ps = p0 + p1;
#pragma unroll
            for (int msk = 16; msk >= 1; msk >>= 1) ps += __shfl_xor(ps, msk);
            l_i[i] = l_i[i] * alpha + ps;
            m_i[i] = mnew;
            accv[i][0] *= alpha; accv[i][1] *= alpha;
            Ps[ty * 4 + i][tx * 2]     = p0;
            Ps[ty * 4 + i][tx * 2 + 1] = p1;
        }
        __syncthreads();

#pragma unroll
        for (int k4 = 0; k4 < 64; k4 += 4) {
            float2 v0 = *(const float2*)&Vs[k4 + 0][tx * 2];
            float2 v1 = *(const float2*)&Vs[k4 + 1][tx * 2];
            float2 v2 = *(const float2*)&Vs[k4 + 2][tx * 2];
            float2 v3 = *(const float2*)&Vs[k4 + 3][tx * 2];
#pragma unroll
            for (int i = 0; i < 4; i++) {
                float4 p4 = *(const float4*)&Ps[ty * 4 + i][k4];
                accv[i][0] += p4.x * v0.x + p4.y * v1.x + p4.z * v2.x + p4.w * v3.x;
                accv[i][1] += p4.x * v0.y + p4.y * v1.y + p4.z * v2.y + p4.w * v3.y;
            }
        }
    }

#pragma unroll
    for (int i = 0; i < 4; i++) {
        const float inv = 1.f / l_i[i];
        ushort2 outv;
        outv.x = f2bf(accv[i][0] * inv);
        outv.y = f2bf(accv[i][1] * inv);
        *(ushort2*)&O[base + (size_t)(row0 + ty * 4 + i) * 1024 + tx * 2] = outv;
    }
}

// ---------- layernorm over 1024 cols; outf (fp32) xor outb (bf16) ----------
template <bool WF32>
__global__ __launch_bounds__(256) void ln_k(
    const int* __restrict__ dflag,
    const float* __restrict__ X, const void* __restrict__ gp,
    const void* __restrict__ bp, float* __restrict__ outf,
    u16* __restrict__ outb) {
    if (mode_mismatch(dflag, WF32)) return;
    const int row = blockIdx.x, tid = threadIdx.x;
    const float* x = X + (size_t)row * 1024;
    float4 xv = *(const float4*)&x[tid * 4];
    float s = xv.x + xv.y + xv.z + xv.w;
    float s2 = xv.x * xv.x + xv.y * xv.y + xv.z * xv.z + xv.w * xv.w;
#pragma unroll
    for (int msk = 32; msk >= 1; msk >>= 1) {
        s += __shfl_xor(s, msk);
        s2 += __shfl_xor(s2, msk);
    }
    __shared__ float red[8];
    const int wv = tid >> 6;
    if ((tid & 63) == 0) { red[wv] = s; red[wv + 4] = s2; }
    __syncthreads();
    s = red[0] + red[1] + red[2] + red[3];
    s2 = red[4] + red[5] + red[6] + red[7];
    const float mu = s * (1.f / 1024.f);
    float var = s2 * (1.f / 1024.f) - mu * mu;
    var = fmaxf(var, 0.f);
    const float rstd = rsqrtf(var + 1e-5f);
    float gv[4], bv[4];
    if (WF32) {
        float4 g4 = *(const float4*)((const float*)gp + tid * 4);
        float4 b4 = *(const float4*)((const float*)bp + tid * 4);
        gv[0] = g4.x; gv[1] = g4.y; gv[2] = g4.z; gv[3] = g4.w;
        bv[0] = b4.x; bv[1] = b4.y; bv[2] = b4.z; bv[3] = b4.w;
    } else {
        ushort4 g4 = *(const ushort4*)((const u16*)gp + tid * 4);
        ushort4 b4 = *(const ushort4*)((const u16*)bp + tid * 4);
        gv[0] = bf1(g4.x); gv[1] = bf1(g4.y); gv[2] = bf1(g4.z); gv[3] = bf1(g4.w);
        bv[0] = bf1(b4.x); bv[1] = bf1(b4.y); bv[2] = bf1(b4.z); bv[3] = bf1(b4.w);
    }
    float o0 = (xv.x - mu) * rstd * gv[0] + bv[0];
    float o1 = (xv.y - mu) * rstd * gv[1] + bv[1];
    float o2 = (xv.z - mu) * rstd * gv[2] + bv[2];
    float o3 = (xv.w - mu) * rstd * gv[3] + bv[3];
    if (outf) {
        *(float4*)(outf + (size_t)row * 1024 + tid * 4) = make_float4(o0, o1, o2, o3);
    } else {
        ushort4 ov;
        ov.x = f2bf(o0); ov.y = f2bf(o1); ov.z = f2bf(o2); ov.w = f2bf(o3);
        *(ushort4*)(outb + (size_t)row * 1024 + tid * 4) = ov;
    }
}

extern "C" void kernel_launch(void* const* d_in, const int* in_sizes, int n_in,
                              void* d_out, int out_size, void* d_ws, size_t ws_size,
                              hipStream_t stream) {
    const void* tgt = d_in[0];
    const void* Wq  = d_in[1];
    const void* bq  = d_in[2];
    const void* Wk  = d_in[3];
    const void* bk  = d_in[4];
    const void* Wv  = d_in[5];
    const void* bv  = d_in[6];
    const void* Wo  = d_in[7];
    const void* bo  = d_in[8];
    const void* W1  = d_in[9];
    const void* b1  = d_in[10];
    const void* W2  = d_in[11];
    const void* b2  = d_in[12];
    const void* g1  = d_in[13];
    const void* be1 = d_in[14];
    const void* g2  = d_in[15];
    const void* be2 = d_in[16];
    const void* rA  = d_in[17];
    const void* rB  = d_in[18];

    const int M = 4096, D = 1024, DFF = 4096;
    const size_t MD = (size_t)M * D;   // 4M elements

    // workspace layout (~56.1 MB):
    //   q,kk,vv,ctx (bf16, 4 x MD u16 = 32 MB); h aliases q
    //   x1 (fp32, MD), sf/cf (fp32, 2 x 1M), P (fp32, 32K), flag (int)
    u16* q   = (u16*)d_ws;
    u16* kk  = q + MD;
    u16* vv  = kk + MD;
    u16* ctx = vv + MD;
    u16* h   = q;                         // alias, free after Wo gemm
    float* x1  = (float*)(q + 4 * MD);
    float* sfp = x1 + MD;
    float* cfp = sfp + (size_t)2048 * 512;
    float* Pp  = cfp + (size_t)2048 * 512;
    int* dflag = (int*)(Pp + 2048 * 16);

    detect_k<<<dim3(1), dim3(1024), 0, stream>>>((const u16*)Wq, dflag);

    rope1_k<false><<<dim3(128), dim3(256), 0, stream>>>(dflag, rA, Pp);
    rope1_k<true ><<<dim3(128), dim3(256), 0, stream>>>(dflag, rA, Pp);
    rope2_k<false><<<dim3(4096), dim3(256), 0, stream>>>(dflag, Pp, rB, sfp, cfp);
    rope2_k<true ><<<dim3(4096), dim3(256), 0, stream>>>(dflag, Pp, rB, sfp, cfp);

    // QKV projections (A = tgt external: bf16 in bf16-mode, fp32 in fp32-mode)
    gemm_k<true , true, false, EP_ROPE><<<dim3(8, 32), dim3(256), 0, stream>>>(
        dflag, tgt, Wq, bq, sfp, cfp, nullptr, nullptr, q, M, D, D);
    gemm_k<false, true, true , EP_ROPE><<<dim3(8, 32), dim3(256), 0, stream>>>(
        dflag, tgt, Wq, bq, sfp, cfp, nullptr, nullptr, q, M, D, D);
    gemm_k<true , true, false, EP_ROPE><<<dim3(8, 32), dim3(256), 0, stream>>>(
        dflag, tgt, Wk, bk, sfp, cfp, nullptr, nullptr, kk, M, D, D);
    gemm_k<false, true, true , EP_ROPE><<<dim3(8, 32), dim3(256), 0, stream>>>(
        dflag, tgt, Wk, bk, sfp, cfp, nullptr, nullptr, kk, M, D, D);
    gemm_k<true , true, false, EP_NONE><<<dim3(8, 32), dim3(256), 0, stream>>>(
        dflag, tgt, Wv, bv, nullptr, nullptr, nullptr, nullptr, vv, M, D, D);
    gemm_k<false, true, true , EP_NONE><<<dim3(8, 32), dim3(256), 0, stream>>>(
        dflag, tgt, Wv, bv, nullptr, nullptr, nullptr, nullptr, vv, M, D, D);

    attn_k<<<dim3(64, 32), dim3(256), 0, stream>>>(q, kk, vv, ctx);

    // Wo projection + residual(tgt) -> x1 fp32
    gemm_k<true, false, false, EP_RBF><<<dim3(8, 32), dim3(256), 0, stream>>>(
        dflag, ctx, Wo, bo, nullptr, nullptr, tgt, nullptr, x1, M, D, D);
    gemm_k<true, false, true , EP_RBF><<<dim3(8, 32), dim3(256), 0, stream>>>(
        dflag, ctx, Wo, bo, nullptr, nullptr, tgt, nullptr, x1, M, D, D);

    ln_k<false><<<dim3(4096), dim3(256), 0, stream>>>(dflag, x1, g1, be1, x1, nullptr);
    ln_k<true ><<<dim3(4096), dim3(256), 0, stream>>>(dflag, x1, g1, be1, x1, nullptr);

    // FFN: relu(x1 @ W1 + b1) -> h (bf16), then h @ W2 + b2 + x1 -> x1
    gemm_k<false, true, false, EP_RELU><<<dim3(32, 32), dim3(256), 0, stream>>>(
        dflag, x1, W1, b1, nullptr, nullptr, nullptr, nullptr, h, M, DFF, D);
    gemm_k<false, true, true , EP_RELU><<<dim3(32, 32), dim3(256), 0, stream>>>(
        dflag, x1, W1, b1, nullptr, nullptr, nullptr, nullptr, h, M, DFF, D);
    gemm_k<true, false, false, EP_RF32><<<dim3(8, 32), dim3(256), 0, stream>>>(
        dflag, h, W2, b2, nullptr, nullptr, nullptr, x1, x1, M, D, DFF);
    gemm_k<true, false, true , EP_RF32><<<dim3(8, 32), dim3(256), 0, stream>>>(
        dflag, h, W2, b2, nullptr, nullptr, nullptr, x1, x1, M, D, DFF);

    // Final LN -> d_out (dtype per mode)
    ln_k<false><<<dim3(4096), dim3(256), 0, stream>>>(
        dflag, x1, g2, be2, nullptr, (u16*)d_out);
    ln_k<true ><<<dim3(4096), dim3(256), 0, stream>>>(
        dflag, x1, g2, be2, (float*)d_out, nullptr);

    (void)in_sizes; (void)n_in; (void)out_size; (void)ws_size;
}

// Round 4
// 762.974 us; speedup vs baseline: 3.6677x; 3.6677x over previous
//
#include <hip/hip_runtime.h>
#include <math.h>

typedef unsigned short u16;
typedef unsigned int u32;
typedef __attribute__((ext_vector_type(8))) short short8v;
typedef __attribute__((ext_vector_type(4))) float f32x4;

__device__ __forceinline__ u16 f2bf(float f) {
    u32 u = __float_as_uint(f);
    u32 r = (u + 0x7fffu + ((u >> 16) & 1u)) >> 16;
    return (u16)r;
}

// ---------- elementwise fp32 -> bf16 cast ----------
__global__ void cast_k(const float* __restrict__ x, u16* __restrict__ y) {
    const int gid = blockIdx.x * blockDim.x + threadIdx.x;
    float4 v = ((const float4*)x)[gid];
    ushort4 o;
    o.x = f2bf(v.x); o.y = f2bf(v.y); o.z = f2bf(v.z); o.w = f2bf(v.w);
    ((ushort4*)y)[gid] = o;
}

// ---------- transpose + cast: S (KxN fp32) -> Dt (NxK bf16) ----------
__global__ __launch_bounds__(256) void tcast_k(const float* __restrict__ S,
                                               u16* __restrict__ Dt,
                                               int K, int N) {
    __shared__ float tile[32][33];
    const int n0 = blockIdx.x * 32, k0 = blockIdx.y * 32;
    const int tx = threadIdx.x & 31, ty = threadIdx.x >> 5;
#pragma unroll
    for (int i = 0; i < 4; i++)
        tile[ty + 8 * i][tx] = S[(size_t)(k0 + ty + 8 * i) * N + n0 + tx];
    __syncthreads();
#pragma unroll
    for (int i = 0; i < 4; i++)
        Dt[(size_t)(n0 + ty + 8 * i) * K + k0 + tx] = f2bf(tile[tx][ty + 8 * i]);
}

// log2(10000)/512
#define ROPE_LOG2C (13.287712379549449f / 512.0f)

// ---------- RoPE pass 1: P[t][r] = sum_d base(t,d) * A[d][r] (A fp32) ----------
__global__ void rope1_k(const float* __restrict__ A, float* __restrict__ P) {
    const int gid = blockIdx.x * blockDim.x + threadIdx.x;
    if (gid >= 2048 * 16) return;
    const int t = gid >> 4, r = gid & 15;
    float acc = 0.f;
    for (int i = 0; i < 512; ++i) {
        const float th = exp2f(-(float)i * ROPE_LOG2C);
        const float ang = (float)t * th;
        acc = fmaf(sinf(ang), A[i * 16 + r], acc);
        acc = fmaf(cosf(ang), A[(512 + i) * 16 + r], acc);
    }
    P[gid] = acc;
}

// ---------- RoPE pass 2: sin_f/cos_f (B fp32) ----------
__global__ void rope2_k(const float* __restrict__ P, const float* __restrict__ Bw,
                        float* __restrict__ sf, float* __restrict__ cf) {
    const int gid = blockIdx.x * blockDim.x + threadIdx.x;
    if (gid >= 2048 * 512) return;
    const int t = gid >> 9, i = gid & 511;
    float ls = 0.f, lc = 0.f;
#pragma unroll
    for (int r = 0; r < 16; ++r) {
        const float p = P[t * 16 + r];
        ls = fmaf(p, Bw[r * 1024 + i], ls);
        lc = fmaf(p, Bw[r * 1024 + 512 + i], lc);
    }
    const float th = exp2f(-(float)i * ROPE_LOG2C);
    const float ang = (float)t * th;
    sf[gid] = sinf(ang) + ls;
    cf[gid] = cosf(ang) + lc;
}

// ---------- MFMA GEMM: C(MxN) = A(MxK,bf16) @ Bt(NxK,bf16)^T + epilogue ----------
enum { EP_NONE = 0, EP_ROPE = 1, EP_RES = 2, EP_RELU = 3 };

template <int EPI, bool CBF>
__global__ __launch_bounds__(256) void mgemm_k(
    const u16* __restrict__ A, const u16* __restrict__ Bt,
    const float* __restrict__ bias, const float* __restrict__ sf,
    const float* __restrict__ cf, const float* __restrict__ resf,
    void* __restrict__ Cp, int M, int N, int K) {
    __shared__ u16 As[128][40];   // [m][k] bf16, pad +8 (2-way conflicts only)
    __shared__ u16 Bs[128][40];   // [n][k] bf16
    const int tid = threadIdx.x;
    const int w = tid >> 6, l = tid & 63;
    const int quad = l >> 4, lr = l & 15;
    const int wr = w >> 1, wc = w & 1;
    const int m0 = blockIdx.y * 128, n0 = blockIdx.x * 128;
    const int srow = tid >> 1, sseg = (tid & 1) * 16;

    f32x4 acc[4][4];
#pragma unroll
    for (int i = 0; i < 4; i++)
#pragma unroll
        for (int j = 0; j < 4; j++) acc[i][j] = (f32x4)(0.0f);

    const u16* ag = A + (size_t)(m0 + srow) * K + sseg;
    const u16* bg = Bt + (size_t)(n0 + srow) * K + sseg;

    for (int k0 = 0; k0 < K; k0 += 32) {
        __syncthreads();
        uint4 a0 = *(const uint4*)(ag + k0);
        uint4 a1 = *(const uint4*)(ag + k0 + 8);
        uint4 b0 = *(const uint4*)(bg + k0);
        uint4 b1 = *(const uint4*)(bg + k0 + 8);
        *(uint4*)&As[srow][sseg]     = a0;
        *(uint4*)&As[srow][sseg + 8] = a1;
        *(uint4*)&Bs[srow][sseg]     = b0;
        *(uint4*)&Bs[srow][sseg + 8] = b1;
        __syncthreads();
        short8v af[4], bf[4];
#pragma unroll
        for (int mt = 0; mt < 4; ++mt)
            af[mt] = *(const short8v*)&As[wr * 64 + mt * 16 + lr][quad * 8];
#pragma unroll
        for (int nt = 0; nt < 4; ++nt)
            bf[nt] = *(const short8v*)&Bs[wc * 64 + nt * 16 + lr][quad * 8];
#pragma unroll
        for (int mt = 0; mt < 4; ++mt)
#pragma unroll
            for (int nt = 0; nt < 4; ++nt)
                acc[mt][nt] = __builtin_amdgcn_mfma_f32_16x16x32_bf16(
                    af[mt], bf[nt], acc[mt][nt], 0, 0, 0);
    }

    // epilogue: D[row=quad*4+reg][col=lr] per 16x16 tile
#pragma unroll
    for (int mt = 0; mt < 4; ++mt) {
#pragma unroll
        for (int nt = 0; nt < 4; ++nt) {
            const int n = n0 + wc * 64 + nt * 16 + lr;
            const float bb = bias[n];
#pragma unroll
            for (int reg = 0; reg < 4; ++reg) {
                const int m = m0 + wr * 64 + mt * 16 + quad * 4 + reg;
                float v = acc[mt][nt][reg] + bb;
                if (EPI == EP_ROPE) {
                    const float partner = __shfl_xor(v, 1);
                    const int t = m & 2047;
                    const int fi = n >> 1;
                    const float svv = sf[t * 512 + fi];
                    const float cvv = cf[t * 512 + fi];
                    v = (n & 1) ? fmaf(partner, svv, v * cvv)
                                : fmaf(v, cvv, -partner * svv);
                }
                if (EPI == EP_RES) v += resf[(size_t)m * N + n];
                if (EPI == EP_RELU) v = fmaxf(v, 0.f);
                if (CBF) ((u16*)Cp)[(size_t)m * N + n] = f2bf(v);
                else     ((float*)Cp)[(size_t)m * N + n] = v;
            }
        }
    }
}

// ---------- MFMA flash attention ----------
// grid (T/64, B*H), block 256 (4 waves, 16 q-rows each). Q/K/V/O bf16 [B*T][1024].
__global__ __launch_bounds__(256) void mattn_k(
    const u16* __restrict__ Q, const u16* __restrict__ Kg,
    const u16* __restrict__ Vg, u16* __restrict__ O) {
    __shared__ u16 Qs[64][72];
    __shared__ u16 Ks[64][72];
    __shared__ u16 Ps[4][16][72];
    const int tid = threadIdx.x;
    const int w = tid >> 6, l = tid & 63;
    const int quad = l >> 4, lr = l & 15;
    const int bh = blockIdx.y, b = bh >> 4, h = bh & 15;
    const int row0 = blockIdx.x * 64;
    const size_t base = (size_t)b * 2048 * 1024 + (size_t)h * 64;

    {   // stage Q tile (64 rows x 64 d)
        const int r = tid >> 2, seg = (tid & 3) * 16;
        const u16* qp = Q + base + (size_t)(row0 + r) * 1024 + seg;
        *(uint4*)&Qs[r][seg]     = *(const uint4*)qp;
        *(uint4*)&Qs[r][seg + 8] = *(const uint4*)(qp + 8);
    }
    __syncthreads();
    const short8v aq0 = *(const short8v*)&Qs[w * 16 + lr][quad * 8];
    const short8v aq1 = *(const short8v*)&Qs[w * 16 + lr][32 + quad * 8];

    float m_i[4], l_i[4];
    f32x4 o_acc[4];
#pragma unroll
    for (int r = 0; r < 4; r++) { m_i[r] = -INFINITY; l_i[r] = 0.f; }
#pragma unroll
    for (int nt = 0; nt < 4; nt++) o_acc[nt] = (f32x4)(0.0f);

    for (int kc = 0; kc < 2048; kc += 64) {
        __syncthreads();
        {   // stage K tile (64 keys x 64 d)
            const int r = tid >> 2, seg = (tid & 3) * 16;
            const u16* kp = Kg + base + (size_t)(kc + r) * 1024 + seg;
            *(uint4*)&Ks[r][seg]     = *(const uint4*)kp;
            *(uint4*)&Ks[r][seg + 8] = *(const uint4*)(kp + 8);
        }
        __syncthreads();

        // S = Q K^T : B-frag from Ks rows (K[key][d] -> B[k=d][n=key])
        f32x4 s[4];
#pragma unroll
        for (int nt = 0; nt < 4; nt++) s[nt] = (f32x4)(0.0f);
#pragma unroll
        for (int nt = 0; nt < 4; nt++) {
            short8v bk0 = *(const short8v*)&Ks[nt * 16 + lr][quad * 8];
            short8v bk1 = *(const short8v*)&Ks[nt * 16 + lr][32 + quad * 8];
            s[nt] = __builtin_amdgcn_mfma_f32_16x16x32_bf16(aq0, bk0, s[nt], 0, 0, 0);
            s[nt] = __builtin_amdgcn_mfma_f32_16x16x32_bf16(aq1, bk1, s[nt], 0, 0, 0);
        }

        // V B-frags direct from global (issued before softmax to hide latency):
        // B[k=key][n=d]: lane holds V[kc + kk*32 + quad*8+j][nt*16+lr]
        short8v vf[4][2];
#pragma unroll
        for (int nt = 0; nt < 4; nt++)
#pragma unroll
            for (int kkh = 0; kkh < 2; kkh++) {
                short8v t;
#pragma unroll
                for (int j = 0; j < 8; j++)
                    t[j] = (short)Vg[base +
                        (size_t)(kc + kkh * 32 + quad * 8 + j) * 1024 +
                        nt * 16 + lr];
                vf[nt][kkh] = t;
            }

        // online softmax (rows = quad*4+reg, cols spread over 16 lanes x 4 nt)
        float p[4][4];
        float alpha[4];
#pragma unroll
        for (int reg = 0; reg < 4; reg++) {
            float sv0 = s[0][reg] * 0.125f, sv1 = s[1][reg] * 0.125f;
            float sv2 = s[2][reg] * 0.125f, sv3 = s[3][reg] * 0.125f;
            float rm = fmaxf(fmaxf(sv0, sv1), fmaxf(sv2, sv3));
            rm = fmaxf(rm, __shfl_xor(rm, 1));
            rm = fmaxf(rm, __shfl_xor(rm, 2));
            rm = fmaxf(rm, __shfl_xor(rm, 4));
            rm = fmaxf(rm, __shfl_xor(rm, 8));
            const float mnew = fmaxf(m_i[reg], rm);
            alpha[reg] = __expf(m_i[reg] - mnew);
            m_i[reg] = mnew;
            p[0][reg] = __expf(sv0 - mnew);
            p[1][reg] = __expf(sv1 - mnew);
            p[2][reg] = __expf(sv2 - mnew);
            p[3][reg] = __expf(sv3 - mnew);
            float rs = p[0][reg] + p[1][reg] + p[2][reg] + p[3][reg];
            rs += __shfl_xor(rs, 1);
            rs += __shfl_xor(rs, 2);
            rs += __shfl_xor(rs, 4);
            rs += __shfl_xor(rs, 8);
            l_i[reg] = l_i[reg] * alpha[reg] + rs;
        }
#pragma unroll
        for (int nt = 0; nt < 4; nt++) {
#pragma unroll
            for (int reg = 0; reg < 4; reg++) {
                o_acc[nt][reg] *= alpha[reg];
                Ps[w][quad * 4 + reg][nt * 16 + lr] = f2bf(p[nt][reg]);
            }
        }
        // P: C-layout -> A-layout via wave-local LDS round-trip (no barrier needed)
        const short8v ap0 = *(const short8v*)&Ps[w][lr][quad * 8];
        const short8v ap1 = *(const short8v*)&Ps[w][lr][32 + quad * 8];
#pragma unroll
        for (int nt = 0; nt < 4; nt++) {
            o_acc[nt] = __builtin_amdgcn_mfma_f32_16x16x32_bf16(ap0, vf[nt][0], o_acc[nt], 0, 0, 0);
            o_acc[nt] = __builtin_amdgcn_mfma_f32_16x16x32_bf16(ap1, vf[nt][1], o_acc[nt], 0, 0, 0);
        }
    }

#pragma unroll
    for (int nt = 0; nt < 4; nt++)
#pragma unroll
        for (int reg = 0; reg < 4; reg++) {
            const float out = o_acc[nt][reg] / l_i[reg];
            O[base + (size_t)(row0 + w * 16 + quad * 4 + reg) * 1024 +
              nt * 16 + lr] = f2bf(out);
        }
}

// ---------- layernorm over 1024 cols; writes fp32 and/or bf16 ----------
__global__ __launch_bounds__(256) void ln_k(
    const float* __restrict__ X, const float* __restrict__ g,
    const float* __restrict__ bb, float* __restrict__ outf,
    u16* __restrict__ outb) {
    const int row = blockIdx.x, tid = threadIdx.x;
    const float* x = X + (size_t)row * 1024;
    float4 xv = *(const float4*)&x[tid * 4];
    float s = xv.x + xv.y + xv.z + xv.w;
    float s2 = xv.x * xv.x + xv.y * xv.y + xv.z * xv.z + xv.w * xv.w;
#pragma unroll
    for (int msk = 32; msk >= 1; msk >>= 1) {
        s += __shfl_xor(s, msk);
        s2 += __shfl_xor(s2, msk);
    }
    __shared__ float red[8];
    const int wv = tid >> 6;
    if ((tid & 63) == 0) { red[wv] = s; red[wv + 4] = s2; }
    __syncthreads();
    s = red[0] + red[1] + red[2] + red[3];
    s2 = red[4] + red[5] + red[6] + red[7];
    const float mu = s * (1.f / 1024.f);
    float var = s2 * (1.f / 1024.f) - mu * mu;
    var = fmaxf(var, 0.f);
    const float rstd = rsqrtf(var + 1e-5f);
    float4 g4 = *(const float4*)&g[tid * 4];
    float4 b4 = *(const float4*)&bb[tid * 4];
    float o0 = (xv.x - mu) * rstd * g4.x + b4.x;
    float o1 = (xv.y - mu) * rstd * g4.y + b4.y;
    float o2 = (xv.z - mu) * rstd * g4.z + b4.z;
    float o3 = (xv.w - mu) * rstd * g4.w + b4.w;
    if (outf)
        *(float4*)(outf + (size_t)row * 1024 + tid * 4) = make_float4(o0, o1, o2, o3);
    if (outb) {
        ushort4 ov;
        ov.x = f2bf(o0); ov.y = f2bf(o1); ov.z = f2bf(o2); ov.w = f2bf(o3);
        *(ushort4*)(outb + (size_t)row * 1024 + tid * 4) = ov;
    }
}

extern "C" void kernel_launch(void* const* d_in, const int* in_sizes, int n_in,
                              void* d_out, int out_size, void* d_ws, size_t ws_size,
                              hipStream_t stream) {
    const float* tgt = (const float*)d_in[0];
    const float* Wq  = (const float*)d_in[1];
    const float* bq  = (const float*)d_in[2];
    const float* Wk  = (const float*)d_in[3];
    const float* bk  = (const float*)d_in[4];
    const float* Wv  = (const float*)d_in[5];
    const float* bv  = (const float*)d_in[6];
    const float* Wo  = (const float*)d_in[7];
    const float* bo  = (const float*)d_in[8];
    const float* W1  = (const float*)d_in[9];
    const float* b1  = (const float*)d_in[10];
    const float* W2  = (const float*)d_in[11];
    const float* b2  = (const float*)d_in[12];
    const float* g1  = (const float*)d_in[13];
    const float* be1 = (const float*)d_in[14];
    const float* g2  = (const float*)d_in[15];
    const float* be2 = (const float*)d_in[16];
    const float* rA  = (const float*)d_in[17];
    const float* rB  = (const float*)d_in[18];

    const int M = 4096, D = 1024, DFF = 4096;
    const size_t MD = (size_t)M * D;
    const size_t MB = 1u << 20;
    char* wsb = (char*)d_ws;

    // layout (~88.2 MB):
    u16* q    = (u16*)wsb;                 // 8 MB
    u16* kk   = q + MD;
    u16* vv   = kk + MD;
    u16* ctx  = vv + MD;
    u16* h    = q;                         // 32 MB alias (free after Wo gemm)
    float* x1  = (float*)(wsb + 32 * MB);  // 16 MB
    float* sfp = (float*)(wsb + 48 * MB);  // 4 MB
    float* cfp = sfp + (size_t)2048 * 512; // 4 MB
    u16* x1b  = (u16*)sfp;                 // 8 MB alias (free after QKV)
    u16* tgtb = (u16*)(wsb + 56 * MB);     // 8 MB
    u16* Wqt  = (u16*)(wsb + 64 * MB);     // 2 MB each
    u16* Wkt  = (u16*)(wsb + 66 * MB);
    u16* Wvt  = (u16*)(wsb + 68 * MB);
    u16* Wot  = (u16*)(wsb + 70 * MB);
    u16* W1t  = (u16*)(wsb + 72 * MB);     // 8 MB [4096][1024]
    u16* W2t  = (u16*)(wsb + 80 * MB);     // 8 MB [1024][4096]
    float* Pp = (float*)(wsb + 88 * MB);   // 128 KB

    cast_k<<<dim3(4096), dim3(256), 0, stream>>>(tgt, tgtb);
    tcast_k<<<dim3(32, 32),  dim3(256), 0, stream>>>(Wq, Wqt, D, D);
    tcast_k<<<dim3(32, 32),  dim3(256), 0, stream>>>(Wk, Wkt, D, D);
    tcast_k<<<dim3(32, 32),  dim3(256), 0, stream>>>(Wv, Wvt, D, D);
    tcast_k<<<dim3(32, 32),  dim3(256), 0, stream>>>(Wo, Wot, D, D);
    tcast_k<<<dim3(128, 32), dim3(256), 0, stream>>>(W1, W1t, D, DFF);
    tcast_k<<<dim3(32, 128), dim3(256), 0, stream>>>(W2, W2t, DFF, D);
    rope1_k<<<dim3(128), dim3(256), 0, stream>>>(rA, Pp);
    rope2_k<<<dim3(4096), dim3(256), 0, stream>>>(Pp, rB, sfp, cfp);

    mgemm_k<EP_ROPE, true><<<dim3(8, 32), dim3(256), 0, stream>>>(
        tgtb, Wqt, bq, sfp, cfp, nullptr, q, M, D, D);
    mgemm_k<EP_ROPE, true><<<dim3(8, 32), dim3(256), 0, stream>>>(
        tgtb, Wkt, bk, sfp, cfp, nullptr, kk, M, D, D);
    mgemm_k<EP_NONE, true><<<dim3(8, 32), dim3(256), 0, stream>>>(
        tgtb, Wvt, bv, nullptr, nullptr, nullptr, vv, M, D, D);

    mattn_k<<<dim3(32, 32), dim3(256), 0, stream>>>(q, kk, vv, ctx);

    mgemm_k<EP_RES, false><<<dim3(8, 32), dim3(256), 0, stream>>>(
        ctx, Wot, bo, nullptr, nullptr, tgt, x1, M, D, D);
    ln_k<<<dim3(4096), dim3(256), 0, stream>>>(x1, g1, be1, x1, x1b);
    mgemm_k<EP_RELU, true><<<dim3(32, 32), dim3(256), 0, stream>>>(
        x1b, W1t, b1, nullptr, nullptr, nullptr, h, M, DFF, D);
    mgemm_k<EP_RES, false><<<dim3(8, 32), dim3(256), 0, stream>>>(
        h, W2t, b2, nullptr, nullptr, x1, x1, M, D, DFF);
    ln_k<<<dim3(4096), dim3(256), 0, stream>>>(x1, g2, be2, (float*)d_out, nullptr);

    (void)in_sizes; (void)n_in; (void)out_size; (void)ws_size;
}

// Round 5
// 580.937 us; speedup vs baseline: 4.8169x; 1.3134x over previous
//
#include <hip/hip_runtime.h>
#include <math.h>

typedef unsigned short u16;
typedef unsigned int u32;
typedef __attribute__((ext_vector_type(8))) short short8v;
typedef __attribute__((ext_vector_type(4))) float f32x4;

__device__ __forceinline__ u16 f2bf(float f) {
    u32 u = __float_as_uint(f);
    u32 r = (u + 0x7fffu + ((u >> 16) & 1u)) >> 16;
    return (u16)r;
}

// ---------- elementwise fp32 -> bf16 cast ----------
__global__ void cast_k(const float* __restrict__ x, u16* __restrict__ y) {
    const int gid = blockIdx.x * blockDim.x + threadIdx.x;
    float4 v = ((const float4*)x)[gid];
    ushort4 o;
    o.x = f2bf(v.x); o.y = f2bf(v.y); o.z = f2bf(v.z); o.w = f2bf(v.w);
    ((ushort4*)y)[gid] = o;
}

// ---------- transpose + cast: S (KxN fp32) -> Dt (NxK bf16) ----------
__global__ __launch_bounds__(256) void tcast_k(const float* __restrict__ S,
                                               u16* __restrict__ Dt,
                                               int K, int N) {
    __shared__ float tile[32][33];
    const int n0 = blockIdx.x * 32, k0 = blockIdx.y * 32;
    const int tx = threadIdx.x & 31, ty = threadIdx.x >> 5;
#pragma unroll
    for (int i = 0; i < 4; i++)
        tile[ty + 8 * i][tx] = S[(size_t)(k0 + ty + 8 * i) * N + n0 + tx];
    __syncthreads();
#pragma unroll
    for (int i = 0; i < 4; i++)
        Dt[(size_t)(n0 + ty + 8 * i) * K + k0 + tx] = f2bf(tile[tx][ty + 8 * i]);
}

// log2(10000)/512
#define ROPE_LOG2C (13.287712379549449f / 512.0f)

// ---------- RoPE pass 1: P[t][r] = sum_i sin(t*th_i)*A[i][r] + cos(t*th_i)*A[512+i][r]
// block 256 = 16 t x 16 r; each thread computes ONE sin/cos pair per 16-i chunk
// (16x fewer transcendentals than per-(t,r) recompute), shared via LDS broadcast.
__global__ __launch_bounds__(256) void rope1_k(const float* __restrict__ A,
                                               float* __restrict__ P) {
    __shared__ float sc[16][17];
    __shared__ float cc[16][17];
    __shared__ float Als[16][17];
    __shared__ float Alc[16][17];
    const int tid = threadIdx.x;
    const int tt = tid >> 4, rr = tid & 15;
    const int t = blockIdx.x * 16 + tt;
    float acc = 0.f;
    for (int i0 = 0; i0 < 512; i0 += 16) {
        __syncthreads();
        {   // thread (tt,rr) computes sin/cos for (t, i0+rr)
            const int i = i0 + rr;
            const float th = exp2f(-(float)i * ROPE_LOG2C);
            const float ang = (float)t * th;
            sc[tt][rr] = sinf(ang);
            cc[tt][rr] = cosf(ang);
            // stage A chunk (roles coincide: ii=tt, r=rr)
            Als[tt][rr] = A[(i0 + tt) * 16 + rr];
            Alc[tt][rr] = A[(512 + i0 + tt) * 16 + rr];
        }
        __syncthreads();
#pragma unroll
        for (int ii = 0; ii < 16; ++ii)
            acc = fmaf(sc[tt][ii], Als[ii][rr],
                       fmaf(cc[tt][ii], Alc[ii][rr], acc));
    }
    P[t * 16 + rr] = acc;
}

// ---------- RoPE pass 2: sin_f/cos_f (B fp32) ----------
__global__ void rope2_k(const float* __restrict__ P, const float* __restrict__ Bw,
                        float* __restrict__ sf, float* __restrict__ cf) {
    const int gid = blockIdx.x * blockDim.x + threadIdx.x;
    if (gid >= 2048 * 512) return;
    const int t = gid >> 9, i = gid & 511;
    float ls = 0.f, lc = 0.f;
#pragma unroll
    for (int r = 0; r < 16; ++r) {
        const float p = P[t * 16 + r];
        ls = fmaf(p, Bw[r * 1024 + i], ls);
        lc = fmaf(p, Bw[r * 1024 + 512 + i], lc);
    }
    const float th = exp2f(-(float)i * ROPE_LOG2C);
    const float ang = (float)t * th;
    sf[gid] = sinf(ang) + ls;
    cf[gid] = cosf(ang) + lc;
}

// ---------- MFMA GEMM: C(MxN) = A(MxK,bf16) @ Bt(NxK,bf16)^T + epilogue ----------
enum { EP_NONE = 0, EP_RES = 2, EP_RELU = 3 };

template <int EPI, bool CBF>
__global__ __launch_bounds__(256) void mgemm_k(
    const u16* __restrict__ A, const u16* __restrict__ Bt,
    const float* __restrict__ bias, const float* __restrict__ resf,
    void* __restrict__ Cp, int M, int N, int K) {
    __shared__ u16 As[128][40];   // [m][k] bf16, pad +8 (2-way conflicts only)
    __shared__ u16 Bs[128][40];   // [n][k] bf16
    const int tid = threadIdx.x;
    const int w = tid >> 6, l = tid & 63;
    const int quad = l >> 4, lr = l & 15;
    const int wr = w >> 1, wc = w & 1;
    const int m0 = blockIdx.y * 128, n0 = blockIdx.x * 128;
    const int srow = tid >> 1, sseg = (tid & 1) * 16;

    f32x4 acc[4][4];
#pragma unroll
    for (int i = 0; i < 4; i++)
#pragma unroll
        for (int j = 0; j < 4; j++) acc[i][j] = (f32x4)(0.0f);

    const u16* ag = A + (size_t)(m0 + srow) * K + sseg;
    const u16* bg = Bt + (size_t)(n0 + srow) * K + sseg;

    for (int k0 = 0; k0 < K; k0 += 32) {
        __syncthreads();
        uint4 a0 = *(const uint4*)(ag + k0);
        uint4 a1 = *(const uint4*)(ag + k0 + 8);
        uint4 b0 = *(const uint4*)(bg + k0);
        uint4 b1 = *(const uint4*)(bg + k0 + 8);
        *(uint4*)&As[srow][sseg]     = a0;
        *(uint4*)&As[srow][sseg + 8] = a1;
        *(uint4*)&Bs[srow][sseg]     = b0;
        *(uint4*)&Bs[srow][sseg + 8] = b1;
        __syncthreads();
        short8v af[4], bf[4];
#pragma unroll
        for (int mt = 0; mt < 4; ++mt)
            af[mt] = *(const short8v*)&As[wr * 64 + mt * 16 + lr][quad * 8];
#pragma unroll
        for (int nt = 0; nt < 4; ++nt)
            bf[nt] = *(const short8v*)&Bs[wc * 64 + nt * 16 + lr][quad * 8];
#pragma unroll
        for (int mt = 0; mt < 4; ++mt)
#pragma unroll
            for (int nt = 0; nt < 4; ++nt)
                acc[mt][nt] = __builtin_amdgcn_mfma_f32_16x16x32_bf16(
                    af[mt], bf[nt], acc[mt][nt], 0, 0, 0);
    }

#pragma unroll
    for (int mt = 0; mt < 4; ++mt) {
#pragma unroll
        for (int nt = 0; nt < 4; ++nt) {
            const int n = n0 + wc * 64 + nt * 16 + lr;
            const float bb = bias[n];
#pragma unroll
            for (int reg = 0; reg < 4; ++reg) {
                const int m = m0 + wr * 64 + mt * 16 + quad * 4 + reg;
                float v = acc[mt][nt][reg] + bb;
                if (EPI == EP_RES) v += resf[(size_t)m * N + n];
                if (EPI == EP_RELU) v = fmaxf(v, 0.f);
                if (CBF) ((u16*)Cp)[(size_t)m * N + n] = f2bf(v);
                else     ((float*)Cp)[(size_t)m * N + n] = v;
            }
        }
    }
}

// ---------- merged QKV GEMM: N=3072 over [Wqt|Wkt|Wvt], RoPE on Q/K ----------
__global__ __launch_bounds__(256) void mqkv_k(
    const u16* __restrict__ A, const u16* __restrict__ Bt,
    const float* __restrict__ bq, const float* __restrict__ bk,
    const float* __restrict__ bv, const float* __restrict__ sf,
    const float* __restrict__ cf, u16* __restrict__ out) {
    const int K = 1024;
    __shared__ u16 As[128][40];
    __shared__ u16 Bs[128][40];
    const int tid = threadIdx.x;
    const int w = tid >> 6, l = tid & 63;
    const int quad = l >> 4, lr = l & 15;
    const int wr = w >> 1, wc = w & 1;
    const int m0 = blockIdx.y * 128, n0 = blockIdx.x * 128;
    const int srow = tid >> 1, sseg = (tid & 1) * 16;

    f32x4 acc[4][4];
#pragma unroll
    for (int i = 0; i < 4; i++)
#pragma unroll
        for (int j = 0; j < 4; j++) acc[i][j] = (f32x4)(0.0f);

    const u16* ag = A + (size_t)(m0 + srow) * K + sseg;
    const u16* bg = Bt + (size_t)(n0 + srow) * K + sseg;

    for (int k0 = 0; k0 < K; k0 += 32) {
        __syncthreads();
        uint4 a0 = *(const uint4*)(ag + k0);
        uint4 a1 = *(const uint4*)(ag + k0 + 8);
        uint4 b0 = *(const uint4*)(bg + k0);
        uint4 b1 = *(const uint4*)(bg + k0 + 8);
        *(uint4*)&As[srow][sseg]     = a0;
        *(uint4*)&As[srow][sseg + 8] = a1;
        *(uint4*)&Bs[srow][sseg]     = b0;
        *(uint4*)&Bs[srow][sseg + 8] = b1;
        __syncthreads();
        short8v af[4], bf[4];
#pragma unroll
        for (int mt = 0; mt < 4; ++mt)
            af[mt] = *(const short8v*)&As[wr * 64 + mt * 16 + lr][quad * 8];
#pragma unroll
        for (int nt = 0; nt < 4; ++nt)
            bf[nt] = *(const short8v*)&Bs[wc * 64 + nt * 16 + lr][quad * 8];
#pragma unroll
        for (int mt = 0; mt < 4; ++mt)
#pragma unroll
            for (int nt = 0; nt < 4; ++nt)
                acc[mt][nt] = __builtin_amdgcn_mfma_f32_16x16x32_bf16(
                    af[mt], bf[nt], acc[mt][nt], 0, 0, 0);
    }

    // block-uniform segment select (1024-boundaries align with 128-tiles)
    const int which = n0 >> 10;
    const float* bias = which == 0 ? bq : (which == 1 ? bk : bv);
    const bool doRope = which < 2;
    u16* Cp = out + (size_t)which * 4096 * 1024;

#pragma unroll
    for (int mt = 0; mt < 4; ++mt) {
#pragma unroll
        for (int nt = 0; nt < 4; ++nt) {
            const int n = n0 + wc * 64 + nt * 16 + lr;
            const int col = n & 1023;
            const float bb = bias[col];
#pragma unroll
            for (int reg = 0; reg < 4; ++reg) {
                const int m = m0 + wr * 64 + mt * 16 + quad * 4 + reg;
                float v = acc[mt][nt][reg] + bb;
                const float partner = __shfl_xor(v, 1);
                if (doRope) {
                    const int t = m & 2047;
                    const int fi = col >> 1;
                    const float svv = sf[t * 512 + fi];
                    const float cvv = cf[t * 512 + fi];
                    v = (col & 1) ? fmaf(partner, svv, v * cvv)
                                  : fmaf(v, cvv, -partner * svv);
                }
                Cp[(size_t)m * 1024 + col] = f2bf(v);
            }
        }
    }
}

// ---------- MFMA flash attention ----------
// grid (T/64, B*H), block 256 (4 waves, 16 q-rows each). Q/K/V/O bf16 [B*T][1024].
__global__ __launch_bounds__(256) void mattn_k(
    const u16* __restrict__ Q, const u16* __restrict__ Kg,
    const u16* __restrict__ Vg, u16* __restrict__ O) {
    __shared__ u16 Qs[64][72];
    __shared__ u16 Ks[64][72];
    __shared__ u16 Ps[4][16][72];
    const int tid = threadIdx.x;
    const int w = tid >> 6, l = tid & 63;
    const int quad = l >> 4, lr = l & 15;
    const int bh = blockIdx.y, b = bh >> 4, h = bh & 15;
    const int row0 = blockIdx.x * 64;
    const size_t base = (size_t)b * 2048 * 1024 + (size_t)h * 64;

    {
        const int r = tid >> 2, seg = (tid & 3) * 16;
        const u16* qp = Q + base + (size_t)(row0 + r) * 1024 + seg;
        *(uint4*)&Qs[r][seg]     = *(const uint4*)qp;
        *(uint4*)&Qs[r][seg + 8] = *(const uint4*)(qp + 8);
    }
    __syncthreads();
    const short8v aq0 = *(const short8v*)&Qs[w * 16 + lr][quad * 8];
    const short8v aq1 = *(const short8v*)&Qs[w * 16 + lr][32 + quad * 8];

    float m_i[4], l_i[4];
    f32x4 o_acc[4];
#pragma unroll
    for (int r = 0; r < 4; r++) { m_i[r] = -INFINITY; l_i[r] = 0.f; }
#pragma unroll
    for (int nt = 0; nt < 4; nt++) o_acc[nt] = (f32x4)(0.0f);

    for (int kc = 0; kc < 2048; kc += 64) {
        __syncthreads();
        {
            const int r = tid >> 2, seg = (tid & 3) * 16;
            const u16* kp = Kg + base + (size_t)(kc + r) * 1024 + seg;
            *(uint4*)&Ks[r][seg]     = *(const uint4*)kp;
            *(uint4*)&Ks[r][seg + 8] = *(const uint4*)(kp + 8);
        }
        __syncthreads();

        f32x4 s[4];
#pragma unroll
        for (int nt = 0; nt < 4; nt++) s[nt] = (f32x4)(0.0f);
#pragma unroll
        for (int nt = 0; nt < 4; nt++) {
            short8v bk0 = *(const short8v*)&Ks[nt * 16 + lr][quad * 8];
            short8v bk1 = *(const short8v*)&Ks[nt * 16 + lr][32 + quad * 8];
            s[nt] = __builtin_amdgcn_mfma_f32_16x16x32_bf16(aq0, bk0, s[nt], 0, 0, 0);
            s[nt] = __builtin_amdgcn_mfma_f32_16x16x32_bf16(aq1, bk1, s[nt], 0, 0, 0);
        }

        short8v vf[4][2];
#pragma unroll
        for (int nt = 0; nt < 4; nt++)
#pragma unroll
            for (int kkh = 0; kkh < 2; kkh++) {
                short8v t;
#pragma unroll
                for (int j = 0; j < 8; j++)
                    t[j] = (short)Vg[base +
                        (size_t)(kc + kkh * 32 + quad * 8 + j) * 1024 +
                        nt * 16 + lr];
                vf[nt][kkh] = t;
            }

        float p[4][4];
        float alpha[4];
#pragma unroll
        for (int reg = 0; reg < 4; reg++) {
            float sv0 = s[0][reg] * 0.125f, sv1 = s[1][reg] * 0.125f;
            float sv2 = s[2][reg] * 0.125f, sv3 = s[3][reg] * 0.125f;
            float rm = fmaxf(fmaxf(sv0, sv1), fmaxf(sv2, sv3));
            rm = fmaxf(rm, __shfl_xor(rm, 1));
            rm = fmaxf(rm, __shfl_xor(rm, 2));
            rm = fmaxf(rm, __shfl_xor(rm, 4));
            rm = fmaxf(rm, __shfl_xor(rm, 8));
            const float mnew = fmaxf(m_i[reg], rm);
            alpha[reg] = __expf(m_i[reg] - mnew);
            m_i[reg] = mnew;
            p[0][reg] = __expf(sv0 - mnew);
            p[1][reg] = __expf(sv1 - mnew);
            p[2][reg] = __expf(sv2 - mnew);
            p[3][reg] = __expf(sv3 - mnew);
            float rs = p[0][reg] + p[1][reg] + p[2][reg] + p[3][reg];
            rs += __shfl_xor(rs, 1);
            rs += __shfl_xor(rs, 2);
            rs += __shfl_xor(rs, 4);
            rs += __shfl_xor(rs, 8);
            l_i[reg] = l_i[reg] * alpha[reg] + rs;
        }
#pragma unroll
        for (int nt = 0; nt < 4; nt++) {
#pragma unroll
            for (int reg = 0; reg < 4; reg++) {
                o_acc[nt][reg] *= alpha[reg];
                Ps[w][quad * 4 + reg][nt * 16 + lr] = f2bf(p[nt][reg]);
            }
        }
        const short8v ap0 = *(const short8v*)&Ps[w][lr][quad * 8];
        const short8v ap1 = *(const short8v*)&Ps[w][lr][32 + quad * 8];
#pragma unroll
        for (int nt = 0; nt < 4; nt++) {
            o_acc[nt] = __builtin_amdgcn_mfma_f32_16x16x32_bf16(ap0, vf[nt][0], o_acc[nt], 0, 0, 0);
            o_acc[nt] = __builtin_amdgcn_mfma_f32_16x16x32_bf16(ap1, vf[nt][1], o_acc[nt], 0, 0, 0);
        }
    }

#pragma unroll
    for (int nt = 0; nt < 4; nt++)
#pragma unroll
        for (int reg = 0; reg < 4; reg++) {
            const float out = o_acc[nt][reg] / l_i[reg];
            O[base + (size_t)(row0 + w * 16 + quad * 4 + reg) * 1024 +
              nt * 16 + lr] = f2bf(out);
        }
}

// ---------- layernorm over 1024 cols; writes fp32 and/or bf16 ----------
__global__ __launch_bounds__(256) void ln_k(
    const float* __restrict__ X, const float* __restrict__ g,
    const float* __restrict__ bb, float* __restrict__ outf,
    u16* __restrict__ outb) {
    const int row = blockIdx.x, tid = threadIdx.x;
    const float* x = X + (size_t)row * 1024;
    float4 xv = *(const float4*)&x[tid * 4];
    float s = xv.x + xv.y + xv.z + xv.w;
    float s2 = xv.x * xv.x + xv.y * xv.y + xv.z * xv.z + xv.w * xv.w;
#pragma unroll
    for (int msk = 32; msk >= 1; msk >>= 1) {
        s += __shfl_xor(s, msk);
        s2 += __shfl_xor(s2, msk);
    }
    __shared__ float red[8];
    const int wv = tid >> 6;
    if ((tid & 63) == 0) { red[wv] = s; red[wv + 4] = s2; }
    __syncthreads();
    s = red[0] + red[1] + red[2] + red[3];
    s2 = red[4] + red[5] + red[6] + red[7];
    const float mu = s * (1.f / 1024.f);
    float var = s2 * (1.f / 1024.f) - mu * mu;
    var = fmaxf(var, 0.f);
    const float rstd = rsqrtf(var + 1e-5f);
    float4 g4 = *(const float4*)&g[tid * 4];
    float4 b4 = *(const float4*)&bb[tid * 4];
    float o0 = (xv.x - mu) * rstd * g4.x + b4.x;
    float o1 = (xv.y - mu) * rstd * g4.y + b4.y;
    float o2 = (xv.z - mu) * rstd * g4.z + b4.z;
    float o3 = (xv.w - mu) * rstd * g4.w + b4.w;
    if (outf)
        *(float4*)(outf + (size_t)row * 1024 + tid * 4) = make_float4(o0, o1, o2, o3);
    if (outb) {
        ushort4 ov;
        ov.x = f2bf(o0); ov.y = f2bf(o1); ov.z = f2bf(o2); ov.w = f2bf(o3);
        *(ushort4*)(outb + (size_t)row * 1024 + tid * 4) = ov;
    }
}

extern "C" void kernel_launch(void* const* d_in, const int* in_sizes, int n_in,
                              void* d_out, int out_size, void* d_ws, size_t ws_size,
                              hipStream_t stream) {
    const float* tgt = (const float*)d_in[0];
    const float* Wq  = (const float*)d_in[1];
    const float* bq  = (const float*)d_in[2];
    const float* Wk  = (const float*)d_in[3];
    const float* bk  = (const float*)d_in[4];
    const float* Wv  = (const float*)d_in[5];
    const float* bv  = (const float*)d_in[6];
    const float* Wo  = (const float*)d_in[7];
    const float* bo  = (const float*)d_in[8];
    const float* W1  = (const float*)d_in[9];
    const float* b1  = (const float*)d_in[10];
    const float* W2  = (const float*)d_in[11];
    const float* b2  = (const float*)d_in[12];
    const float* g1  = (const float*)d_in[13];
    const float* be1 = (const float*)d_in[14];
    const float* g2  = (const float*)d_in[15];
    const float* be2 = (const float*)d_in[16];
    const float* rA  = (const float*)d_in[17];
    const float* rB  = (const float*)d_in[18];

    const int M = 4096, D = 1024, DFF = 4096;
    const size_t MD = (size_t)M * D;
    const size_t MB = 1u << 20;
    char* wsb = (char*)d_ws;

    u16* q    = (u16*)wsb;                 // q,kk,vv,ctx: 8 MB each
    u16* vv   = q + 2 * MD;
    u16* ctx  = q + 3 * MD;
    u16* h    = q;                         // 32 MB alias (free after Wo gemm)
    float* x1  = (float*)(wsb + 32 * MB);  // 16 MB
    float* sfp = (float*)(wsb + 48 * MB);  // 4 MB
    float* cfp = sfp + (size_t)2048 * 512; // 4 MB
    u16* x1b  = (u16*)sfp;                 // 8 MB alias (free after QKV)
    u16* tgtb = (u16*)(wsb + 56 * MB);     // 8 MB
    u16* Wqt  = (u16*)(wsb + 64 * MB);     // 2 MB each; Wqt|Wkt|Wvt contiguous
    u16* Wkt  = (u16*)(wsb + 66 * MB);
    u16* Wvt  = (u16*)(wsb + 68 * MB);
    u16* Wot  = (u16*)(wsb + 70 * MB);
    u16* W1t  = (u16*)(wsb + 72 * MB);     // 8 MB [4096][1024]
    u16* W2t  = (u16*)(wsb + 80 * MB);     // 8 MB [1024][4096]
    float* Pp = (float*)(wsb + 88 * MB);   // 128 KB

    cast_k<<<dim3(4096), dim3(256), 0, stream>>>(tgt, tgtb);
    tcast_k<<<dim3(32, 32),  dim3(256), 0, stream>>>(Wq, Wqt, D, D);
    tcast_k<<<dim3(32, 32),  dim3(256), 0, stream>>>(Wk, Wkt, D, D);
    tcast_k<<<dim3(32, 32),  dim3(256), 0, stream>>>(Wv, Wvt, D, D);
    tcast_k<<<dim3(32, 32),  dim3(256), 0, stream>>>(Wo, Wot, D, D);
    tcast_k<<<dim3(128, 32), dim3(256), 0, stream>>>(W1, W1t, D, DFF);
    tcast_k<<<dim3(32, 128), dim3(256), 0, stream>>>(W2, W2t, DFF, D);
    rope1_k<<<dim3(128), dim3(256), 0, stream>>>(rA, Pp);
    rope2_k<<<dim3(4096), dim3(256), 0, stream>>>(Pp, rB, sfp, cfp);

    mqkv_k<<<dim3(24, 32), dim3(256), 0, stream>>>(
        tgtb, Wqt, bq, bk, bv, sfp, cfp, q);

    mattn_k<<<dim3(32, 32), dim3(256), 0, stream>>>(q, q + MD, vv, ctx);

    mgemm_k<EP_RES, false><<<dim3(8, 32), dim3(256), 0, stream>>>(
        ctx, Wot, bo, tgt, x1, M, D, D);
    ln_k<<<dim3(4096), dim3(256), 0, stream>>>(x1, g1, be1, x1, x1b);
    mgemm_k<EP_RELU, true><<<dim3(32, 32), dim3(256), 0, stream>>>(
        x1b, W1t, b1, nullptr, h, M, DFF, D);
    mgemm_k<EP_RES, false><<<dim3(8, 32), dim3(256), 0, stream>>>(
        h, W2t, b2, x1, x1, M, D, DFF);
    ln_k<<<dim3(4096), dim3(256), 0, stream>>>(x1, g2, be2, (float*)d_out, nullptr);

    (void)in_sizes; (void)n_in; (void)out_size; (void)ws_size;
}

// Round 6
// 570.797 us; speedup vs baseline: 4.9025x; 1.0178x over previous
//
#include <hip/hip_runtime.h>
#include <math.h>

typedef unsigned short u16;
typedef unsigned int u32;
typedef __attribute__((ext_vector_type(8))) short short8v;
typedef __attribute__((ext_vector_type(4))) float f32x4;

__device__ __forceinline__ u16 f2bf(float f) {
    u32 u = __float_as_uint(f);
    u32 r = (u + 0x7fffu + ((u >> 16) & 1u)) >> 16;
    return (u16)r;
}

// async global->LDS DMA, 16 B per lane; lds dst = wave-uniform base + lane*16
#define GLOAD_LDS(g, l)                                                        \
    __builtin_amdgcn_global_load_lds(                                          \
        (const __attribute__((address_space(1))) void*)(g),                    \
        (__attribute__((address_space(3))) void*)(l), 16, 0, 0)

// ---------- elementwise fp32 -> bf16 cast ----------
__global__ void cast_k(const float* __restrict__ x, u16* __restrict__ y) {
    const int gid = blockIdx.x * blockDim.x + threadIdx.x;
    float4 v = ((const float4*)x)[gid];
    ushort4 o;
    o.x = f2bf(v.x); o.y = f2bf(v.y); o.z = f2bf(v.z); o.w = f2bf(v.w);
    ((ushort4*)y)[gid] = o;
}

// ---------- transpose + cast: S (KxN fp32) -> Dt (NxK bf16) ----------
__global__ __launch_bounds__(256) void tcast_k(const float* __restrict__ S,
                                               u16* __restrict__ Dt,
                                               int K, int N) {
    __shared__ float tile[32][33];
    const int n0 = blockIdx.x * 32, k0 = blockIdx.y * 32;
    const int tx = threadIdx.x & 31, ty = threadIdx.x >> 5;
#pragma unroll
    for (int i = 0; i < 4; i++)
        tile[ty + 8 * i][tx] = S[(size_t)(k0 + ty + 8 * i) * N + n0 + tx];
    __syncthreads();
#pragma unroll
    for (int i = 0; i < 4; i++)
        Dt[(size_t)(n0 + ty + 8 * i) * K + k0 + tx] = f2bf(tile[tx][ty + 8 * i]);
}

// log2(10000)/512
#define ROPE_LOG2C (13.287712379549449f / 512.0f)

// ---------- RoPE pass 1 (LDS-shared transcendentals) ----------
__global__ __launch_bounds__(256) void rope1_k(const float* __restrict__ A,
                                               float* __restrict__ P) {
    __shared__ float sc[16][17];
    __shared__ float cc[16][17];
    __shared__ float Als[16][17];
    __shared__ float Alc[16][17];
    const int tid = threadIdx.x;
    const int tt = tid >> 4, rr = tid & 15;
    const int t = blockIdx.x * 16 + tt;
    float acc = 0.f;
    for (int i0 = 0; i0 < 512; i0 += 16) {
        __syncthreads();
        {
            const int i = i0 + rr;
            const float th = exp2f(-(float)i * ROPE_LOG2C);
            const float ang = (float)t * th;
            sc[tt][rr] = sinf(ang);
            cc[tt][rr] = cosf(ang);
            Als[tt][rr] = A[(i0 + tt) * 16 + rr];
            Alc[tt][rr] = A[(512 + i0 + tt) * 16 + rr];
        }
        __syncthreads();
#pragma unroll
        for (int ii = 0; ii < 16; ++ii)
            acc = fmaf(sc[tt][ii], Als[ii][rr],
                       fmaf(cc[tt][ii], Alc[ii][rr], acc));
    }
    P[t * 16 + rr] = acc;
}

// ---------- RoPE pass 2 ----------
__global__ void rope2_k(const float* __restrict__ P, const float* __restrict__ Bw,
                        float* __restrict__ sf, float* __restrict__ cf) {
    const int gid = blockIdx.x * blockDim.x + threadIdx.x;
    if (gid >= 2048 * 512) return;
    const int t = gid >> 9, i = gid & 511;
    float ls = 0.f, lc = 0.f;
#pragma unroll
    for (int r = 0; r < 16; ++r) {
        const float p = P[t * 16 + r];
        ls = fmaf(p, Bw[r * 1024 + i], ls);
        lc = fmaf(p, Bw[r * 1024 + 512 + i], lc);
    }
    const float th = exp2f(-(float)i * ROPE_LOG2C);
    const float ang = (float)t * th;
    sf[gid] = sinf(ang) + ls;
    cf[gid] = cosf(ang) + lc;
}

// ---------- MFMA GEMM with global_load_lds staging ----------
enum { EP_NONE = 0, EP_RES = 2, EP_RELU = 3 };

template <int EPI, bool CBF>
__global__ __launch_bounds__(256) void mgemm_k(
    const u16* __restrict__ A, const u16* __restrict__ Bt,
    const float* __restrict__ bias, const float* __restrict__ resf,
    void* __restrict__ Cp, int M, int N, int K) {
    __shared__ u16 As[128 * 32];   // [m][k] unpadded (DMA layout)
    __shared__ u16 Bs[128 * 32];   // [n][k]
    const int tid = threadIdx.x;
    const int w = tid >> 6, l = tid & 63;
    const int quad = l >> 4, lr = l & 15;
    const int wr = w >> 1, wc = w & 1;
    const int m0 = blockIdx.y * 128, n0 = blockIdx.x * 128;

    // DMA slot mapping: lane dst = wave_base + lane*16B -> row = w*16 + (l>>2),
    // col chunk = (l&3)*8 u16; round 1 covers rows 64..127.
    const int srow = w * 16 + (l >> 2);
    const int scol = (l & 3) * 8;
    const u16* ag0 = A + (size_t)(m0 + srow) * K + scol;
    const u16* ag1 = A + (size_t)(m0 + 64 + srow) * K + scol;
    const u16* bg0 = Bt + (size_t)(n0 + srow) * K + scol;
    const u16* bg1 = Bt + (size_t)(n0 + 64 + srow) * K + scol;
    u16* lA0 = As + w * 512;
    u16* lA1 = As + 2048 + w * 512;
    u16* lB0 = Bs + w * 512;
    u16* lB1 = Bs + 2048 + w * 512;

    f32x4 acc[4][4];
#pragma unroll
    for (int i = 0; i < 4; i++)
#pragma unroll
        for (int j = 0; j < 4; j++) acc[i][j] = (f32x4)(0.0f);

    for (int k0 = 0; k0 < K; k0 += 32) {
        __syncthreads();
        GLOAD_LDS(ag0 + k0, lA0);
        GLOAD_LDS(ag1 + k0, lA1);
        GLOAD_LDS(bg0 + k0, lB0);
        GLOAD_LDS(bg1 + k0, lB1);
        __syncthreads();
        short8v af[4], bf[4];
#pragma unroll
        for (int mt = 0; mt < 4; ++mt)
            af[mt] = *(const short8v*)&As[(wr * 64 + mt * 16 + lr) * 32 + quad * 8];
#pragma unroll
        for (int nt = 0; nt < 4; ++nt)
            bf[nt] = *(const short8v*)&Bs[(wc * 64 + nt * 16 + lr) * 32 + quad * 8];
#pragma unroll
        for (int mt = 0; mt < 4; ++mt)
#pragma unroll
            for (int nt = 0; nt < 4; ++nt)
                acc[mt][nt] = __builtin_amdgcn_mfma_f32_16x16x32_bf16(
                    af[mt], bf[nt], acc[mt][nt], 0, 0, 0);
    }

#pragma unroll
    for (int mt = 0; mt < 4; ++mt) {
#pragma unroll
        for (int nt = 0; nt < 4; ++nt) {
            const int n = n0 + wc * 64 + nt * 16 + lr;
            const float bb = bias[n];
#pragma unroll
            for (int reg = 0; reg < 4; ++reg) {
                const int m = m0 + wr * 64 + mt * 16 + quad * 4 + reg;
                float v = acc[mt][nt][reg] + bb;
                if (EPI == EP_RES) v += resf[(size_t)m * N + n];
                if (EPI == EP_RELU) v = fmaxf(v, 0.f);
                if (CBF) ((u16*)Cp)[(size_t)m * N + n] = f2bf(v);
                else     ((float*)Cp)[(size_t)m * N + n] = v;
            }
        }
    }
}

// ---------- merged QKV GEMM (N=3072 over [Wqt|Wkt|Wvt]), RoPE on Q/K ----------
__global__ __launch_bounds__(256) void mqkv_k(
    const u16* __restrict__ A, const u16* __restrict__ Bt,
    const float* __restrict__ bq, const float* __restrict__ bk,
    const float* __restrict__ bv, const float* __restrict__ sf,
    const float* __restrict__ cf, u16* __restrict__ out) {
    const int K = 1024;
    __shared__ u16 As[128 * 32];
    __shared__ u16 Bs[128 * 32];
    const int tid = threadIdx.x;
    const int w = tid >> 6, l = tid & 63;
    const int quad = l >> 4, lr = l & 15;
    const int wr = w >> 1, wc = w & 1;
    const int m0 = blockIdx.y * 128, n0 = blockIdx.x * 128;

    const int srow = w * 16 + (l >> 2);
    const int scol = (l & 3) * 8;
    const u16* ag0 = A + (size_t)(m0 + srow) * K + scol;
    const u16* ag1 = A + (size_t)(m0 + 64 + srow) * K + scol;
    const u16* bg0 = Bt + (size_t)(n0 + srow) * K + scol;
    const u16* bg1 = Bt + (size_t)(n0 + 64 + srow) * K + scol;
    u16* lA0 = As + w * 512;
    u16* lA1 = As + 2048 + w * 512;
    u16* lB0 = Bs + w * 512;
    u16* lB1 = Bs + 2048 + w * 512;

    f32x4 acc[4][4];
#pragma unroll
    for (int i = 0; i < 4; i++)
#pragma unroll
        for (int j = 0; j < 4; j++) acc[i][j] = (f32x4)(0.0f);

    for (int k0 = 0; k0 < K; k0 += 32) {
        __syncthreads();
        GLOAD_LDS(ag0 + k0, lA0);
        GLOAD_LDS(ag1 + k0, lA1);
        GLOAD_LDS(bg0 + k0, lB0);
        GLOAD_LDS(bg1 + k0, lB1);
        __syncthreads();
        short8v af[4], bf[4];
#pragma unroll
        for (int mt = 0; mt < 4; ++mt)
            af[mt] = *(const short8v*)&As[(wr * 64 + mt * 16 + lr) * 32 + quad * 8];
#pragma unroll
        for (int nt = 0; nt < 4; ++nt)
            bf[nt] = *(const short8v*)&Bs[(wc * 64 + nt * 16 + lr) * 32 + quad * 8];
#pragma unroll
        for (int mt = 0; mt < 4; ++mt)
#pragma unroll
            for (int nt = 0; nt < 4; ++nt)
                acc[mt][nt] = __builtin_amdgcn_mfma_f32_16x16x32_bf16(
                    af[mt], bf[nt], acc[mt][nt], 0, 0, 0);
    }

    const int which = n0 >> 10;  // block-uniform (1024-boundaries align)
    const float* bias = which == 0 ? bq : (which == 1 ? bk : bv);
    const bool doRope = which < 2;
    u16* Cp = out + (size_t)which * 4096 * 1024;

#pragma unroll
    for (int mt = 0; mt < 4; ++mt) {
#pragma unroll
        for (int nt = 0; nt < 4; ++nt) {
            const int n = n0 + wc * 64 + nt * 16 + lr;
            const int col = n & 1023;
            const float bb = bias[col];
#pragma unroll
            for (int reg = 0; reg < 4; ++reg) {
                const int m = m0 + wr * 64 + mt * 16 + quad * 4 + reg;
                float v = acc[mt][nt][reg] + bb;
                const float partner = __shfl_xor(v, 1);
                if (doRope) {
                    const int t = m & 2047;
                    const int fi = col >> 1;
                    const float svv = sf[t * 512 + fi];
                    const float cvv = cf[t * 512 + fi];
                    v = (col & 1) ? fmaf(partner, svv, v * cvv)
                                  : fmaf(v, cvv, -partner * svv);
                }
                Cp[(size_t)m * 1024 + col] = f2bf(v);
            }
        }
    }
}

// ---------- MFMA flash attention (V staged transposed in LDS) ----------
__global__ __launch_bounds__(256) void mattn_k(
    const u16* __restrict__ Q, const u16* __restrict__ Kg,
    const u16* __restrict__ Vg, u16* __restrict__ O) {
    __shared__ u16 Qs[64][72];
    __shared__ u16 Ks[64][72];
    __shared__ u16 VsT[64][72];   // [d][key]
    __shared__ u16 Ps[4][16][72];
    const int tid = threadIdx.x;
    const int w = tid >> 6, l = tid & 63;
    const int quad = l >> 4, lr = l & 15;
    const int bh = blockIdx.y, b = bh >> 4, h = bh & 15;
    const int row0 = blockIdx.x * 64;
    const size_t base = (size_t)b * 2048 * 1024 + (size_t)h * 64;

    {
        const int r = tid >> 2, seg = (tid & 3) * 16;
        const u16* qp = Q + base + (size_t)(row0 + r) * 1024 + seg;
        *(uint4*)&Qs[r][seg]     = *(const uint4*)qp;
        *(uint4*)&Qs[r][seg + 8] = *(const uint4*)(qp + 8);
    }
    __syncthreads();
    const short8v aq0 = *(const short8v*)&Qs[w * 16 + lr][quad * 8];
    const short8v aq1 = *(const short8v*)&Qs[w * 16 + lr][32 + quad * 8];

    float m_i[4], l_i[4];
    f32x4 o_acc[4];
#pragma unroll
    for (int r = 0; r < 4; r++) { m_i[r] = -INFINITY; l_i[r] = 0.f; }
#pragma unroll
    for (int nt = 0; nt < 4; nt++) o_acc[nt] = (f32x4)(0.0f);

    for (int kc = 0; kc < 2048; kc += 64) {
        __syncthreads();
        {
            const int r = tid >> 2, seg = (tid & 3) * 16;
            const u16* kp = Kg + base + (size_t)(kc + r) * 1024 + seg;
            *(uint4*)&Ks[r][seg]     = *(const uint4*)kp;
            *(uint4*)&Ks[r][seg + 8] = *(const uint4*)(kp + 8);
            // V: coalesced load, transposed scatter into VsT[d][key]
            const u16* vp = Vg + base + (size_t)(kc + r) * 1024 + seg;
            uint4 v0 = *(const uint4*)vp;
            uint4 v1 = *(const uint4*)(vp + 8);
            u16 tmp[16];
            *(uint4*)tmp = v0; *(uint4*)(tmp + 8) = v1;
#pragma unroll
            for (int j = 0; j < 16; ++j) VsT[seg + j][r] = tmp[j];
        }
        __syncthreads();

        f32x4 s[4];
#pragma unroll
        for (int nt = 0; nt < 4; nt++) s[nt] = (f32x4)(0.0f);
#pragma unroll
        for (int nt = 0; nt < 4; nt++) {
            short8v bk0 = *(const short8v*)&Ks[nt * 16 + lr][quad * 8];
            short8v bk1 = *(const short8v*)&Ks[nt * 16 + lr][32 + quad * 8];
            s[nt] = __builtin_amdgcn_mfma_f32_16x16x32_bf16(aq0, bk0, s[nt], 0, 0, 0);
            s[nt] = __builtin_amdgcn_mfma_f32_16x16x32_bf16(aq1, bk1, s[nt], 0, 0, 0);
        }

        float p[4][4];
        float alpha[4];
#pragma unroll
        for (int reg = 0; reg < 4; reg++) {
            float sv0 = s[0][reg] * 0.125f, sv1 = s[1][reg] * 0.125f;
            float sv2 = s[2][reg] * 0.125f, sv3 = s[3][reg] * 0.125f;
            float rm = fmaxf(fmaxf(sv0, sv1), fmaxf(sv2, sv3));
            rm = fmaxf(rm, __shfl_xor(rm, 1));
            rm = fmaxf(rm, __shfl_xor(rm, 2));
            rm = fmaxf(rm, __shfl_xor(rm, 4));
            rm = fmaxf(rm, __shfl_xor(rm, 8));
            const float mnew = fmaxf(m_i[reg], rm);
            alpha[reg] = __expf(m_i[reg] - mnew);
            m_i[reg] = mnew;
            p[0][reg] = __expf(sv0 - mnew);
            p[1][reg] = __expf(sv1 - mnew);
            p[2][reg] = __expf(sv2 - mnew);
            p[3][reg] = __expf(sv3 - mnew);
            float rs = p[0][reg] + p[1][reg] + p[2][reg] + p[3][reg];
            rs += __shfl_xor(rs, 1);
            rs += __shfl_xor(rs, 2);
            rs += __shfl_xor(rs, 4);
            rs += __shfl_xor(rs, 8);
            l_i[reg] = l_i[reg] * alpha[reg] + rs;
        }
#pragma unroll
        for (int nt = 0; nt < 4; nt++) {
#pragma unroll
            for (int reg = 0; reg < 4; reg++) {
                o_acc[nt][reg] *= alpha[reg];
                Ps[w][quad * 4 + reg][nt * 16 + lr] = f2bf(p[nt][reg]);
            }
        }
        // P: C-layout -> A-layout (wave-local LDS round-trip, no barrier)
        const short8v ap0 = *(const short8v*)&Ps[w][lr][quad * 8];
        const short8v ap1 = *(const short8v*)&Ps[w][lr][32 + quad * 8];
#pragma unroll
        for (int nt = 0; nt < 4; nt++) {
            short8v vf0 = *(const short8v*)&VsT[nt * 16 + lr][quad * 8];
            short8v vf1 = *(const short8v*)&VsT[nt * 16 + lr][32 + quad * 8];
            o_acc[nt] = __builtin_amdgcn_mfma_f32_16x16x32_bf16(ap0, vf0, o_acc[nt], 0, 0, 0);
            o_acc[nt] = __builtin_amdgcn_mfma_f32_16x16x32_bf16(ap1, vf1, o_acc[nt], 0, 0, 0);
        }
    }

#pragma unroll
    for (int nt = 0; nt < 4; nt++)
#pragma unroll
        for (int reg = 0; reg < 4; reg++) {
            const float out = o_acc[nt][reg] / l_i[reg];
            O[base + (size_t)(row0 + w * 16 + quad * 4 + reg) * 1024 +
              nt * 16 + lr] = f2bf(out);
        }
}

// ---------- layernorm over 1024 cols; writes fp32 and/or bf16 ----------
__global__ __launch_bounds__(256) void ln_k(
    const float* __restrict__ X, const float* __restrict__ g,
    const float* __restrict__ bb, float* __restrict__ outf,
    u16* __restrict__ outb) {
    const int row = blockIdx.x, tid = threadIdx.x;
    const float* x = X + (size_t)row * 1024;
    float4 xv = *(const float4*)&x[tid * 4];
    float s = xv.x + xv.y + xv.z + xv.w;
    float s2 = xv.x * xv.x + xv.y * xv.y + xv.z * xv.z + xv.w * xv.w;
#pragma unroll
    for (int msk = 32; msk >= 1; msk >>= 1) {
        s += __shfl_xor(s, msk);
        s2 += __shfl_xor(s2, msk);
    }
    __shared__ float red[8];
    const int wv = tid >> 6;
    if ((tid & 63) == 0) { red[wv] = s; red[wv + 4] = s2; }
    __syncthreads();
    s = red[0] + red[1] + red[2] + red[3];
    s2 = red[4] + red[5] + red[6] + red[7];
    const float mu = s * (1.f / 1024.f);
    float var = s2 * (1.f / 1024.f) - mu * mu;
    var = fmaxf(var, 0.f);
    const float rstd = rsqrtf(var + 1e-5f);
    float4 g4 = *(const float4*)&g[tid * 4];
    float4 b4 = *(const float4*)&bb[tid * 4];
    float o0 = (xv.x - mu) * rstd * g4.x + b4.x;
    float o1 = (xv.y - mu) * rstd * g4.y + b4.y;
    float o2 = (xv.z - mu) * rstd * g4.z + b4.z;
    float o3 = (xv.w - mu) * rstd * g4.w + b4.w;
    if (outf)
        *(float4*)(outf + (size_t)row * 1024 + tid * 4) = make_float4(o0, o1, o2, o3);
    if (outb) {
        ushort4 ov;
        ov.x = f2bf(o0); ov.y = f2bf(o1); ov.z = f2bf(o2); ov.w = f2bf(o3);
        *(ushort4*)(outb + (size_t)row * 1024 + tid * 4) = ov;
    }
}

extern "C" void kernel_launch(void* const* d_in, const int* in_sizes, int n_in,
                              void* d_out, int out_size, void* d_ws, size_t ws_size,
                              hipStream_t stream) {
    const float* tgt = (const float*)d_in[0];
    const float* Wq  = (const float*)d_in[1];
    const float* bq  = (const float*)d_in[2];
    const float* Wk  = (const float*)d_in[3];
    const float* bk  = (const float*)d_in[4];
    const float* Wv  = (const float*)d_in[5];
    const float* bv  = (const float*)d_in[6];
    const float* Wo  = (const float*)d_in[7];
    const float* bo  = (const float*)d_in[8];
    const float* W1  = (const float*)d_in[9];
    const float* b1  = (const float*)d_in[10];
    const float* W2  = (const float*)d_in[11];
    const float* b2  = (const float*)d_in[12];
    const float* g1  = (const float*)d_in[13];
    const float* be1 = (const float*)d_in[14];
    const float* g2  = (const float*)d_in[15];
    const float* be2 = (const float*)d_in[16];
    const float* rA  = (const float*)d_in[17];
    const float* rB  = (const float*)d_in[18];

    const int M = 4096, D = 1024, DFF = 4096;
    const size_t MD = (size_t)M * D;
    const size_t MB = 1u << 20;
    char* wsb = (char*)d_ws;

    u16* q    = (u16*)wsb;                 // q,kk,vv,ctx: 8 MB each
    u16* vv   = q + 2 * MD;
    u16* ctx  = q + 3 * MD;
    u16* h    = q;                         // 32 MB alias (free after Wo gemm)
    float* x1  = (float*)(wsb + 32 * MB);  // 16 MB
    float* sfp = (float*)(wsb + 48 * MB);  // 4 MB
    float* cfp = sfp + (size_t)2048 * 512; // 4 MB
    u16* x1b  = (u16*)sfp;                 // 8 MB alias (free after QKV)
    u16* tgtb = (u16*)(wsb + 56 * MB);     // 8 MB
    u16* Wqt  = (u16*)(wsb + 64 * MB);     // 2 MB each; Wqt|Wkt|Wvt contiguous
    u16* Wkt  = (u16*)(wsb + 66 * MB);
    u16* Wvt  = (u16*)(wsb + 68 * MB);
    u16* Wot  = (u16*)(wsb + 70 * MB);
    u16* W1t  = (u16*)(wsb + 72 * MB);     // 8 MB [4096][1024]
    u16* W2t  = (u16*)(wsb + 80 * MB);     // 8 MB [1024][4096]
    float* Pp = (float*)(wsb + 88 * MB);   // 128 KB

    cast_k<<<dim3(4096), dim3(256), 0, stream>>>(tgt, tgtb);
    tcast_k<<<dim3(32, 32),  dim3(256), 0, stream>>>(Wq, Wqt, D, D);
    tcast_k<<<dim3(32, 32),  dim3(256), 0, stream>>>(Wk, Wkt, D, D);
    tcast_k<<<dim3(32, 32),  dim3(256), 0, stream>>>(Wv, Wvt, D, D);
    tcast_k<<<dim3(32, 32),  dim3(256), 0, stream>>>(Wo, Wot, D, D);
    tcast_k<<<dim3(128, 32), dim3(256), 0, stream>>>(W1, W1t, D, DFF);
    tcast_k<<<dim3(32, 128), dim3(256), 0, stream>>>(W2, W2t, DFF, D);
    rope1_k<<<dim3(128), dim3(256), 0, stream>>>(rA, Pp);
    rope2_k<<<dim3(4096), dim3(256), 0, stream>>>(Pp, rB, sfp, cfp);

    mqkv_k<<<dim3(24, 32), dim3(256), 0, stream>>>(
        tgtb, Wqt, bq, bk, bv, sfp, cfp, q);

    mattn_k<<<dim3(32, 32), dim3(256), 0, stream>>>(q, q + MD, vv, ctx);

    mgemm_k<EP_RES, false><<<dim3(8, 32), dim3(256), 0, stream>>>(
        ctx, Wot, bo, tgt, x1, M, D, D);
    ln_k<<<dim3(4096), dim3(256), 0, stream>>>(x1, g1, be1, x1, x1b);
    mgemm_k<EP_RELU, true><<<dim3(32, 32), dim3(256), 0, stream>>>(
        x1b, W1t, b1, nullptr, h, M, DFF, D);
    mgemm_k<EP_RES, false><<<dim3(8, 32), dim3(256), 0, stream>>>(
        h, W2t, b2, x1, x1, M, D, DFF);
    ln_k<<<dim3(4096), dim3(256), 0, stream>>>(x1, g2, be2, (float*)d_out, nullptr);

    (void)in_sizes; (void)n_in; (void)out_size; (void)ws_size;
}

// Round 7
// 543.665 us; speedup vs baseline: 5.1472x; 1.0499x over previous
//
#include <hip/hip_runtime.h>
#include <math.h>

typedef unsigned short u16;
typedef unsigned int u32;
typedef __attribute__((ext_vector_type(8))) short short8v;
typedef __attribute__((ext_vector_type(4))) float f32x4;

__device__ __forceinline__ u16 f2bf(float f) {
    u32 u = __float_as_uint(f);
    u32 r = (u + 0x7fffu + ((u >> 16) & 1u)) >> 16;
    return (u16)r;
}

// async global->LDS DMA, 16 B per lane; lds dst = wave-uniform base + lane*16
#define GLOAD_LDS(g, l)                                                        \
    __builtin_amdgcn_global_load_lds(                                          \
        (const __attribute__((address_space(1))) void*)(g),                    \
        (__attribute__((address_space(3))) void*)(l), 16, 0, 0)

// ---------- elementwise fp32 -> bf16 cast ----------
__global__ void cast_k(const float* __restrict__ x, u16* __restrict__ y) {
    const int gid = blockIdx.x * blockDim.x + threadIdx.x;
    float4 v = ((const float4*)x)[gid];
    ushort4 o;
    o.x = f2bf(v.x); o.y = f2bf(v.y); o.z = f2bf(v.z); o.w = f2bf(v.w);
    ((ushort4*)y)[gid] = o;
}

// ---------- transpose + cast: S (KxN fp32) -> Dt (NxK bf16) ----------
__global__ __launch_bounds__(256) void tcast_k(const float* __restrict__ S,
                                               u16* __restrict__ Dt,
                                               int K, int N) {
    __shared__ float tile[32][33];
    const int n0 = blockIdx.x * 32, k0 = blockIdx.y * 32;
    const int tx = threadIdx.x & 31, ty = threadIdx.x >> 5;
#pragma unroll
    for (int i = 0; i < 4; i++)
        tile[ty + 8 * i][tx] = S[(size_t)(k0 + ty + 8 * i) * N + n0 + tx];
    __syncthreads();
#pragma unroll
    for (int i = 0; i < 4; i++)
        Dt[(size_t)(n0 + ty + 8 * i) * K + k0 + tx] = f2bf(tile[tx][ty + 8 * i]);
}

// log2(10000)/512
#define ROPE_LOG2C (13.287712379549449f / 512.0f)

// ---------- RoPE pass 1 (LDS-shared transcendentals) ----------
__global__ __launch_bounds__(256) void rope1_k(const float* __restrict__ A,
                                               float* __restrict__ P) {
    __shared__ float sc[16][17];
    __shared__ float cc[16][17];
    __shared__ float Als[16][17];
    __shared__ float Alc[16][17];
    const int tid = threadIdx.x;
    const int tt = tid >> 4, rr = tid & 15;
    const int t = blockIdx.x * 16 + tt;
    float acc = 0.f;
    for (int i0 = 0; i0 < 512; i0 += 16) {
        __syncthreads();
        {
            const int i = i0 + rr;
            const float th = exp2f(-(float)i * ROPE_LOG2C);
            const float ang = (float)t * th;
            sc[tt][rr] = sinf(ang);
            cc[tt][rr] = cosf(ang);
            Als[tt][rr] = A[(i0 + tt) * 16 + rr];
            Alc[tt][rr] = A[(512 + i0 + tt) * 16 + rr];
        }
        __syncthreads();
#pragma unroll
        for (int ii = 0; ii < 16; ++ii)
            acc = fmaf(sc[tt][ii], Als[ii][rr],
                       fmaf(cc[tt][ii], Alc[ii][rr], acc));
    }
    P[t * 16 + rr] = acc;
}

// ---------- RoPE pass 2 ----------
__global__ void rope2_k(const float* __restrict__ P, const float* __restrict__ Bw,
                        float* __restrict__ sf, float* __restrict__ cf) {
    const int gid = blockIdx.x * blockDim.x + threadIdx.x;
    if (gid >= 2048 * 512) return;
    const int t = gid >> 9, i = gid & 511;
    float ls = 0.f, lc = 0.f;
#pragma unroll
    for (int r = 0; r < 16; ++r) {
        const float p = P[t * 16 + r];
        ls = fmaf(p, Bw[r * 1024 + i], ls);
        lc = fmaf(p, Bw[r * 1024 + 512 + i], lc);
    }
    const float th = exp2f(-(float)i * ROPE_LOG2C);
    const float ang = (float)t * th;
    sf[gid] = sinf(ang) + ls;
    cf[gid] = cosf(ang) + lc;
}

// ---------- MFMA GEMM with global_load_lds staging ----------
enum { EP_NONE = 0, EP_RES = 2, EP_RELU = 3 };

template <int EPI, bool CBF>
__global__ __launch_bounds__(256) void mgemm_k(
    const u16* __restrict__ A, const u16* __restrict__ Bt,
    const float* __restrict__ bias, const float* __restrict__ resf,
    void* __restrict__ Cp, int M, int N, int K) {
    __shared__ u16 As[128 * 32];   // [m][k] unpadded (DMA layout)
    __shared__ u16 Bs[128 * 32];   // [n][k]
    const int tid = threadIdx.x;
    const int w = tid >> 6, l = tid & 63;
    const int quad = l >> 4, lr = l & 15;
    const int wr = w >> 1, wc = w & 1;
    const int m0 = blockIdx.y * 128, n0 = blockIdx.x * 128;

    const int srow = w * 16 + (l >> 2);
    const int scol = (l & 3) * 8;
    const u16* ag0 = A + (size_t)(m0 + srow) * K + scol;
    const u16* ag1 = A + (size_t)(m0 + 64 + srow) * K + scol;
    const u16* bg0 = Bt + (size_t)(n0 + srow) * K + scol;
    const u16* bg1 = Bt + (size_t)(n0 + 64 + srow) * K + scol;
    u16* lA0 = As + w * 512;
    u16* lA1 = As + 2048 + w * 512;
    u16* lB0 = Bs + w * 512;
    u16* lB1 = Bs + 2048 + w * 512;

    f32x4 acc[4][4];
#pragma unroll
    for (int i = 0; i < 4; i++)
#pragma unroll
        for (int j = 0; j < 4; j++) acc[i][j] = (f32x4)(0.0f);

    for (int k0 = 0; k0 < K; k0 += 32) {
        __syncthreads();
        GLOAD_LDS(ag0 + k0, lA0);
        GLOAD_LDS(ag1 + k0, lA1);
        GLOAD_LDS(bg0 + k0, lB0);
        GLOAD_LDS(bg1 + k0, lB1);
        __syncthreads();
        short8v af[4], bf[4];
#pragma unroll
        for (int mt = 0; mt < 4; ++mt)
            af[mt] = *(const short8v*)&As[(wr * 64 + mt * 16 + lr) * 32 + quad * 8];
#pragma unroll
        for (int nt = 0; nt < 4; ++nt)
            bf[nt] = *(const short8v*)&Bs[(wc * 64 + nt * 16 + lr) * 32 + quad * 8];
#pragma unroll
        for (int mt = 0; mt < 4; ++mt)
#pragma unroll
            for (int nt = 0; nt < 4; ++nt)
                acc[mt][nt] = __builtin_amdgcn_mfma_f32_16x16x32_bf16(
                    af[mt], bf[nt], acc[mt][nt], 0, 0, 0);
    }

#pragma unroll
    for (int mt = 0; mt < 4; ++mt) {
#pragma unroll
        for (int nt = 0; nt < 4; ++nt) {
            const int n = n0 + wc * 64 + nt * 16 + lr;
            const float bb = bias[n];
#pragma unroll
            for (int reg = 0; reg < 4; ++reg) {
                const int m = m0 + wr * 64 + mt * 16 + quad * 4 + reg;
                float v = acc[mt][nt][reg] + bb;
                if (EPI == EP_RES) v += resf[(size_t)m * N + n];
                if (EPI == EP_RELU) v = fmaxf(v, 0.f);
                if (CBF) ((u16*)Cp)[(size_t)m * N + n] = f2bf(v);
                else     ((float*)Cp)[(size_t)m * N + n] = v;
            }
        }
    }
}

// ---------- merged QKV GEMM (N=3072 over [Wqt|Wkt|Wvt]), RoPE on Q/K ----------
__global__ __launch_bounds__(256) void mqkv_k(
    const u16* __restrict__ A, const u16* __restrict__ Bt,
    const float* __restrict__ bq, const float* __restrict__ bk,
    const float* __restrict__ bv, const float* __restrict__ sf,
    const float* __restrict__ cf, u16* __restrict__ out) {
    const int K = 1024;
    __shared__ u16 As[128 * 32];
    __shared__ u16 Bs[128 * 32];
    const int tid = threadIdx.x;
    const int w = tid >> 6, l = tid & 63;
    const int quad = l >> 4, lr = l & 15;
    const int wr = w >> 1, wc = w & 1;
    const int m0 = blockIdx.y * 128, n0 = blockIdx.x * 128;

    const int srow = w * 16 + (l >> 2);
    const int scol = (l & 3) * 8;
    const u16* ag0 = A + (size_t)(m0 + srow) * K + scol;
    const u16* ag1 = A + (size_t)(m0 + 64 + srow) * K + scol;
    const u16* bg0 = Bt + (size_t)(n0 + srow) * K + scol;
    const u16* bg1 = Bt + (size_t)(n0 + 64 + srow) * K + scol;
    u16* lA0 = As + w * 512;
    u16* lA1 = As + 2048 + w * 512;
    u16* lB0 = Bs + w * 512;
    u16* lB1 = Bs + 2048 + w * 512;

    f32x4 acc[4][4];
#pragma unroll
    for (int i = 0; i < 4; i++)
#pragma unroll
        for (int j = 0; j < 4; j++) acc[i][j] = (f32x4)(0.0f);

    for (int k0 = 0; k0 < K; k0 += 32) {
        __syncthreads();
        GLOAD_LDS(ag0 + k0, lA0);
        GLOAD_LDS(ag1 + k0, lA1);
        GLOAD_LDS(bg0 + k0, lB0);
        GLOAD_LDS(bg1 + k0, lB1);
        __syncthreads();
        short8v af[4], bf[4];
#pragma unroll
        for (int mt = 0; mt < 4; ++mt)
            af[mt] = *(const short8v*)&As[(wr * 64 + mt * 16 + lr) * 32 + quad * 8];
#pragma unroll
        for (int nt = 0; nt < 4; ++nt)
            bf[nt] = *(const short8v*)&Bs[(wc * 64 + nt * 16 + lr) * 32 + quad * 8];
#pragma unroll
        for (int mt = 0; mt < 4; ++mt)
#pragma unroll
            for (int nt = 0; nt < 4; ++nt)
                acc[mt][nt] = __builtin_amdgcn_mfma_f32_16x16x32_bf16(
                    af[mt], bf[nt], acc[mt][nt], 0, 0, 0);
    }

    const int which = n0 >> 10;  // block-uniform (1024-boundaries align)
    const float* bias = which == 0 ? bq : (which == 1 ? bk : bv);
    const bool doRope = which < 2;
    u16* Cp = out + (size_t)which * 4096 * 1024;

#pragma unroll
    for (int mt = 0; mt < 4; ++mt) {
#pragma unroll
        for (int nt = 0; nt < 4; ++nt) {
            const int n = n0 + wc * 64 + nt * 16 + lr;
            const int col = n & 1023;
            const float bb = bias[col];
#pragma unroll
            for (int reg = 0; reg < 4; ++reg) {
                const int m = m0 + wr * 64 + mt * 16 + quad * 4 + reg;
                float v = acc[mt][nt][reg] + bb;
                const float partner = __shfl_xor(v, 1);
                if (doRope) {
                    const int t = m & 2047;
                    const int fi = col >> 1;
                    const float svv = sf[t * 512 + fi];
                    const float cvv = cf[t * 512 + fi];
                    v = (col & 1) ? fmaf(partner, svv, v * cvv)
                                  : fmaf(v, cvv, -partner * svv);
                }
                Cp[(size_t)m * 1024 + col] = f2bf(v);
            }
        }
    }
}

// ---------- MFMA flash attention ----------
// 1-D grid of 1024, XCD-swizzled: all 32 row-tiles of one (b,h) share an XCD
// so the K/V stream stays L2-resident. V staged transposed with XOR-swizzled
// key index (breaks the 8-way write conflict; reads stay 16B-contiguous).
__global__ __launch_bounds__(256) void mattn_k(
    const u16* __restrict__ Q, const u16* __restrict__ Kg,
    const u16* __restrict__ Vg, u16* __restrict__ O) {
    __shared__ u16 Qs[64][72];
    __shared__ u16 Ks[64][72];
    __shared__ u16 VsT[64 * 72];  // [d][key^sw(d)]
    __shared__ u16 Ps[4][16][72];
    const int tid = threadIdx.x;
    const int w = tid >> 6, l = tid & 63;
    const int quad = l >> 4, lr = l & 15;
    const int L = blockIdx.x;
    const int bh = (L & 7) * 4 + ((L >> 3) & 3);   // 32 bh, 4 per XCD
    const int b = bh >> 4, h = bh & 15;
    const int row0 = (L >> 5) * 64;
    const size_t base = (size_t)b * 2048 * 1024 + (size_t)h * 64;

    {
        const int r = tid >> 2, seg = (tid & 3) * 16;
        const u16* qp = Q + base + (size_t)(row0 + r) * 1024 + seg;
        *(uint4*)&Qs[r][seg]     = *(const uint4*)qp;
        *(uint4*)&Qs[r][seg + 8] = *(const uint4*)(qp + 8);
    }
    __syncthreads();
    const short8v aq0 = *(const short8v*)&Qs[w * 16 + lr][quad * 8];
    const short8v aq1 = *(const short8v*)&Qs[w * 16 + lr][32 + quad * 8];

    float m_i[4], l_i[4];
    f32x4 o_acc[4];
#pragma unroll
    for (int r = 0; r < 4; r++) { m_i[r] = -INFINITY; l_i[r] = 0.f; }
#pragma unroll
    for (int nt = 0; nt < 4; nt++) o_acc[nt] = (f32x4)(0.0f);

    for (int kc = 0; kc < 2048; kc += 64) {
        __syncthreads();
        {
            const int r = tid >> 2, seg = (tid & 3) * 16;
            const u16* kp = Kg + base + (size_t)(kc + r) * 1024 + seg;
            *(uint4*)&Ks[r][seg]     = *(const uint4*)kp;
            *(uint4*)&Ks[r][seg + 8] = *(const uint4*)(kp + 8);
            const u16* vp = Vg + base + (size_t)(kc + r) * 1024 + seg;
            uint4 v0 = *(const uint4*)vp;
            uint4 v1 = *(const uint4*)(vp + 8);
            u16 tmp[16];
            *(uint4*)tmp = v0; *(uint4*)(tmp + 8) = v1;
#pragma unroll
            for (int j = 0; j < 16; ++j) {
                const int d = seg + j;
                const int keyp = r ^ (((d >> 3) & 7) << 3);
                VsT[d * 72 + keyp] = tmp[j];
            }
        }
        __syncthreads();

        f32x4 s[4];
#pragma unroll
        for (int nt = 0; nt < 4; nt++) s[nt] = (f32x4)(0.0f);
#pragma unroll
        for (int nt = 0; nt < 4; nt++) {
            short8v bk0 = *(const short8v*)&Ks[nt * 16 + lr][quad * 8];
            short8v bk1 = *(const short8v*)&Ks[nt * 16 + lr][32 + quad * 8];
            s[nt] = __builtin_amdgcn_mfma_f32_16x16x32_bf16(aq0, bk0, s[nt], 0, 0, 0);
            s[nt] = __builtin_amdgcn_mfma_f32_16x16x32_bf16(aq1, bk1, s[nt], 0, 0, 0);
        }

        float p[4][4];
        float alpha[4];
#pragma unroll
        for (int reg = 0; reg < 4; reg++) {
            float sv0 = s[0][reg] * 0.125f, sv1 = s[1][reg] * 0.125f;
            float sv2 = s[2][reg] * 0.125f, sv3 = s[3][reg] * 0.125f;
            float rm = fmaxf(fmaxf(sv0, sv1), fmaxf(sv2, sv3));
            rm = fmaxf(rm, __shfl_xor(rm, 1));
            rm = fmaxf(rm, __shfl_xor(rm, 2));
            rm = fmaxf(rm, __shfl_xor(rm, 4));
            rm = fmaxf(rm, __shfl_xor(rm, 8));
            const float mnew = fmaxf(m_i[reg], rm);
            alpha[reg] = __expf(m_i[reg] - mnew);
            m_i[reg] = mnew;
            p[0][reg] = __expf(sv0 - mnew);
            p[1][reg] = __expf(sv1 - mnew);
            p[2][reg] = __expf(sv2 - mnew);
            p[3][reg] = __expf(sv3 - mnew);
            float rs = p[0][reg] + p[1][reg] + p[2][reg] + p[3][reg];
            rs += __shfl_xor(rs, 1);
            rs += __shfl_xor(rs, 2);
            rs += __shfl_xor(rs, 4);
            rs += __shfl_xor(rs, 8);
            l_i[reg] = l_i[reg] * alpha[reg] + rs;
        }
#pragma unroll
        for (int nt = 0; nt < 4; nt++) {
#pragma unroll
            for (int reg = 0; reg < 4; reg++) {
                o_acc[nt][reg] *= alpha[reg];
                Ps[w][quad * 4 + reg][nt * 16 + lr] = f2bf(p[nt][reg]);
            }
        }
        // P: C-layout -> A-layout (wave-local LDS round-trip, no barrier)
        const short8v ap0 = *(const short8v*)&Ps[w][lr][quad * 8];
        const short8v ap1 = *(const short8v*)&Ps[w][lr][32 + quad * 8];
#pragma unroll
        for (int nt = 0; nt < 4; nt++) {
            const int row = nt * 16 + lr;
            const int sw = (((row >> 3) & 7) << 3);
            short8v vf0 = *(const short8v*)&VsT[row * 72 + ((quad * 8) ^ sw)];
            short8v vf1 = *(const short8v*)&VsT[row * 72 + (((32 + quad * 8)) ^ sw)];
            o_acc[nt] = __builtin_amdgcn_mfma_f32_16x16x32_bf16(ap0, vf0, o_acc[nt], 0, 0, 0);
            o_acc[nt] = __builtin_amdgcn_mfma_f32_16x16x32_bf16(ap1, vf1, o_acc[nt], 0, 0, 0);
        }
    }

#pragma unroll
    for (int nt = 0; nt < 4; nt++)
#pragma unroll
        for (int reg = 0; reg < 4; reg++) {
            const float out = o_acc[nt][reg] / l_i[reg];
            O[base + (size_t)(row0 + w * 16 + quad * 4 + reg) * 1024 +
              nt * 16 + lr] = f2bf(out);
        }
}

// ---------- layernorm over 1024 cols; writes fp32 and/or bf16 ----------
__global__ __launch_bounds__(256) void ln_k(
    const float* __restrict__ X, const float* __restrict__ g,
    const float* __restrict__ bb, float* __restrict__ outf,
    u16* __restrict__ outb) {
    const int row = blockIdx.x, tid = threadIdx.x;
    const float* x = X + (size_t)row * 1024;
    float4 xv = *(const float4*)&x[tid * 4];
    float s = xv.x + xv.y + xv.z + xv.w;
    float s2 = xv.x * xv.x + xv.y * xv.y + xv.z * xv.z + xv.w * xv.w;
#pragma unroll
    for (int msk = 32; msk >= 1; msk >>= 1) {
        s += __shfl_xor(s, msk);
        s2 += __shfl_xor(s2, msk);
    }
    __shared__ float red[8];
    const int wv = tid >> 6;
    if ((tid & 63) == 0) { red[wv] = s; red[wv + 4] = s2; }
    __syncthreads();
    s = red[0] + red[1] + red[2] + red[3];
    s2 = red[4] + red[5] + red[6] + red[7];
    const float mu = s * (1.f / 1024.f);
    float var = s2 * (1.f / 1024.f) - mu * mu;
    var = fmaxf(var, 0.f);
    const float rstd = rsqrtf(var + 1e-5f);
    float4 g4 = *(const float4*)&g[tid * 4];
    float4 b4 = *(const float4*)&bb[tid * 4];
    float o0 = (xv.x - mu) * rstd * g4.x + b4.x;
    float o1 = (xv.y - mu) * rstd * g4.y + b4.y;
    float o2 = (xv.z - mu) * rstd * g4.z + b4.z;
    float o3 = (xv.w - mu) * rstd * g4.w + b4.w;
    if (outf)
        *(float4*)(outf + (size_t)row * 1024 + tid * 4) = make_float4(o0, o1, o2, o3);
    if (outb) {
        ushort4 ov;
        ov.x = f2bf(o0); ov.y = f2bf(o1); ov.z = f2bf(o2); ov.w = f2bf(o3);
        *(ushort4*)(outb + (size_t)row * 1024 + tid * 4) = ov;
    }
}

extern "C" void kernel_launch(void* const* d_in, const int* in_sizes, int n_in,
                              void* d_out, int out_size, void* d_ws, size_t ws_size,
                              hipStream_t stream) {
    const float* tgt = (const float*)d_in[0];
    const float* Wq  = (const float*)d_in[1];
    const float* bq  = (const float*)d_in[2];
    const float* Wk  = (const float*)d_in[3];
    const float* bk  = (const float*)d_in[4];
    const float* Wv  = (const float*)d_in[5];
    const float* bv  = (const float*)d_in[6];
    const float* Wo  = (const float*)d_in[7];
    const float* bo  = (const float*)d_in[8];
    const float* W1  = (const float*)d_in[9];
    const float* b1  = (const float*)d_in[10];
    const float* W2  = (const float*)d_in[11];
    const float* b2  = (const float*)d_in[12];
    const float* g1  = (const float*)d_in[13];
    const float* be1 = (const float*)d_in[14];
    const float* g2  = (const float*)d_in[15];
    const float* be2 = (const float*)d_in[16];
    const float* rA  = (const float*)d_in[17];
    const float* rB  = (const float*)d_in[18];

    const int M = 4096, D = 1024, DFF = 4096;
    const size_t MD = (size_t)M * D;
    const size_t MB = 1u << 20;
    char* wsb = (char*)d_ws;

    u16* q    = (u16*)wsb;                 // q,kk,vv,ctx: 8 MB each
    u16* vv   = q + 2 * MD;
    u16* ctx  = q + 3 * MD;
    u16* h    = q;                         // 32 MB alias (free after Wo gemm)
    float* x1  = (float*)(wsb + 32 * MB);  // 16 MB
    float* sfp = (float*)(wsb + 48 * MB);  // 4 MB
    float* cfp = sfp + (size_t)2048 * 512; // 4 MB
    u16* x1b  = (u16*)sfp;                 // 8 MB alias (free after QKV)
    u16* tgtb = (u16*)(wsb + 56 * MB);     // 8 MB
    u16* Wqt  = (u16*)(wsb + 64 * MB);     // 2 MB each; Wqt|Wkt|Wvt contiguous
    u16* Wkt  = (u16*)(wsb + 66 * MB);
    u16* Wvt  = (u16*)(wsb + 68 * MB);
    u16* Wot  = (u16*)(wsb + 70 * MB);
    u16* W1t  = (u16*)(wsb + 72 * MB);     // 8 MB [4096][1024]
    u16* W2t  = (u16*)(wsb + 80 * MB);     // 8 MB [1024][4096]
    float* Pp = (float*)(wsb + 88 * MB);   // 128 KB

    cast_k<<<dim3(4096), dim3(256), 0, stream>>>(tgt, tgtb);
    tcast_k<<<dim3(32, 32),  dim3(256), 0, stream>>>(Wq, Wqt, D, D);
    tcast_k<<<dim3(32, 32),  dim3(256), 0, stream>>>(Wk, Wkt, D, D);
    tcast_k<<<dim3(32, 32),  dim3(256), 0, stream>>>(Wv, Wvt, D, D);
    tcast_k<<<dim3(32, 32),  dim3(256), 0, stream>>>(Wo, Wot, D, D);
    tcast_k<<<dim3(128, 32), dim3(256), 0, stream>>>(W1, W1t, D, DFF);
    tcast_k<<<dim3(32, 128), dim3(256), 0, stream>>>(W2, W2t, DFF, D);
    rope1_k<<<dim3(128), dim3(256), 0, stream>>>(rA, Pp);
    rope2_k<<<dim3(4096), dim3(256), 0, stream>>>(Pp, rB, sfp, cfp);

    mqkv_k<<<dim3(24, 32), dim3(256), 0, stream>>>(
        tgtb, Wqt, bq, bk, bv, sfp, cfp, q);

    mattn_k<<<dim3(1024), dim3(256), 0, stream>>>(q, q + MD, vv, ctx);

    mgemm_k<EP_RES, false><<<dim3(8, 32), dim3(256), 0, stream>>>(
        ctx, Wot, bo, tgt, x1, M, D, D);
    ln_k<<<dim3(4096), dim3(256), 0, stream>>>(x1, g1, be1, x1, x1b);
    mgemm_k<EP_RELU, true><<<dim3(32, 32), dim3(256), 0, stream>>>(
        x1b, W1t, b1, nullptr, h, M, DFF, D);
    mgemm_k<EP_RES, false><<<dim3(8, 32), dim3(256), 0, stream>>>(
        h, W2t, b2, x1, x1, M, D, DFF);
    ln_k<<<dim3(4096), dim3(256), 0, stream>>>(x1, g2, be2, (float*)d_out, nullptr);

    (void)in_sizes; (void)n_in; (void)out_size; (void)ws_size;
}

// Round 8
// 501.759 us; speedup vs baseline: 5.5771x; 1.0835x over previous
//
#include <hip/hip_runtime.h>
#include <math.h>

typedef unsigned short u16;
typedef unsigned int u32;
typedef __attribute__((ext_vector_type(8))) short short8v;
typedef __attribute__((ext_vector_type(4))) float f32x4;

__device__ __forceinline__ u16 f2bf(float f) {
    u32 u = __float_as_uint(f);
    u32 r = (u + 0x7fffu + ((u >> 16) & 1u)) >> 16;
    return (u16)r;
}

// async global->LDS DMA, 16 B per lane; lds dst = wave-uniform base + lane*16
#define GLOAD_LDS(g, l)                                                        \
    __builtin_amdgcn_global_load_lds(                                          \
        (const __attribute__((address_space(1))) void*)(g),                    \
        (__attribute__((address_space(3))) void*)(l), 16, 0, 0)

// ---------- elementwise fp32 -> bf16 cast ----------
__global__ void cast_k(const float* __restrict__ x, u16* __restrict__ y) {
    const int gid = blockIdx.x * blockDim.x + threadIdx.x;
    float4 v = ((const float4*)x)[gid];
    ushort4 o;
    o.x = f2bf(v.x); o.y = f2bf(v.y); o.z = f2bf(v.z); o.w = f2bf(v.w);
    ((ushort4*)y)[gid] = o;
}

// ---------- transpose + cast: S (KxN fp32) -> Dt (NxK bf16) ----------
__global__ __launch_bounds__(256) void tcast_k(const float* __restrict__ S,
                                               u16* __restrict__ Dt,
                                               int K, int N) {
    __shared__ float tile[32][33];
    const int n0 = blockIdx.x * 32, k0 = blockIdx.y * 32;
    const int tx = threadIdx.x & 31, ty = threadIdx.x >> 5;
#pragma unroll
    for (int i = 0; i < 4; i++)
        tile[ty + 8 * i][tx] = S[(size_t)(k0 + ty + 8 * i) * N + n0 + tx];
    __syncthreads();
#pragma unroll
    for (int i = 0; i < 4; i++)
        Dt[(size_t)(n0 + ty + 8 * i) * K + k0 + tx] = f2bf(tile[tx][ty + 8 * i]);
}

// ---------- V transpose per head: vv[m][h*64+d] -> Vt[bh][d][key] ----------
// key index block-swizzled within each 64-key group: block ^= (d & 7).
__global__ __launch_bounds__(256) void vtrans_k(const u16* __restrict__ vv,
                                                u16* __restrict__ Vt) {
    __shared__ u16 tile[32][33];
    const int key0 = blockIdx.x * 32, d0 = blockIdx.y * 32, bh = blockIdx.z;
    const int b = bh >> 4, h = bh & 15;
    const int tx = threadIdx.x & 31, ty = threadIdx.x >> 5;
#pragma unroll
    for (int i = 0; i < 4; i++)
        tile[ty + 8 * i][tx] =
            vv[(size_t)(b * 2048 + key0 + ty + 8 * i) * 1024 + h * 64 + d0 + tx];
    __syncthreads();
#pragma unroll
    for (int i = 0; i < 4; i++) {
        const int d = d0 + ty + 8 * i;
        const int key = key0 + tx;
        const int ksw = (key & ~63) | ((((key >> 3) & 7) ^ (d & 7)) << 3) | (key & 7);
        Vt[((size_t)bh * 64 + d) * 2048 + ksw] = tile[tx][ty + 8 * i];
    }
}

// log2(10000)/512
#define ROPE_LOG2C (13.287712379549449f / 512.0f)

// ---------- RoPE pass 1 (LDS-shared transcendentals) ----------
__global__ __launch_bounds__(256) void rope1_k(const float* __restrict__ A,
                                               float* __restrict__ P) {
    __shared__ float sc[16][17];
    __shared__ float cc[16][17];
    __shared__ float Als[16][17];
    __shared__ float Alc[16][17];
    const int tid = threadIdx.x;
    const int tt = tid >> 4, rr = tid & 15;
    const int t = blockIdx.x * 16 + tt;
    float acc = 0.f;
    for (int i0 = 0; i0 < 512; i0 += 16) {
        __syncthreads();
        {
            const int i = i0 + rr;
            const float th = exp2f(-(float)i * ROPE_LOG2C);
            const float ang = (float)t * th;
            sc[tt][rr] = sinf(ang);
            cc[tt][rr] = cosf(ang);
            Als[tt][rr] = A[(i0 + tt) * 16 + rr];
            Alc[tt][rr] = A[(512 + i0 + tt) * 16 + rr];
        }
        __syncthreads();
#pragma unroll
        for (int ii = 0; ii < 16; ++ii)
            acc = fmaf(sc[tt][ii], Als[ii][rr],
                       fmaf(cc[tt][ii], Alc[ii][rr], acc));
    }
    P[t * 16 + rr] = acc;
}

// ---------- RoPE pass 2 ----------
__global__ void rope2_k(const float* __restrict__ P, const float* __restrict__ Bw,
                        float* __restrict__ sf, float* __restrict__ cf) {
    const int gid = blockIdx.x * blockDim.x + threadIdx.x;
    if (gid >= 2048 * 512) return;
    const int t = gid >> 9, i = gid & 511;
    float ls = 0.f, lc = 0.f;
#pragma unroll
    for (int r = 0; r < 16; ++r) {
        const float p = P[t * 16 + r];
        ls = fmaf(p, Bw[r * 1024 + i], ls);
        lc = fmaf(p, Bw[r * 1024 + 512 + i], lc);
    }
    const float th = exp2f(-(float)i * ROPE_LOG2C);
    const float ang = (float)t * th;
    sf[gid] = sinf(ang) + ls;
    cf[gid] = cosf(ang) + lc;
}

// ---------- MFMA GEMM with global_load_lds staging ----------
enum { EP_NONE = 0, EP_RES = 2, EP_RELU = 3 };

template <int EPI, bool CBF>
__global__ __launch_bounds__(256) void mgemm_k(
    const u16* __restrict__ A, const u16* __restrict__ Bt,
    const float* __restrict__ bias, const float* __restrict__ resf,
    void* __restrict__ Cp, int M, int N, int K) {
    __shared__ u16 As[128 * 32];   // [m][k] unpadded (DMA layout)
    __shared__ u16 Bs[128 * 32];   // [n][k]
    const int tid = threadIdx.x;
    const int w = tid >> 6, l = tid & 63;
    const int quad = l >> 4, lr = l & 15;
    const int wr = w >> 1, wc = w & 1;
    const int m0 = blockIdx.y * 128, n0 = blockIdx.x * 128;

    const int srow = w * 16 + (l >> 2);
    const int scol = (l & 3) * 8;
    const u16* ag0 = A + (size_t)(m0 + srow) * K + scol;
    const u16* ag1 = A + (size_t)(m0 + 64 + srow) * K + scol;
    const u16* bg0 = Bt + (size_t)(n0 + srow) * K + scol;
    const u16* bg1 = Bt + (size_t)(n0 + 64 + srow) * K + scol;
    u16* lA0 = As + w * 512;
    u16* lA1 = As + 2048 + w * 512;
    u16* lB0 = Bs + w * 512;
    u16* lB1 = Bs + 2048 + w * 512;

    f32x4 acc[4][4];
#pragma unroll
    for (int i = 0; i < 4; i++)
#pragma unroll
        for (int j = 0; j < 4; j++) acc[i][j] = (f32x4)(0.0f);

    for (int k0 = 0; k0 < K; k0 += 32) {
        __syncthreads();
        GLOAD_LDS(ag0 + k0, lA0);
        GLOAD_LDS(ag1 + k0, lA1);
        GLOAD_LDS(bg0 + k0, lB0);
        GLOAD_LDS(bg1 + k0, lB1);
        __syncthreads();
        short8v af[4], bf[4];
#pragma unroll
        for (int mt = 0; mt < 4; ++mt)
            af[mt] = *(const short8v*)&As[(wr * 64 + mt * 16 + lr) * 32 + quad * 8];
#pragma unroll
        for (int nt = 0; nt < 4; ++nt)
            bf[nt] = *(const short8v*)&Bs[(wc * 64 + nt * 16 + lr) * 32 + quad * 8];
#pragma unroll
        for (int mt = 0; mt < 4; ++mt)
#pragma unroll
            for (int nt = 0; nt < 4; ++nt)
                acc[mt][nt] = __builtin_amdgcn_mfma_f32_16x16x32_bf16(
                    af[mt], bf[nt], acc[mt][nt], 0, 0, 0);
    }

#pragma unroll
    for (int mt = 0; mt < 4; ++mt) {
#pragma unroll
        for (int nt = 0; nt < 4; ++nt) {
            const int n = n0 + wc * 64 + nt * 16 + lr;
            const float bb = bias[n];
#pragma unroll
            for (int reg = 0; reg < 4; ++reg) {
                const int m = m0 + wr * 64 + mt * 16 + quad * 4 + reg;
                float v = acc[mt][nt][reg] + bb;
                if (EPI == EP_RES) v += resf[(size_t)m * N + n];
                if (EPI == EP_RELU) v = fmaxf(v, 0.f);
                if (CBF) ((u16*)Cp)[(size_t)m * N + n] = f2bf(v);
                else     ((float*)Cp)[(size_t)m * N + n] = v;
            }
        }
    }
}

// ---------- merged QKV GEMM (N=3072 over [Wqt|Wkt|Wvt]), RoPE on Q/K ----------
// Q/K outputs stored with 16B-block XOR swizzle (keyed on token&7) inside each
// 64-col head segment, so attention can DMA tiles and read conflict-free.
// Q is pre-scaled by 0.125 (exact in bf16).
__global__ __launch_bounds__(256) void mqkv_k(
    const u16* __restrict__ A, const u16* __restrict__ Bt,
    const float* __restrict__ bq, const float* __restrict__ bk,
    const float* __restrict__ bv, const float* __restrict__ sf,
    const float* __restrict__ cf, u16* __restrict__ out) {
    const int K = 1024;
    __shared__ u16 As[128 * 32];
    __shared__ u16 Bs[128 * 32];
    const int tid = threadIdx.x;
    const int w = tid >> 6, l = tid & 63;
    const int quad = l >> 4, lr = l & 15;
    const int wr = w >> 1, wc = w & 1;
    const int m0 = blockIdx.y * 128, n0 = blockIdx.x * 128;

    const int srow = w * 16 + (l >> 2);
    const int scol = (l & 3) * 8;
    const u16* ag0 = A + (size_t)(m0 + srow) * K + scol;
    const u16* ag1 = A + (size_t)(m0 + 64 + srow) * K + scol;
    const u16* bg0 = Bt + (size_t)(n0 + srow) * K + scol;
    const u16* bg1 = Bt + (size_t)(n0 + 64 + srow) * K + scol;
    u16* lA0 = As + w * 512;
    u16* lA1 = As + 2048 + w * 512;
    u16* lB0 = Bs + w * 512;
    u16* lB1 = Bs + 2048 + w * 512;

    f32x4 acc[4][4];
#pragma unroll
    for (int i = 0; i < 4; i++)
#pragma unroll
        for (int j = 0; j < 4; j++) acc[i][j] = (f32x4)(0.0f);

    for (int k0 = 0; k0 < K; k0 += 32) {
        __syncthreads();
        GLOAD_LDS(ag0 + k0, lA0);
        GLOAD_LDS(ag1 + k0, lA1);
        GLOAD_LDS(bg0 + k0, lB0);
        GLOAD_LDS(bg1 + k0, lB1);
        __syncthreads();
        short8v af[4], bf[4];
#pragma unroll
        for (int mt = 0; mt < 4; ++mt)
            af[mt] = *(const short8v*)&As[(wr * 64 + mt * 16 + lr) * 32 + quad * 8];
#pragma unroll
        for (int nt = 0; nt < 4; ++nt)
            bf[nt] = *(const short8v*)&Bs[(wc * 64 + nt * 16 + lr) * 32 + quad * 8];
#pragma unroll
        for (int mt = 0; mt < 4; ++mt)
#pragma unroll
            for (int nt = 0; nt < 4; ++nt)
                acc[mt][nt] = __builtin_amdgcn_mfma_f32_16x16x32_bf16(
                    af[mt], bf[nt], acc[mt][nt], 0, 0, 0);
    }

    const int which = n0 >> 10;  // block-uniform (1024-boundaries align)
    const float* bias = which == 0 ? bq : (which == 1 ? bk : bv);
    const bool doRope = which < 2;
    u16* Cp = out + (size_t)which * 4096 * 1024;

#pragma unroll
    for (int mt = 0; mt < 4; ++mt) {
#pragma unroll
        for (int nt = 0; nt < 4; ++nt) {
            const int n = n0 + wc * 64 + nt * 16 + lr;
            const int col = n & 1023;
            const float bb = bias[col];
#pragma unroll
            for (int reg = 0; reg < 4; ++reg) {
                const int m = m0 + wr * 64 + mt * 16 + quad * 4 + reg;
                float v = acc[mt][nt][reg] + bb;
                const float partner = __shfl_xor(v, 1);
                int colw = col;
                if (doRope) {
                    const int t = m & 2047;
                    const int fi = col >> 1;
                    const float svv = sf[t * 512 + fi];
                    const float cvv = cf[t * 512 + fi];
                    v = (col & 1) ? fmaf(partner, svv, v * cvv)
                                  : fmaf(v, cvv, -partner * svv);
                    if (which == 0) v *= 0.125f;
                    colw = (col & ~63) | ((((col >> 3) & 7) ^ (m & 7)) << 3) |
                           (col & 7);
                }
                Cp[(size_t)m * 1024 + colw] = f2bf(v);
            }
        }
    }
}

// ---------- MFMA flash attention (maxless softmax, full DMA staging) ----------
// 1-D grid 1024, XCD-swizzled (all 32 row-tiles of a bh share one XCD).
// Q/K read from swizzled layout (block^token&7); V from Vt (block^d&7).
__global__ __launch_bounds__(256) void mattn_k(
    const u16* __restrict__ Q, const u16* __restrict__ Kg,
    const u16* __restrict__ Vt, u16* __restrict__ O) {
    __shared__ u16 Qs[64 * 64];
    __shared__ u16 Ks[64 * 64];
    __shared__ u16 Vs[64 * 64];
    __shared__ u16 Ps[4][16][72];
    const int tid = threadIdx.x;
    const int w = tid >> 6, l = tid & 63;
    const int quad = l >> 4, lr = l & 15;
    const int L = blockIdx.x;
    const int bh = (L & 7) * 4 + ((L >> 3) & 3);   // 32 bh, 4 per XCD
    const int b = bh >> 4, h = bh & 15;
    const int row0 = (L >> 5) * 64;
    const size_t base = (size_t)b * 2048 * 1024 + (size_t)h * 64;
    const size_t vbase = (size_t)bh * 64 * 2048;

    const int dr = l >> 3;        // DMA: row-in-group
    const int dc = (l & 7) * 8;   // DMA: u16 col (16B chunk)
    const int g0 = w * 2, g1 = w * 2 + 1;

    GLOAD_LDS(Q + base + (size_t)(row0 + g0 * 8 + dr) * 1024 + dc, Qs + g0 * 512);
    GLOAD_LDS(Q + base + (size_t)(row0 + g1 * 8 + dr) * 1024 + dc, Qs + g1 * 512);
    __syncthreads();
    const int qr = w * 16 + lr;
    const short8v aq0 = *(const short8v*)&Qs[qr * 64 + ((quad ^ (qr & 7)) << 3)];
    const short8v aq1 = *(const short8v*)&Qs[qr * 64 + (((quad + 4) ^ (qr & 7)) << 3)];

    float lsum[4] = {0.f, 0.f, 0.f, 0.f};
    f32x4 o_acc[4];
#pragma unroll
    for (int nt = 0; nt < 4; nt++) o_acc[nt] = (f32x4)(0.0f);

    for (int kc = 0; kc < 2048; kc += 64) {
        __syncthreads();
        GLOAD_LDS(Kg + base + (size_t)(kc + g0 * 8 + dr) * 1024 + dc, Ks + g0 * 512);
        GLOAD_LDS(Kg + base + (size_t)(kc + g1 * 8 + dr) * 1024 + dc, Ks + g1 * 512);
        GLOAD_LDS(Vt + vbase + (size_t)(g0 * 8 + dr) * 2048 + kc + dc, Vs + g0 * 512);
        GLOAD_LDS(Vt + vbase + (size_t)(g1 * 8 + dr) * 2048 + kc + dc, Vs + g1 * 512);
        __syncthreads();

        // S = Q K^T (Q pre-scaled by 1/8)
        f32x4 s[4];
#pragma unroll
        for (int nt = 0; nt < 4; nt++) s[nt] = (f32x4)(0.0f);
#pragma unroll
        for (int nt = 0; nt < 4; nt++) {
            const int kr = nt * 16 + lr;
            short8v bk0 = *(const short8v*)&Ks[kr * 64 + ((quad ^ (kr & 7)) << 3)];
            short8v bk1 = *(const short8v*)&Ks[kr * 64 + (((quad + 4) ^ (kr & 7)) << 3)];
            s[nt] = __builtin_amdgcn_mfma_f32_16x16x32_bf16(aq0, bk0, s[nt], 0, 0, 0);
            s[nt] = __builtin_amdgcn_mfma_f32_16x16x32_bf16(aq1, bk1, s[nt], 0, 0, 0);
        }

        // maxless softmax: p = exp(s); per-lane partial row sums, no shuffles
#pragma unroll
        for (int nt = 0; nt < 4; nt++) {
#pragma unroll
            for (int reg = 0; reg < 4; reg++) {
                const float p = __expf(s[nt][reg]);
                lsum[reg] += p;
                Ps[w][quad * 4 + reg][nt * 16 + lr] = f2bf(p);
            }
        }
        // P: C-layout -> A-layout (wave-local LDS round-trip)
        const short8v ap0 = *(const short8v*)&Ps[w][lr][quad * 8];
        const short8v ap1 = *(const short8v*)&Ps[w][lr][32 + quad * 8];
#pragma unroll
        for (int nt = 0; nt < 4; nt++) {
            const int vr = nt * 16 + lr;
            short8v vf0 = *(const short8v*)&Vs[vr * 64 + ((quad ^ (vr & 7)) << 3)];
            short8v vf1 = *(const short8v*)&Vs[vr * 64 + (((quad + 4) ^ (vr & 7)) << 3)];
            o_acc[nt] = __builtin_amdgcn_mfma_f32_16x16x32_bf16(ap0, vf0, o_acc[nt], 0, 0, 0);
            o_acc[nt] = __builtin_amdgcn_mfma_f32_16x16x32_bf16(ap1, vf1, o_acc[nt], 0, 0, 0);
        }
    }

    // final row-sum reduction across the 16 lanes of each quad
    float l_i[4];
#pragma unroll
    for (int reg = 0; reg < 4; reg++) {
        float t = lsum[reg];
        t += __shfl_xor(t, 1);
        t += __shfl_xor(t, 2);
        t += __shfl_xor(t, 4);
        t += __shfl_xor(t, 8);
        l_i[reg] = t;
    }

#pragma unroll
    for (int nt = 0; nt < 4; nt++)
#pragma unroll
        for (int reg = 0; reg < 4; reg++) {
            const float out = o_acc[nt][reg] / l_i[reg];
            O[base + (size_t)(row0 + w * 16 + quad * 4 + reg) * 1024 +
              nt * 16 + lr] = f2bf(out);
        }
}

// ---------- layernorm over 1024 cols; writes fp32 and/or bf16 ----------
__global__ __launch_bounds__(256) void ln_k(
    const float* __restrict__ X, const float* __restrict__ g,
    const float* __restrict__ bb, float* __restrict__ outf,
    u16* __restrict__ outb) {
    const int row = blockIdx.x, tid = threadIdx.x;
    const float* x = X + (size_t)row * 1024;
    float4 xv = *(const float4*)&x[tid * 4];
    float s = xv.x + xv.y + xv.z + xv.w;
    float s2 = xv.x * xv.x + xv.y * xv.y + xv.z * xv.z + xv.w * xv.w;
#pragma unroll
    for (int msk = 32; msk >= 1; msk >>= 1) {
        s += __shfl_xor(s, msk);
        s2 += __shfl_xor(s2, msk);
    }
    __shared__ float red[8];
    const int wv = tid >> 6;
    if ((tid & 63) == 0) { red[wv] = s; red[wv + 4] = s2; }
    __syncthreads();
    s = red[0] + red[1] + red[2] + red[3];
    s2 = red[4] + red[5] + red[6] + red[7];
    const float mu = s * (1.f / 1024.f);
    float var = s2 * (1.f / 1024.f) - mu * mu;
    var = fmaxf(var, 0.f);
    const float rstd = rsqrtf(var + 1e-5f);
    float4 g4 = *(const float4*)&g[tid * 4];
    float4 b4 = *(const float4*)&bb[tid * 4];
    float o0 = (xv.x - mu) * rstd * g4.x + b4.x;
    float o1 = (xv.y - mu) * rstd * g4.y + b4.y;
    float o2 = (xv.z - mu) * rstd * g4.z + b4.z;
    float o3 = (xv.w - mu) * rstd * g4.w + b4.w;
    if (outf)
        *(float4*)(outf + (size_t)row * 1024 + tid * 4) = make_float4(o0, o1, o2, o3);
    if (outb) {
        ushort4 ov;
        ov.x = f2bf(o0); ov.y = f2bf(o1); ov.z = f2bf(o2); ov.w = f2bf(o3);
        *(ushort4*)(outb + (size_t)row * 1024 + tid * 4) = ov;
    }
}

extern "C" void kernel_launch(void* const* d_in, const int* in_sizes, int n_in,
                              void* d_out, int out_size, void* d_ws, size_t ws_size,
                              hipStream_t stream) {
    const float* tgt = (const float*)d_in[0];
    const float* Wq  = (const float*)d_in[1];
    const float* bq  = (const float*)d_in[2];
    const float* Wk  = (const float*)d_in[3];
    const float* bk  = (const float*)d_in[4];
    const float* Wv  = (const float*)d_in[5];
    const float* bv  = (const float*)d_in[6];
    const float* Wo  = (const float*)d_in[7];
    const float* bo  = (const float*)d_in[8];
    const float* W1  = (const float*)d_in[9];
    const float* b1  = (const float*)d_in[10];
    const float* W2  = (const float*)d_in[11];
    const float* b2  = (const float*)d_in[12];
    const float* g1  = (const float*)d_in[13];
    const float* be1 = (const float*)d_in[14];
    const float* g2  = (const float*)d_in[15];
    const float* be2 = (const float*)d_in[16];
    const float* rA  = (const float*)d_in[17];
    const float* rB  = (const float*)d_in[18];

    const int M = 4096, D = 1024, DFF = 4096;
    const size_t MD = (size_t)M * D;
    const size_t MB = 1u << 20;
    char* wsb = (char*)d_ws;

    u16* q    = (u16*)wsb;                 // q,kk,vv,ctx: 8 MB each
    u16* vv   = q + 2 * MD;
    u16* ctx  = q + 3 * MD;
    u16* h    = q;                         // 32 MB alias (free after Wo gemm)
    float* x1  = (float*)(wsb + 32 * MB);  // 16 MB
    float* sfp = (float*)(wsb + 48 * MB);  // 4 MB
    float* cfp = sfp + (size_t)2048 * 512; // 4 MB
    u16* x1b  = (u16*)sfp;                 // 8 MB alias (free after QKV)
    u16* tgtb = (u16*)(wsb + 56 * MB);     // 8 MB
    u16* Vt   = (u16*)(wsb + 56 * MB);     // 8 MB alias (tgtb dead after mqkv)
    u16* Wqt  = (u16*)(wsb + 64 * MB);     // 2 MB each; Wqt|Wkt|Wvt contiguous
    u16* Wkt  = (u16*)(wsb + 66 * MB);
    u16* Wvt  = (u16*)(wsb + 68 * MB);
    u16* Wot  = (u16*)(wsb + 70 * MB);
    u16* W1t  = (u16*)(wsb + 72 * MB);     // 8 MB [4096][1024]
    u16* W2t  = (u16*)(wsb + 80 * MB);     // 8 MB [1024][4096]
    float* Pp = (float*)(wsb + 88 * MB);   // 128 KB

    cast_k<<<dim3(4096), dim3(256), 0, stream>>>(tgt, tgtb);
    tcast_k<<<dim3(32, 32),  dim3(256), 0, stream>>>(Wq, Wqt, D, D);
    tcast_k<<<dim3(32, 32),  dim3(256), 0, stream>>>(Wk, Wkt, D, D);
    tcast_k<<<dim3(32, 32),  dim3(256), 0, stream>>>(Wv, Wvt, D, D);
    tcast_k<<<dim3(32, 32),  dim3(256), 0, stream>>>(Wo, Wot, D, D);
    tcast_k<<<dim3(128, 32), dim3(256), 0, stream>>>(W1, W1t, D, DFF);
    tcast_k<<<dim3(32, 128), dim3(256), 0, stream>>>(W2, W2t, DFF, D);
    rope1_k<<<dim3(128), dim3(256), 0, stream>>>(rA, Pp);
    rope2_k<<<dim3(4096), dim3(256), 0, stream>>>(Pp, rB, sfp, cfp);

    mqkv_k<<<dim3(24, 32), dim3(256), 0, stream>>>(
        tgtb, Wqt, bq, bk, bv, sfp, cfp, q);

    vtrans_k<<<dim3(64, 2, 32), dim3(256), 0, stream>>>(vv, Vt);

    mattn_k<<<dim3(1024), dim3(256), 0, stream>>>(q, q + MD, Vt, ctx);

    mgemm_k<EP_RES, false><<<dim3(8, 32), dim3(256), 0, stream>>>(
        ctx, Wot, bo, tgt, x1, M, D, D);
    ln_k<<<dim3(4096), dim3(256), 0, stream>>>(x1, g1, be1, x1, x1b);
    mgemm_k<EP_RELU, true><<<dim3(32, 32), dim3(256), 0, stream>>>(
        x1b, W1t, b1, nullptr, h, M, DFF, D);
    mgemm_k<EP_RES, false><<<dim3(8, 32), dim3(256), 0, stream>>>(
        h, W2t, b2, x1, x1, M, D, DFF);
    ln_k<<<dim3(4096), dim3(256), 0, stream>>>(x1, g2, be2, (float*)d_out, nullptr);

    (void)in_sizes; (void)n_in; (void)out_size; (void)ws_size;
}

// Round 9
// 499.233 us; speedup vs baseline: 5.6053x; 1.0051x over previous
//
#include <hip/hip_runtime.h>
#include <math.h>

typedef unsigned short u16;
typedef unsigned int u32;
typedef __attribute__((ext_vector_type(8))) short short8v;
typedef __attribute__((ext_vector_type(4))) float f32x4;

__device__ __forceinline__ u16 f2bf(float f) {
    u32 u = __float_as_uint(f);
    u32 r = (u + 0x7fffu + ((u >> 16) & 1u)) >> 16;
    return (u16)r;
}

// async global->LDS DMA, 16 B per lane; lds dst = wave-uniform base + lane*16
#define GLOAD_LDS(g, l)                                                        \
    __builtin_amdgcn_global_load_lds(                                          \
        (const __attribute__((address_space(1))) void*)(g),                    \
        (__attribute__((address_space(3))) void*)(l), 16, 0, 0)

// ---------- elementwise fp32 -> bf16 cast ----------
__global__ void cast_k(const float* __restrict__ x, u16* __restrict__ y) {
    const int gid = blockIdx.x * blockDim.x + threadIdx.x;
    float4 v = ((const float4*)x)[gid];
    ushort4 o;
    o.x = f2bf(v.x); o.y = f2bf(v.y); o.z = f2bf(v.z); o.w = f2bf(v.w);
    ((ushort4*)y)[gid] = o;
}

// ---------- transpose + cast: S (KxN fp32) -> Dt (NxK bf16) ----------
__global__ __launch_bounds__(256) void tcast_k(const float* __restrict__ S,
                                               u16* __restrict__ Dt,
                                               int K, int N) {
    __shared__ float tile[32][33];
    const int n0 = blockIdx.x * 32, k0 = blockIdx.y * 32;
    const int tx = threadIdx.x & 31, ty = threadIdx.x >> 5;
#pragma unroll
    for (int i = 0; i < 4; i++)
        tile[ty + 8 * i][tx] = S[(size_t)(k0 + ty + 8 * i) * N + n0 + tx];
    __syncthreads();
#pragma unroll
    for (int i = 0; i < 4; i++)
        Dt[(size_t)(n0 + ty + 8 * i) * K + k0 + tx] = f2bf(tile[tx][ty + 8 * i]);
}

// ---------- V transpose per head: vv[m][h*64+d] -> Vt[bh][d][key] ----------
// key index block-swizzled within each 64-key group: block ^= (d & 7).
__global__ __launch_bounds__(256) void vtrans_k(const u16* __restrict__ vv,
                                                u16* __restrict__ Vt) {
    __shared__ u16 tile[32][33];
    const int key0 = blockIdx.x * 32, d0 = blockIdx.y * 32, bh = blockIdx.z;
    const int b = bh >> 4, h = bh & 15;
    const int tx = threadIdx.x & 31, ty = threadIdx.x >> 5;
#pragma unroll
    for (int i = 0; i < 4; i++)
        tile[ty + 8 * i][tx] =
            vv[(size_t)(b * 2048 + key0 + ty + 8 * i) * 1024 + h * 64 + d0 + tx];
    __syncthreads();
#pragma unroll
    for (int i = 0; i < 4; i++) {
        const int d = d0 + ty + 8 * i;
        const int key = key0 + tx;
        const int ksw = (key & ~63) | ((((key >> 3) & 7) ^ (d & 7)) << 3) | (key & 7);
        Vt[((size_t)bh * 64 + d) * 2048 + ksw] = tile[tx][ty + 8 * i];
    }
}

// log2(10000)/512
#define ROPE_LOG2C (13.287712379549449f / 512.0f)

// ---------- RoPE pass 1 (LDS-shared transcendentals) ----------
__global__ __launch_bounds__(256) void rope1_k(const float* __restrict__ A,
                                               float* __restrict__ P) {
    __shared__ float sc[16][17];
    __shared__ float cc[16][17];
    __shared__ float Als[16][17];
    __shared__ float Alc[16][17];
    const int tid = threadIdx.x;
    const int tt = tid >> 4, rr = tid & 15;
    const int t = blockIdx.x * 16 + tt;
    float acc = 0.f;
    for (int i0 = 0; i0 < 512; i0 += 16) {
        __syncthreads();
        {
            const int i = i0 + rr;
            const float th = exp2f(-(float)i * ROPE_LOG2C);
            const float ang = (float)t * th;
            sc[tt][rr] = sinf(ang);
            cc[tt][rr] = cosf(ang);
            Als[tt][rr] = A[(i0 + tt) * 16 + rr];
            Alc[tt][rr] = A[(512 + i0 + tt) * 16 + rr];
        }
        __syncthreads();
#pragma unroll
        for (int ii = 0; ii < 16; ++ii)
            acc = fmaf(sc[tt][ii], Als[ii][rr],
                       fmaf(cc[tt][ii], Alc[ii][rr], acc));
    }
    P[t * 16 + rr] = acc;
}

// ---------- RoPE pass 2 ----------
__global__ void rope2_k(const float* __restrict__ P, const float* __restrict__ Bw,
                        float* __restrict__ sf, float* __restrict__ cf) {
    const int gid = blockIdx.x * blockDim.x + threadIdx.x;
    if (gid >= 2048 * 512) return;
    const int t = gid >> 9, i = gid & 511;
    float ls = 0.f, lc = 0.f;
#pragma unroll
    for (int r = 0; r < 16; ++r) {
        const float p = P[t * 16 + r];
        ls = fmaf(p, Bw[r * 1024 + i], ls);
        lc = fmaf(p, Bw[r * 1024 + 512 + i], lc);
    }
    const float th = exp2f(-(float)i * ROPE_LOG2C);
    const float ang = (float)t * th;
    sf[gid] = sinf(ang) + ls;
    cf[gid] = cosf(ang) + lc;
}

// XCD supertile mapping: linear grid; xcd = L&7 owns an rn x rm tile region,
// n-inner ordering keeps the B-stripe (rn tiles) L2-resident per XCD.
__device__ __forceinline__ void xcd_tile(int L, int xn, int rn, int rm,
                                         int& m0, int& n0) {
    const int xcd = L & 7, i = L >> 3;
    const int cx = xcd % xn, cy = xcd / xn;
    const int ln = i % rn, lm = i / rn;
    n0 = (cx * rn + ln) * 128;
    m0 = (cy * rm + lm) * 128;
}

// ---------- MFMA GEMM with global_load_lds staging + XCD supertiling ----------
enum { EP_NONE = 0, EP_RES = 2, EP_RELU = 3 };

template <int EPI, bool CBF>
__global__ __launch_bounds__(256) void mgemm_k(
    const u16* __restrict__ A, const u16* __restrict__ Bt,
    const float* __restrict__ bias, const float* __restrict__ resf,
    void* __restrict__ Cp, int M, int N, int K, int xn, int rn, int rm) {
    __shared__ u16 As[128 * 32];   // [m][k] unpadded (DMA layout)
    __shared__ u16 Bs[128 * 32];   // [n][k]
    const int tid = threadIdx.x;
    const int w = tid >> 6, l = tid & 63;
    const int quad = l >> 4, lr = l & 15;
    const int wr = w >> 1, wc = w & 1;
    int m0, n0;
    xcd_tile(blockIdx.x, xn, rn, rm, m0, n0);

    const int srow = w * 16 + (l >> 2);
    const int scol = (l & 3) * 8;
    const u16* ag0 = A + (size_t)(m0 + srow) * K + scol;
    const u16* ag1 = A + (size_t)(m0 + 64 + srow) * K + scol;
    const u16* bg0 = Bt + (size_t)(n0 + srow) * K + scol;
    const u16* bg1 = Bt + (size_t)(n0 + 64 + srow) * K + scol;
    u16* lA0 = As + w * 512;
    u16* lA1 = As + 2048 + w * 512;
    u16* lB0 = Bs + w * 512;
    u16* lB1 = Bs + 2048 + w * 512;

    f32x4 acc[4][4];
#pragma unroll
    for (int i = 0; i < 4; i++)
#pragma unroll
        for (int j = 0; j < 4; j++) acc[i][j] = (f32x4)(0.0f);

    for (int k0 = 0; k0 < K; k0 += 32) {
        __syncthreads();
        GLOAD_LDS(ag0 + k0, lA0);
        GLOAD_LDS(ag1 + k0, lA1);
        GLOAD_LDS(bg0 + k0, lB0);
        GLOAD_LDS(bg1 + k0, lB1);
        __syncthreads();
        short8v af[4], bf[4];
#pragma unroll
        for (int mt = 0; mt < 4; ++mt)
            af[mt] = *(const short8v*)&As[(wr * 64 + mt * 16 + lr) * 32 + quad * 8];
#pragma unroll
        for (int nt = 0; nt < 4; ++nt)
            bf[nt] = *(const short8v*)&Bs[(wc * 64 + nt * 16 + lr) * 32 + quad * 8];
#pragma unroll
        for (int mt = 0; mt < 4; ++mt)
#pragma unroll
            for (int nt = 0; nt < 4; ++nt)
                acc[mt][nt] = __builtin_amdgcn_mfma_f32_16x16x32_bf16(
                    af[mt], bf[nt], acc[mt][nt], 0, 0, 0);
    }

#pragma unroll
    for (int mt = 0; mt < 4; ++mt) {
#pragma unroll
        for (int nt = 0; nt < 4; ++nt) {
            const int n = n0 + wc * 64 + nt * 16 + lr;
            const float bb = bias[n];
#pragma unroll
            for (int reg = 0; reg < 4; ++reg) {
                const int m = m0 + wr * 64 + mt * 16 + quad * 4 + reg;
                float v = acc[mt][nt][reg] + bb;
                if (EPI == EP_RES) v += resf[(size_t)m * N + n];
                if (EPI == EP_RELU) v = fmaxf(v, 0.f);
                if (CBF) ((u16*)Cp)[(size_t)m * N + n] = f2bf(v);
                else     ((float*)Cp)[(size_t)m * N + n] = v;
            }
        }
    }
}

// ---------- merged QKV GEMM (N=3072 over [Wqt|Wkt|Wvt]), RoPE on Q/K ----------
// Q/K outputs stored with 16B-block XOR swizzle (keyed on token&7) inside each
// 64-col head segment; Q pre-scaled by 0.125.
__global__ __launch_bounds__(256) void mqkv_k(
    const u16* __restrict__ A, const u16* __restrict__ Bt,
    const float* __restrict__ bq, const float* __restrict__ bk,
    const float* __restrict__ bv, const float* __restrict__ sf,
    const float* __restrict__ cf, u16* __restrict__ out) {
    const int K = 1024;
    __shared__ u16 As[128 * 32];
    __shared__ u16 Bs[128 * 32];
    const int tid = threadIdx.x;
    const int w = tid >> 6, l = tid & 63;
    const int quad = l >> 4, lr = l & 15;
    const int wr = w >> 1, wc = w & 1;
    int m0, n0;
    xcd_tile(blockIdx.x, 4, 6, 16, m0, n0);   // 24n x 32m grid

    const int srow = w * 16 + (l >> 2);
    const int scol = (l & 3) * 8;
    const u16* ag0 = A + (size_t)(m0 + srow) * K + scol;
    const u16* ag1 = A + (size_t)(m0 + 64 + srow) * K + scol;
    const u16* bg0 = Bt + (size_t)(n0 + srow) * K + scol;
    const u16* bg1 = Bt + (size_t)(n0 + 64 + srow) * K + scol;
    u16* lA0 = As + w * 512;
    u16* lA1 = As + 2048 + w * 512;
    u16* lB0 = Bs + w * 512;
    u16* lB1 = Bs + 2048 + w * 512;

    f32x4 acc[4][4];
#pragma unroll
    for (int i = 0; i < 4; i++)
#pragma unroll
        for (int j = 0; j < 4; j++) acc[i][j] = (f32x4)(0.0f);

    for (int k0 = 0; k0 < K; k0 += 32) {
        __syncthreads();
        GLOAD_LDS(ag0 + k0, lA0);
        GLOAD_LDS(ag1 + k0, lA1);
        GLOAD_LDS(bg0 + k0, lB0);
        GLOAD_LDS(bg1 + k0, lB1);
        __syncthreads();
        short8v af[4], bf[4];
#pragma unroll
        for (int mt = 0; mt < 4; ++mt)
            af[mt] = *(const short8v*)&As[(wr * 64 + mt * 16 + lr) * 32 + quad * 8];
#pragma unroll
        for (int nt = 0; nt < 4; ++nt)
            bf[nt] = *(const short8v*)&Bs[(wc * 64 + nt * 16 + lr) * 32 + quad * 8];
#pragma unroll
        for (int mt = 0; mt < 4; ++mt)
#pragma unroll
            for (int nt = 0; nt < 4; ++nt)
                acc[mt][nt] = __builtin_amdgcn_mfma_f32_16x16x32_bf16(
                    af[mt], bf[nt], acc[mt][nt], 0, 0, 0);
    }

    const int which = n0 >> 10;  // block-uniform (1024-boundaries align)
    const float* bias = which == 0 ? bq : (which == 1 ? bk : bv);
    const bool doRope = which < 2;
    u16* Cp = out + (size_t)which * 4096 * 1024;

#pragma unroll
    for (int mt = 0; mt < 4; ++mt) {
#pragma unroll
        for (int nt = 0; nt < 4; ++nt) {
            const int n = n0 + wc * 64 + nt * 16 + lr;
            const int col = n & 1023;
            const float bb = bias[col];
#pragma unroll
            for (int reg = 0; reg < 4; ++reg) {
                const int m = m0 + wr * 64 + mt * 16 + quad * 4 + reg;
                float v = acc[mt][nt][reg] + bb;
                const float partner = __shfl_xor(v, 1);
                int colw = col;
                if (doRope) {
                    const int t = m & 2047;
                    const int fi = col >> 1;
                    const float svv = sf[t * 512 + fi];
                    const float cvv = cf[t * 512 + fi];
                    v = (col & 1) ? fmaf(partner, svv, v * cvv)
                                  : fmaf(v, cvv, -partner * svv);
                    if (which == 0) v *= 0.125f;
                    colw = (col & ~63) | ((((col >> 3) & 7) ^ (m & 7)) << 3) |
                           (col & 7);
                }
                Cp[(size_t)m * 1024 + colw] = f2bf(v);
            }
        }
    }
}

// ---------- MFMA flash attention (maxless softmax, full DMA staging) ----------
__global__ __launch_bounds__(256) void mattn_k(
    const u16* __restrict__ Q, const u16* __restrict__ Kg,
    const u16* __restrict__ Vt, u16* __restrict__ O) {
    __shared__ u16 Qs[64 * 64];
    __shared__ u16 Ks[64 * 64];
    __shared__ u16 Vs[64 * 64];
    __shared__ u16 Ps[4][16][72];
    const int tid = threadIdx.x;
    const int w = tid >> 6, l = tid & 63;
    const int quad = l >> 4, lr = l & 15;
    const int L = blockIdx.x;
    const int bh = (L & 7) * 4 + ((L >> 3) & 3);   // 32 bh, 4 per XCD
    const int b = bh >> 4, h = bh & 15;
    const int row0 = (L >> 5) * 64;
    const size_t base = (size_t)b * 2048 * 1024 + (size_t)h * 64;
    const size_t vbase = (size_t)bh * 64 * 2048;

    const int dr = l >> 3;
    const int dc = (l & 7) * 8;
    const int g0 = w * 2, g1 = w * 2 + 1;

    GLOAD_LDS(Q + base + (size_t)(row0 + g0 * 8 + dr) * 1024 + dc, Qs + g0 * 512);
    GLOAD_LDS(Q + base + (size_t)(row0 + g1 * 8 + dr) * 1024 + dc, Qs + g1 * 512);
    __syncthreads();
    const int qr = w * 16 + lr;
    const short8v aq0 = *(const short8v*)&Qs[qr * 64 + ((quad ^ (qr & 7)) << 3)];
    const short8v aq1 = *(const short8v*)&Qs[qr * 64 + (((quad + 4) ^ (qr & 7)) << 3)];

    float lsum[4] = {0.f, 0.f, 0.f, 0.f};
    f32x4 o_acc[4];
#pragma unroll
    for (int nt = 0; nt < 4; nt++) o_acc[nt] = (f32x4)(0.0f);

    for (int kc = 0; kc < 2048; kc += 64) {
        __syncthreads();
        GLOAD_LDS(Kg + base + (size_t)(kc + g0 * 8 + dr) * 1024 + dc, Ks + g0 * 512);
        GLOAD_LDS(Kg + base + (size_t)(kc + g1 * 8 + dr) * 1024 + dc, Ks + g1 * 512);
        GLOAD_LDS(Vt + vbase + (size_t)(g0 * 8 + dr) * 2048 + kc + dc, Vs + g0 * 512);
        GLOAD_LDS(Vt + vbase + (size_t)(g1 * 8 + dr) * 2048 + kc + dc, Vs + g1 * 512);
        __syncthreads();

        f32x4 s[4];
#pragma unroll
        for (int nt = 0; nt < 4; nt++) s[nt] = (f32x4)(0.0f);
#pragma unroll
        for (int nt = 0; nt < 4; nt++) {
            const int kr = nt * 16 + lr;
            short8v bk0 = *(const short8v*)&Ks[kr * 64 + ((quad ^ (kr & 7)) << 3)];
            short8v bk1 = *(const short8v*)&Ks[kr * 64 + (((quad + 4) ^ (kr & 7)) << 3)];
            s[nt] = __builtin_amdgcn_mfma_f32_16x16x32_bf16(aq0, bk0, s[nt], 0, 0, 0);
            s[nt] = __builtin_amdgcn_mfma_f32_16x16x32_bf16(aq1, bk1, s[nt], 0, 0, 0);
        }

#pragma unroll
        for (int nt = 0; nt < 4; nt++) {
#pragma unroll
            for (int reg = 0; reg < 4; reg++) {
                const float p = __expf(s[nt][reg]);
                lsum[reg] += p;
                Ps[w][quad * 4 + reg][nt * 16 + lr] = f2bf(p);
            }
        }
        const short8v ap0 = *(const short8v*)&Ps[w][lr][quad * 8];
        const short8v ap1 = *(const short8v*)&Ps[w][lr][32 + quad * 8];
#pragma unroll
        for (int nt = 0; nt < 4; nt++) {
            const int vr = nt * 16 + lr;
            short8v vf0 = *(const short8v*)&Vs[vr * 64 + ((quad ^ (vr & 7)) << 3)];
            short8v vf1 = *(const short8v*)&Vs[vr * 64 + (((quad + 4) ^ (vr & 7)) << 3)];
            o_acc[nt] = __builtin_amdgcn_mfma_f32_16x16x32_bf16(ap0, vf0, o_acc[nt], 0, 0, 0);
            o_acc[nt] = __builtin_amdgcn_mfma_f32_16x16x32_bf16(ap1, vf1, o_acc[nt], 0, 0, 0);
        }
    }

    float l_i[4];
#pragma unroll
    for (int reg = 0; reg < 4; reg++) {
        float t = lsum[reg];
        t += __shfl_xor(t, 1);
        t += __shfl_xor(t, 2);
        t += __shfl_xor(t, 4);
        t += __shfl_xor(t, 8);
        l_i[reg] = t;
    }

#pragma unroll
    for (int nt = 0; nt < 4; nt++)
#pragma unroll
        for (int reg = 0; reg < 4; reg++) {
            const float out = o_acc[nt][reg] / l_i[reg];
            O[base + (size_t)(row0 + w * 16 + quad * 4 + reg) * 1024 +
              nt * 16 + lr] = f2bf(out);
        }
}

// ---------- layernorm over 1024 cols; writes fp32 and/or bf16 ----------
__global__ __launch_bounds__(256) void ln_k(
    const float* __restrict__ X, const float* __restrict__ g,
    const float* __restrict__ bb, float* __restrict__ outf,
    u16* __restrict__ outb) {
    const int row = blockIdx.x, tid = threadIdx.x;
    const float* x = X + (size_t)row * 1024;
    float4 xv = *(const float4*)&x[tid * 4];
    float s = xv.x + xv.y + xv.z + xv.w;
    float s2 = xv.x * xv.x + xv.y * xv.y + xv.z * xv.z + xv.w * xv.w;
#pragma unroll
    for (int msk = 32; msk >= 1; msk >>= 1) {
        s += __shfl_xor(s, msk);
        s2 += __shfl_xor(s2, msk);
    }
    __shared__ float red[8];
    const int wv = tid >> 6;
    if ((tid & 63) == 0) { red[wv] = s; red[wv + 4] = s2; }
    __syncthreads();
    s = red[0] + red[1] + red[2] + red[3];
    s2 = red[4] + red[5] + red[6] + red[7];
    const float mu = s * (1.f / 1024.f);
    float var = s2 * (1.f / 1024.f) - mu * mu;
    var = fmaxf(var, 0.f);
    const float rstd = rsqrtf(var + 1e-5f);
    float4 g4 = *(const float4*)&g[tid * 4];
    float4 b4 = *(const float4*)&bb[tid * 4];
    float o0 = (xv.x - mu) * rstd * g4.x + b4.x;
    float o1 = (xv.y - mu) * rstd * g4.y + b4.y;
    float o2 = (xv.z - mu) * rstd * g4.z + b4.z;
    float o3 = (xv.w - mu) * rstd * g4.w + b4.w;
    if (outf)
        *(float4*)(outf + (size_t)row * 1024 + tid * 4) = make_float4(o0, o1, o2, o3);
    if (outb) {
        ushort4 ov;
        ov.x = f2bf(o0); ov.y = f2bf(o1); ov.z = f2bf(o2); ov.w = f2bf(o3);
        *(ushort4*)(outb + (size_t)row * 1024 + tid * 4) = ov;
    }
}

extern "C" void kernel_launch(void* const* d_in, const int* in_sizes, int n_in,
                              void* d_out, int out_size, void* d_ws, size_t ws_size,
                              hipStream_t stream) {
    const float* tgt = (const float*)d_in[0];
    const float* Wq  = (const float*)d_in[1];
    const float* bq  = (const float*)d_in[2];
    const float* Wk  = (const float*)d_in[3];
    const float* bk  = (const float*)d_in[4];
    const float* Wv  = (const float*)d_in[5];
    const float* bv  = (const float*)d_in[6];
    const float* Wo  = (const float*)d_in[7];
    const float* bo  = (const float*)d_in[8];
    const float* W1  = (const float*)d_in[9];
    const float* b1  = (const float*)d_in[10];
    const float* W2  = (const float*)d_in[11];
    const float* b2  = (const float*)d_in[12];
    const float* g1  = (const float*)d_in[13];
    const float* be1 = (const float*)d_in[14];
    const float* g2  = (const float*)d_in[15];
    const float* be2 = (const float*)d_in[16];
    const float* rA  = (const float*)d_in[17];
    const float* rB  = (const float*)d_in[18];

    const int M = 4096, D = 1024, DFF = 4096;
    const size_t MD = (size_t)M * D;
    const size_t MB = 1u << 20;
    char* wsb = (char*)d_ws;

    u16* q    = (u16*)wsb;                 // q,kk,vv,ctx: 8 MB each
    u16* vv   = q + 2 * MD;
    u16* ctx  = q + 3 * MD;
    u16* h    = q;                         // 32 MB alias (free after Wo gemm)
    float* x1  = (float*)(wsb + 32 * MB);  // 16 MB
    float* sfp = (float*)(wsb + 48 * MB);  // 4 MB
    float* cfp = sfp + (size_t)2048 * 512; // 4 MB
    u16* x1b  = (u16*)sfp;                 // 8 MB alias (free after QKV)
    u16* tgtb = (u16*)(wsb + 56 * MB);     // 8 MB
    u16* Vt   = (u16*)(wsb + 56 * MB);     // 8 MB alias (tgtb dead after mqkv)
    u16* Wqt  = (u16*)(wsb + 64 * MB);     // 2 MB each; Wqt|Wkt|Wvt contiguous
    u16* Wkt  = (u16*)(wsb + 66 * MB);
    u16* Wvt  = (u16*)(wsb + 68 * MB);
    u16* Wot  = (u16*)(wsb + 70 * MB);
    u16* W1t  = (u16*)(wsb + 72 * MB);     // 8 MB [4096][1024]
    u16* W2t  = (u16*)(wsb + 80 * MB);     // 8 MB [1024][4096]
    float* Pp = (float*)(wsb + 88 * MB);   // 128 KB

    cast_k<<<dim3(4096), dim3(256), 0, stream>>>(tgt, tgtb);
    tcast_k<<<dim3(32, 32),  dim3(256), 0, stream>>>(Wq, Wqt, D, D);
    tcast_k<<<dim3(32, 32),  dim3(256), 0, stream>>>(Wk, Wkt, D, D);
    tcast_k<<<dim3(32, 32),  dim3(256), 0, stream>>>(Wv, Wvt, D, D);
    tcast_k<<<dim3(32, 32),  dim3(256), 0, stream>>>(Wo, Wot, D, D);
    tcast_k<<<dim3(128, 32), dim3(256), 0, stream>>>(W1, W1t, D, DFF);
    tcast_k<<<dim3(32, 128), dim3(256), 0, stream>>>(W2, W2t, DFF, D);
    rope1_k<<<dim3(128), dim3(256), 0, stream>>>(rA, Pp);
    rope2_k<<<dim3(4096), dim3(256), 0, stream>>>(Pp, rB, sfp, cfp);

    // 24n x 32m, xn=4 -> per-XCD 6n x 16m (B-stripe 1.5 MB resident)
    mqkv_k<<<dim3(768), dim3(256), 0, stream>>>(
        tgtb, Wqt, bq, bk, bv, sfp, cfp, q);

    vtrans_k<<<dim3(64, 2, 32), dim3(256), 0, stream>>>(vv, Vt);

    mattn_k<<<dim3(1024), dim3(256), 0, stream>>>(q, q + MD, Vt, ctx);

    // Wo: 8n x 32m, xn=2 -> per-XCD 4n x 8m
    mgemm_k<EP_RES, false><<<dim3(256), dim3(256), 0, stream>>>(
        ctx, Wot, bo, tgt, x1, M, D, D, 2, 4, 8);
    ln_k<<<dim3(4096), dim3(256), 0, stream>>>(x1, g1, be1, x1, x1b);
    // FFN1: 32n x 32m, xn=4 -> per-XCD 8n x 16m (B-stripe 2 MB resident)
    mgemm_k<EP_RELU, true><<<dim3(1024), dim3(256), 0, stream>>>(
        x1b, W1t, b1, nullptr, h, M, DFF, D, 4, 8, 16);
    // FFN2: 8n x 32m, K=4096, xn=2 -> per-XCD 4n x 8m
    mgemm_k<EP_RES, false><<<dim3(256), dim3(256), 0, stream>>>(
        h, W2t, b2, x1, x1, M, D, DFF, 2, 4, 8);
    ln_k<<<dim3(4096), dim3(256), 0, stream>>>(x1, g2, be2, (float*)d_out, nullptr);

    (void)in_sizes; (void)n_in; (void)out_size; (void)ws_size;
}

// Round 10
// 474.491 us; speedup vs baseline: 5.8976x; 1.0521x over previous
//
#include <hip/hip_runtime.h>
#include <math.h>

typedef unsigned short u16;
typedef unsigned int u32;
typedef __attribute__((ext_vector_type(8))) short short8v;
typedef __attribute__((ext_vector_type(4))) float f32x4;

__device__ __forceinline__ u16 f2bf(float f) {
    u32 u = __float_as_uint(f);
    u32 r = (u + 0x7fffu + ((u >> 16) & 1u)) >> 16;
    return (u16)r;
}

// async global->LDS DMA, 16 B per lane; lds dst = wave-uniform base + lane*16
#define GLOAD_LDS(g, l)                                                        \
    __builtin_amdgcn_global_load_lds(                                          \
        (const __attribute__((address_space(1))) void*)(g),                    \
        (__attribute__((address_space(3))) void*)(l), 16, 0, 0)

// ---------- elementwise fp32 -> bf16 cast ----------
__global__ void cast_k(const float* __restrict__ x, u16* __restrict__ y) {
    const int gid = blockIdx.x * blockDim.x + threadIdx.x;
    float4 v = ((const float4*)x)[gid];
    ushort4 o;
    o.x = f2bf(v.x); o.y = f2bf(v.y); o.z = f2bf(v.z); o.w = f2bf(v.w);
    ((ushort4*)y)[gid] = o;
}

// ---------- transpose + cast: S (KxN fp32) -> Dt (NxK bf16) ----------
__global__ __launch_bounds__(256) void tcast_k(const float* __restrict__ S,
                                               u16* __restrict__ Dt,
                                               int K, int N) {
    __shared__ float tile[32][33];
    const int n0 = blockIdx.x * 32, k0 = blockIdx.y * 32;
    const int tx = threadIdx.x & 31, ty = threadIdx.x >> 5;
#pragma unroll
    for (int i = 0; i < 4; i++)
        tile[ty + 8 * i][tx] = S[(size_t)(k0 + ty + 8 * i) * N + n0 + tx];
    __syncthreads();
#pragma unroll
    for (int i = 0; i < 4; i++)
        Dt[(size_t)(n0 + ty + 8 * i) * K + k0 + tx] = f2bf(tile[tx][ty + 8 * i]);
}

// ---------- V transpose per head: vv[m][h*64+d] -> Vt[bh][d][key] ----------
__global__ __launch_bounds__(256) void vtrans_k(const u16* __restrict__ vv,
                                                u16* __restrict__ Vt) {
    __shared__ u16 tile[32][33];
    const int key0 = blockIdx.x * 32, d0 = blockIdx.y * 32, bh = blockIdx.z;
    const int b = bh >> 4, h = bh & 15;
    const int tx = threadIdx.x & 31, ty = threadIdx.x >> 5;
#pragma unroll
    for (int i = 0; i < 4; i++)
        tile[ty + 8 * i][tx] =
            vv[(size_t)(b * 2048 + key0 + ty + 8 * i) * 1024 + h * 64 + d0 + tx];
    __syncthreads();
#pragma unroll
    for (int i = 0; i < 4; i++) {
        const int d = d0 + ty + 8 * i;
        const int key = key0 + tx;
        const int ksw = (key & ~63) | ((((key >> 3) & 7) ^ (d & 7)) << 3) | (key & 7);
        Vt[((size_t)bh * 64 + d) * 2048 + ksw] = tile[tx][ty + 8 * i];
    }
}

// log2(10000)/512
#define ROPE_LOG2C (13.287712379549449f / 512.0f)

// ---------- RoPE pass 1 (LDS-shared transcendentals) ----------
__global__ __launch_bounds__(256) void rope1_k(const float* __restrict__ A,
                                               float* __restrict__ P) {
    __shared__ float sc[16][17];
    __shared__ float cc[16][17];
    __shared__ float Als[16][17];
    __shared__ float Alc[16][17];
    const int tid = threadIdx.x;
    const int tt = tid >> 4, rr = tid & 15;
    const int t = blockIdx.x * 16 + tt;
    float acc = 0.f;
    for (int i0 = 0; i0 < 512; i0 += 16) {
        __syncthreads();
        {
            const int i = i0 + rr;
            const float th = exp2f(-(float)i * ROPE_LOG2C);
            const float ang = (float)t * th;
            sc[tt][rr] = sinf(ang);
            cc[tt][rr] = cosf(ang);
            Als[tt][rr] = A[(i0 + tt) * 16 + rr];
            Alc[tt][rr] = A[(512 + i0 + tt) * 16 + rr];
        }
        __syncthreads();
#pragma unroll
        for (int ii = 0; ii < 16; ++ii)
            acc = fmaf(sc[tt][ii], Als[ii][rr],
                       fmaf(cc[tt][ii], Alc[ii][rr], acc));
    }
    P[t * 16 + rr] = acc;
}

// ---------- RoPE pass 2 ----------
__global__ void rope2_k(const float* __restrict__ P, const float* __restrict__ Bw,
                        float* __restrict__ sf, float* __restrict__ cf) {
    const int gid = blockIdx.x * blockDim.x + threadIdx.x;
    if (gid >= 2048 * 512) return;
    const int t = gid >> 9, i = gid & 511;
    float ls = 0.f, lc = 0.f;
#pragma unroll
    for (int r = 0; r < 16; ++r) {
        const float p = P[t * 16 + r];
        ls = fmaf(p, Bw[r * 1024 + i], ls);
        lc = fmaf(p, Bw[r * 1024 + 512 + i], lc);
    }
    const float th = exp2f(-(float)i * ROPE_LOG2C);
    const float ang = (float)t * th;
    sf[gid] = sinf(ang) + ls;
    cf[gid] = cosf(ang) + lc;
}

// XCD supertile mapping: linear grid; xcd = L&7 owns an rn x rm tile region.
__device__ __forceinline__ void xcd_tile(int L, int xn, int rn, int rm,
                                         int& tm, int& tn) {
    const int xcd = L & 7, i = L >> 3;
    const int cx = xcd % xn, cy = xcd / xn;
    tn = cx * rn + (i % rn);
    tm = cy * rm + (i / rn);
}

// ---------- MFMA GEMM: double-buffered DMA staging, single barrier/iter ----
enum { EP_NONE = 0, EP_RES = 2, EP_RELU = 3 };

template <int EPI, bool CBF, int BN>
__global__ __launch_bounds__(256) void mgemm_k(
    const u16* __restrict__ A, const u16* __restrict__ Bt,
    const float* __restrict__ bias, const float* __restrict__ resf,
    void* __restrict__ Cp, int M, int N, int K, int xn, int rn, int rm) {
    constexpr int NT = BN / 32;            // n-frags per wave
    __shared__ u16 As[2 * 128 * 32];
    __shared__ u16 Bs[2 * BN * 32];
    const int tid = threadIdx.x;
    const int w = tid >> 6, l = tid & 63;
    const int quad = l >> 4, lr = l & 15;
    const int wr = w >> 1, wc = w & 1;
    int tm, tn;
    xcd_tile(blockIdx.x, xn, rn, rm, tm, tn);
    const int m0 = tm * 128, n0 = tn * BN;

    const int srow = w * 16 + (l >> 2);    // staging row (64-row round)
    const int scol = (l & 3) * 8;
    const u16* ag0 = A + (size_t)(m0 + srow) * K + scol;
    const u16* ag1 = A + (size_t)(m0 + 64 + srow) * K + scol;
    const u16* bg0 = Bt + (size_t)(n0 + srow) * K + scol;
    const u16* bg1 = Bt + (size_t)(n0 + 64 + srow) * K + scol;  // BN==128 only

    f32x4 acc[4][NT];
#pragma unroll
    for (int i = 0; i < 4; i++)
#pragma unroll
        for (int j = 0; j < NT; j++) acc[i][j] = (f32x4)(0.0f);

    // prologue: stage tile 0 into buffer 0
    {
        u16* Ab = As;
        u16* Bb = Bs;
        GLOAD_LDS(ag0, Ab + w * 512);
        GLOAD_LDS(ag1, Ab + 2048 + w * 512);
        GLOAD_LDS(bg0, Bb + w * 512);
        if (BN == 128) GLOAD_LDS(bg1, Bb + 2048 + w * 512);
    }

    const int niter = K >> 5;
    for (int i = 0; i < niter; ++i) {
        __syncthreads();   // drains DMA(i); protects buffer reuse
        const int knext = (i + 1) << 5;
        if (knext < K) {
            u16* Ab = As + ((i + 1) & 1) * 4096;
            u16* Bb = Bs + ((i + 1) & 1) * (BN * 32);
            GLOAD_LDS(ag0 + knext, Ab + w * 512);
            GLOAD_LDS(ag1 + knext, Ab + 2048 + w * 512);
            GLOAD_LDS(bg0 + knext, Bb + w * 512);
            if (BN == 128) GLOAD_LDS(bg1 + knext, Bb + 2048 + w * 512);
        }
        const u16* Ac = As + (i & 1) * 4096;
        const u16* Bc = Bs + (i & 1) * (BN * 32);
        short8v af[4], bf[NT];
#pragma unroll
        for (int mt = 0; mt < 4; ++mt)
            af[mt] = *(const short8v*)&Ac[(wr * 64 + mt * 16 + lr) * 32 + quad * 8];
#pragma unroll
        for (int nt = 0; nt < NT; ++nt)
            bf[nt] = *(const short8v*)&Bc[(wc * (BN / 2) + nt * 16 + lr) * 32 + quad * 8];
#pragma unroll
        for (int mt = 0; mt < 4; ++mt)
#pragma unroll
            for (int nt = 0; nt < NT; ++nt)
                acc[mt][nt] = __builtin_amdgcn_mfma_f32_16x16x32_bf16(
                    af[mt], bf[nt], acc[mt][nt], 0, 0, 0);
    }

#pragma unroll
    for (int mt = 0; mt < 4; ++mt) {
#pragma unroll
        for (int nt = 0; nt < NT; ++nt) {
            const int n = n0 + wc * (BN / 2) + nt * 16 + lr;
            const float bb = bias[n];
#pragma unroll
            for (int reg = 0; reg < 4; ++reg) {
                const int m = m0 + wr * 64 + mt * 16 + quad * 4 + reg;
                float v = acc[mt][nt][reg] + bb;
                if (EPI == EP_RES) v += resf[(size_t)m * N + n];
                if (EPI == EP_RELU) v = fmaxf(v, 0.f);
                if (CBF) ((u16*)Cp)[(size_t)m * N + n] = f2bf(v);
                else     ((float*)Cp)[(size_t)m * N + n] = v;
            }
        }
    }
}

// ---------- merged QKV GEMM (N=3072), dbuf staging, RoPE+swizzle epilogue ----
__global__ __launch_bounds__(256) void mqkv_k(
    const u16* __restrict__ A, const u16* __restrict__ Bt,
    const float* __restrict__ bq, const float* __restrict__ bk,
    const float* __restrict__ bv, const float* __restrict__ sf,
    const float* __restrict__ cf, u16* __restrict__ out) {
    const int K = 1024;
    __shared__ u16 As[2 * 128 * 32];
    __shared__ u16 Bs[2 * 128 * 32];
    const int tid = threadIdx.x;
    const int w = tid >> 6, l = tid & 63;
    const int quad = l >> 4, lr = l & 15;
    const int wr = w >> 1, wc = w & 1;
    int tm, tn;
    xcd_tile(blockIdx.x, 4, 6, 16, tm, tn);   // 24n x 32m grid
    const int m0 = tm * 128, n0 = tn * 128;

    const int srow = w * 16 + (l >> 2);
    const int scol = (l & 3) * 8;
    const u16* ag0 = A + (size_t)(m0 + srow) * K + scol;
    const u16* ag1 = A + (size_t)(m0 + 64 + srow) * K + scol;
    const u16* bg0 = Bt + (size_t)(n0 + srow) * K + scol;
    const u16* bg1 = Bt + (size_t)(n0 + 64 + srow) * K + scol;

    f32x4 acc[4][4];
#pragma unroll
    for (int i = 0; i < 4; i++)
#pragma unroll
        for (int j = 0; j < 4; j++) acc[i][j] = (f32x4)(0.0f);

    {
        GLOAD_LDS(ag0, As + w * 512);
        GLOAD_LDS(ag1, As + 2048 + w * 512);
        GLOAD_LDS(bg0, Bs + w * 512);
        GLOAD_LDS(bg1, Bs + 2048 + w * 512);
    }
    for (int i = 0; i < 32; ++i) {
        __syncthreads();
        const int knext = (i + 1) << 5;
        if (knext < K) {
            u16* Ab = As + ((i + 1) & 1) * 4096;
            u16* Bb = Bs + ((i + 1) & 1) * 4096;
            GLOAD_LDS(ag0 + knext, Ab + w * 512);
            GLOAD_LDS(ag1 + knext, Ab + 2048 + w * 512);
            GLOAD_LDS(bg0 + knext, Bb + w * 512);
            GLOAD_LDS(bg1 + knext, Bb + 2048 + w * 512);
        }
        const u16* Ac = As + (i & 1) * 4096;
        const u16* Bc = Bs + (i & 1) * 4096;
        short8v af[4], bf[4];
#pragma unroll
        for (int mt = 0; mt < 4; ++mt)
            af[mt] = *(const short8v*)&Ac[(wr * 64 + mt * 16 + lr) * 32 + quad * 8];
#pragma unroll
        for (int nt = 0; nt < 4; ++nt)
            bf[nt] = *(const short8v*)&Bc[(wc * 64 + nt * 16 + lr) * 32 + quad * 8];
#pragma unroll
        for (int mt = 0; mt < 4; ++mt)
#pragma unroll
            for (int nt = 0; nt < 4; ++nt)
                acc[mt][nt] = __builtin_amdgcn_mfma_f32_16x16x32_bf16(
                    af[mt], bf[nt], acc[mt][nt], 0, 0, 0);
    }

    const int which = n0 >> 10;  // block-uniform (1024-boundaries align)
    const float* bias = which == 0 ? bq : (which == 1 ? bk : bv);
    const bool doRope = which < 2;
    u16* Cp = out + (size_t)which * 4096 * 1024;

#pragma unroll
    for (int mt = 0; mt < 4; ++mt) {
#pragma unroll
        for (int nt = 0; nt < 4; ++nt) {
            const int n = n0 + wc * 64 + nt * 16 + lr;
            const int col = n & 1023;
            const float bb = bias[col];
#pragma unroll
            for (int reg = 0; reg < 4; ++reg) {
                const int m = m0 + wr * 64 + mt * 16 + quad * 4 + reg;
                float v = acc[mt][nt][reg] + bb;
                const float partner = __shfl_xor(v, 1);
                int colw = col;
                if (doRope) {
                    const int t = m & 2047;
                    const int fi = col >> 1;
                    const float svv = sf[t * 512 + fi];
                    const float cvv = cf[t * 512 + fi];
                    v = (col & 1) ? fmaf(partner, svv, v * cvv)
                                  : fmaf(v, cvv, -partner * svv);
                    if (which == 0) v *= 0.125f;
                    colw = (col & ~63) | ((((col >> 3) & 7) ^ (m & 7)) << 3) |
                           (col & 7);
                }
                Cp[(size_t)m * 1024 + colw] = f2bf(v);
            }
        }
    }
}

// ---------- MFMA flash attention (maxless softmax, full DMA staging) ----------
__global__ __launch_bounds__(256) void mattn_k(
    const u16* __restrict__ Q, const u16* __restrict__ Kg,
    const u16* __restrict__ Vt, u16* __restrict__ O) {
    __shared__ u16 Qs[64 * 64];
    __shared__ u16 Ks[64 * 64];
    __shared__ u16 Vs[64 * 64];
    __shared__ u16 Ps[4][16][72];
    const int tid = threadIdx.x;
    const int w = tid >> 6, l = tid & 63;
    const int quad = l >> 4, lr = l & 15;
    const int L = blockIdx.x;
    const int bh = (L & 7) * 4 + ((L >> 3) & 3);   // 32 bh, 4 per XCD
    const int b = bh >> 4, h = bh & 15;
    const int row0 = (L >> 5) * 64;
    const size_t base = (size_t)b * 2048 * 1024 + (size_t)h * 64;
    const size_t vbase = (size_t)bh * 64 * 2048;

    const int dr = l >> 3;
    const int dc = (l & 7) * 8;
    const int g0 = w * 2, g1 = w * 2 + 1;

    GLOAD_LDS(Q + base + (size_t)(row0 + g0 * 8 + dr) * 1024 + dc, Qs + g0 * 512);
    GLOAD_LDS(Q + base + (size_t)(row0 + g1 * 8 + dr) * 1024 + dc, Qs + g1 * 512);
    __syncthreads();
    const int qr = w * 16 + lr;
    const short8v aq0 = *(const short8v*)&Qs[qr * 64 + ((quad ^ (qr & 7)) << 3)];
    const short8v aq1 = *(const short8v*)&Qs[qr * 64 + (((quad + 4) ^ (qr & 7)) << 3)];

    float lsum[4] = {0.f, 0.f, 0.f, 0.f};
    f32x4 o_acc[4];
#pragma unroll
    for (int nt = 0; nt < 4; nt++) o_acc[nt] = (f32x4)(0.0f);

    for (int kc = 0; kc < 2048; kc += 64) {
        __syncthreads();
        GLOAD_LDS(Kg + base + (size_t)(kc + g0 * 8 + dr) * 1024 + dc, Ks + g0 * 512);
        GLOAD_LDS(Kg + base + (size_t)(kc + g1 * 8 + dr) * 1024 + dc, Ks + g1 * 512);
        GLOAD_LDS(Vt + vbase + (size_t)(g0 * 8 + dr) * 2048 + kc + dc, Vs + g0 * 512);
        GLOAD_LDS(Vt + vbase + (size_t)(g1 * 8 + dr) * 2048 + kc + dc, Vs + g1 * 512);
        __syncthreads();

        f32x4 s[4];
#pragma unroll
        for (int nt = 0; nt < 4; nt++) s[nt] = (f32x4)(0.0f);
#pragma unroll
        for (int nt = 0; nt < 4; nt++) {
            const int kr = nt * 16 + lr;
            short8v bk0 = *(const short8v*)&Ks[kr * 64 + ((quad ^ (kr & 7)) << 3)];
            short8v bk1 = *(const short8v*)&Ks[kr * 64 + (((quad + 4) ^ (kr & 7)) << 3)];
            s[nt] = __builtin_amdgcn_mfma_f32_16x16x32_bf16(aq0, bk0, s[nt], 0, 0, 0);
            s[nt] = __builtin_amdgcn_mfma_f32_16x16x32_bf16(aq1, bk1, s[nt], 0, 0, 0);
        }

#pragma unroll
        for (int nt = 0; nt < 4; nt++) {
#pragma unroll
            for (int reg = 0; reg < 4; reg++) {
                const float p = __expf(s[nt][reg]);
                lsum[reg] += p;
                Ps[w][quad * 4 + reg][nt * 16 + lr] = f2bf(p);
            }
        }
        const short8v ap0 = *(const short8v*)&Ps[w][lr][quad * 8];
        const short8v ap1 = *(const short8v*)&Ps[w][lr][32 + quad * 8];
#pragma unroll
        for (int nt = 0; nt < 4; nt++) {
            const int vr = nt * 16 + lr;
            short8v vf0 = *(const short8v*)&Vs[vr * 64 + ((quad ^ (vr & 7)) << 3)];
            short8v vf1 = *(const short8v*)&Vs[vr * 64 + (((quad + 4) ^ (vr & 7)) << 3)];
            o_acc[nt] = __builtin_amdgcn_mfma_f32_16x16x32_bf16(ap0, vf0, o_acc[nt], 0, 0, 0);
            o_acc[nt] = __builtin_amdgcn_mfma_f32_16x16x32_bf16(ap1, vf1, o_acc[nt], 0, 0, 0);
        }
    }

    float l_i[4];
#pragma unroll
    for (int reg = 0; reg < 4; reg++) {
        float t = lsum[reg];
        t += __shfl_xor(t, 1);
        t += __shfl_xor(t, 2);
        t += __shfl_xor(t, 4);
        t += __shfl_xor(t, 8);
        l_i[reg] = t;
    }

#pragma unroll
    for (int nt = 0; nt < 4; nt++)
#pragma unroll
        for (int reg = 0; reg < 4; reg++) {
            const float out = o_acc[nt][reg] / l_i[reg];
            O[base + (size_t)(row0 + w * 16 + quad * 4 + reg) * 1024 +
              nt * 16 + lr] = f2bf(out);
        }
}

// ---------- layernorm over 1024 cols; writes fp32 and/or bf16 ----------
__global__ __launch_bounds__(256) void ln_k(
    const float* __restrict__ X, const float* __restrict__ g,
    const float* __restrict__ bb, float* __restrict__ outf,
    u16* __restrict__ outb) {
    const int row = blockIdx.x, tid = threadIdx.x;
    const float* x = X + (size_t)row * 1024;
    float4 xv = *(const float4*)&x[tid * 4];
    float s = xv.x + xv.y + xv.z + xv.w;
    float s2 = xv.x * xv.x + xv.y * xv.y + xv.z * xv.z + xv.w * xv.w;
#pragma unroll
    for (int msk = 32; msk >= 1; msk >>= 1) {
        s += __shfl_xor(s, msk);
        s2 += __shfl_xor(s2, msk);
    }
    __shared__ float red[8];
    const int wv = tid >> 6;
    if ((tid & 63) == 0) { red[wv] = s; red[wv + 4] = s2; }
    __syncthreads();
    s = red[0] + red[1] + red[2] + red[3];
    s2 = red[4] + red[5] + red[6] + red[7];
    const float mu = s * (1.f / 1024.f);
    float var = s2 * (1.f / 1024.f) - mu * mu;
    var = fmaxf(var, 0.f);
    const float rstd = rsqrtf(var + 1e-5f);
    float4 g4 = *(const float4*)&g[tid * 4];
    float4 b4 = *(const float4*)&bb[tid * 4];
    float o0 = (xv.x - mu) * rstd * g4.x + b4.x;
    float o1 = (xv.y - mu) * rstd * g4.y + b4.y;
    float o2 = (xv.z - mu) * rstd * g4.z + b4.z;
    float o3 = (xv.w - mu) * rstd * g4.w + b4.w;
    if (outf)
        *(float4*)(outf + (size_t)row * 1024 + tid * 4) = make_float4(o0, o1, o2, o3);
    if (outb) {
        ushort4 ov;
        ov.x = f2bf(o0); ov.y = f2bf(o1); ov.z = f2bf(o2); ov.w = f2bf(o3);
        *(ushort4*)(outb + (size_t)row * 1024 + tid * 4) = ov;
    }
}

extern "C" void kernel_launch(void* const* d_in, const int* in_sizes, int n_in,
                              void* d_out, int out_size, void* d_ws, size_t ws_size,
                              hipStream_t stream) {
    const float* tgt = (const float*)d_in[0];
    const float* Wq  = (const float*)d_in[1];
    const float* bq  = (const float*)d_in[2];
    const float* Wk  = (const float*)d_in[3];
    const float* bk  = (const float*)d_in[4];
    const float* Wv  = (const float*)d_in[5];
    const float* bv  = (const float*)d_in[6];
    const float* Wo  = (const float*)d_in[7];
    const float* bo  = (const float*)d_in[8];
    const float* W1  = (const float*)d_in[9];
    const float* b1  = (const float*)d_in[10];
    const float* W2  = (const float*)d_in[11];
    const float* b2  = (const float*)d_in[12];
    const float* g1  = (const float*)d_in[13];
    const float* be1 = (const float*)d_in[14];
    const float* g2  = (const float*)d_in[15];
    const float* be2 = (const float*)d_in[16];
    const float* rA  = (const float*)d_in[17];
    const float* rB  = (const float*)d_in[18];

    const int M = 4096, D = 1024, DFF = 4096;
    const size_t MD = (size_t)M * D;
    const size_t MB = 1u << 20;
    char* wsb = (char*)d_ws;

    u16* q    = (u16*)wsb;                 // q,kk,vv,ctx: 8 MB each
    u16* vv   = q + 2 * MD;
    u16* ctx  = q + 3 * MD;
    u16* h    = q;                         // 32 MB alias (free after Wo gemm)
    float* x1  = (float*)(wsb + 32 * MB);  // 16 MB
    float* sfp = (float*)(wsb + 48 * MB);  // 4 MB
    float* cfp = sfp + (size_t)2048 * 512; // 4 MB
    u16* x1b  = (u16*)sfp;                 // 8 MB alias (free after QKV)
    u16* tgtb = (u16*)(wsb + 56 * MB);     // 8 MB
    u16* Vt   = (u16*)(wsb + 56 * MB);     // 8 MB alias (tgtb dead after mqkv)
    u16* Wqt  = (u16*)(wsb + 64 * MB);     // 2 MB each; Wqt|Wkt|Wvt contiguous
    u16* Wkt  = (u16*)(wsb + 66 * MB);
    u16* Wvt  = (u16*)(wsb + 68 * MB);
    u16* Wot  = (u16*)(wsb + 70 * MB);
    u16* W1t  = (u16*)(wsb + 72 * MB);     // 8 MB [4096][1024]
    u16* W2t  = (u16*)(wsb + 80 * MB);     // 8 MB [1024][4096]
    float* Pp = (float*)(wsb + 88 * MB);   // 128 KB

    cast_k<<<dim3(4096), dim3(256), 0, stream>>>(tgt, tgtb);
    tcast_k<<<dim3(32, 32),  dim3(256), 0, stream>>>(Wq, Wqt, D, D);
    tcast_k<<<dim3(32, 32),  dim3(256), 0, stream>>>(Wk, Wkt, D, D);
    tcast_k<<<dim3(32, 32),  dim3(256), 0, stream>>>(Wv, Wvt, D, D);
    tcast_k<<<dim3(32, 32),  dim3(256), 0, stream>>>(Wo, Wot, D, D);
    tcast_k<<<dim3(128, 32), dim3(256), 0, stream>>>(W1, W1t, D, DFF);
    tcast_k<<<dim3(32, 128), dim3(256), 0, stream>>>(W2, W2t, DFF, D);
    rope1_k<<<dim3(128), dim3(256), 0, stream>>>(rA, Pp);
    rope2_k<<<dim3(4096), dim3(256), 0, stream>>>(Pp, rB, sfp, cfp);

    // 24n x 32m, xn=4 -> per-XCD 6n x 16m
    mqkv_k<<<dim3(768), dim3(256), 0, stream>>>(
        tgtb, Wqt, bq, bk, bv, sfp, cfp, q);

    vtrans_k<<<dim3(64, 2, 32), dim3(256), 0, stream>>>(vv, Vt);

    mattn_k<<<dim3(1024), dim3(256), 0, stream>>>(q, q + MD, Vt, ctx);

    // Wo: BN=64 -> 16n x 32m = 512 blocks (2/CU); xn=2 -> per-XCD 8n x 8m
    mgemm_k<EP_RES, false, 64><<<dim3(512), dim3(256), 0, stream>>>(
        ctx, Wot, bo, tgt, x1, M, D, D, 2, 8, 8);
    ln_k<<<dim3(4096), dim3(256), 0, stream>>>(x1, g1, be1, x1, x1b);
    // FFN1: BN=128 -> 32n x 32m = 1024 blocks; xn=4 -> per-XCD 8n x 16m
    mgemm_k<EP_RELU, true, 128><<<dim3(1024), dim3(256), 0, stream>>>(
        x1b, W1t, b1, nullptr, h, M, DFF, D, 4, 8, 16);
    // FFN2: BN=64 -> 16n x 32m = 512 blocks (2/CU); xn=2 -> per-XCD 8n x 8m
    mgemm_k<EP_RES, false, 64><<<dim3(512), dim3(256), 0, stream>>>(
        h, W2t, b2, x1, x1, M, D, DFF, 2, 8, 8);
    ln_k<<<dim3(4096), dim3(256), 0, stream>>>(x1, g2, be2, (float*)d_out, nullptr);

    (void)in_sizes; (void)n_in; (void)out_size; (void)ws_size;
}